// Round 1
// baseline (4036.131 us; speedup 1.0000x reference)
//
#include <hip/hip_runtime.h>
#include <hip/hip_bf16.h>

// ---------------------------------------------------------------------------
// NCP model: 5-layer conv head + FC + LTC (liquid time-constant) recurrence.
// Round 0: straightforward fp32 implementation for a correct baseline.
// ---------------------------------------------------------------------------

static __device__ __forceinline__ float sigmoidf_fast(float x) {
    return 1.0f / (1.0f + __expf(-x));
}

// ---------------------------------------------------------------------------
// Direct convolution + bias + relu. NCHW / OIHW, VALID padding.
// One thread per output element. Inner window unrolled so the compiler can
// merge kw-consecutive loads into dwordx4.
// ---------------------------------------------------------------------------
template<int CIN, int KH, int KW, int STRIDE>
__global__ __launch_bounds__(256)
void conv_relu_kernel(const float* __restrict__ in, const float* __restrict__ wt,
                      const float* __restrict__ bias, float* __restrict__ out,
                      int Cout, int Hin, int Win, int Hout, int Wout, int total)
{
    int idx = blockIdx.x * blockDim.x + threadIdx.x;
    if (idx >= total) return;
    int wo = idx % Wout;
    int t  = idx / Wout;
    int ho = t % Hout; t /= Hout;
    int co = t % Cout;
    int m  = t / Cout;

    const float* ip = in + ((m * CIN) * Hin + ho * STRIDE) * Win + wo * STRIDE;
    const float* wp = wt + co * (CIN * KH * KW);
    float acc = bias[co];
    for (int ci = 0; ci < CIN; ++ci) {
        const float* iprow = ip + ci * (Hin * Win);
        const float* wrow  = wp + ci * (KH * KW);
        #pragma unroll
        for (int kh = 0; kh < KH; ++kh) {
            #pragma unroll
            for (int kw = 0; kw < KW; ++kw) {
                acc = fmaf(iprow[kh * Win + kw], wrow[kh * KW + kw], acc);
            }
        }
    }
    out[idx] = fmaxf(acc, 0.0f);
}

// ---------------------------------------------------------------------------
// FC (1152 -> 128) + relu. One block per frame (bt), 128 threads (one per out).
// Input row staged in LDS; weight reads coalesced across j.
// ---------------------------------------------------------------------------
__global__ __launch_bounds__(128)
void fc_relu_kernel(const float* __restrict__ h, const float* __restrict__ w,
                    const float* __restrict__ b, float* __restrict__ out)
{
    __shared__ float hs[1152];
    int bt = blockIdx.x;
    int j  = threadIdx.x; // 0..127
    for (int k = j; k < 1152; k += 128) hs[k] = h[bt * 1152 + k];
    __syncthreads();
    float acc = b[j];
    for (int k = 0; k < 1152; ++k) {
        acc = fmaf(hs[k], w[k * 128 + j], acc);
    }
    out[bt * 128 + j] = fmaxf(acc, 0.0f);
}

// ---------------------------------------------------------------------------
// Sensory synapse pre-computation: for each (b,t,n) sum over S=128 sensory
// inputs. Fully parallel over B*T (512 blocks), 64 threads = one per neuron.
// ---------------------------------------------------------------------------
__global__ __launch_bounds__(64)
void sensory_kernel(const float* __restrict__ feat,   // [BT, 128]
                    const float* __restrict__ s_mu,   // [128, 64]
                    const float* __restrict__ s_sigma,
                    const float* __restrict__ s_w,
                    const float* __restrict__ s_erev,
                    float* __restrict__ wnum,         // [BT, 64]
                    float* __restrict__ wden)         // [BT, 64]
{
    __shared__ float y[128];
    int bt = blockIdx.x;
    int n  = threadIdx.x; // 0..63
    for (int s = n; s < 128; s += 64) y[s] = feat[bt * 128 + s];
    __syncthreads();
    float num = 0.0f, den = 0.0f;
    for (int s = 0; s < 128; ++s) {
        int o = s * 64 + n;
        float a = s_w[o] * sigmoidf_fast((y[s] - s_mu[o]) * s_sigma[o]);
        num = fmaf(a, s_erev[o], num);
        den += a;
    }
    wnum[bt * 64 + n] = num;
    wden[bt * 64 + n] = den;
}

// ---------------------------------------------------------------------------
// LTC recurrence: one block per batch element (32 blocks), 256 threads.
// Thread (j = tid&63, p = tid>>6): p-th quarter of the i-sum for neuron j.
// N=64, T=16, 6 ODE unfolds per step. Matrices staged in LDS (64 KB).
// ---------------------------------------------------------------------------
__global__ __launch_bounds__(256)
void ltc_kernel(const float* __restrict__ wnum_s,  // [B*T, 64]
                const float* __restrict__ wden_s,  // [B*T, 64]
                const float* __restrict__ mu,      // [64, 64]
                const float* __restrict__ sigma,
                const float* __restrict__ w,
                const float* __restrict__ erev,
                const float* __restrict__ gleak,   // [64]
                const float* __restrict__ vleak,
                const float* __restrict__ cm,
                float* __restrict__ out,           // [B*T, 3]
                int T)
{
    __shared__ float smu[4096], ssg[4096], sww[4096], ser[4096];
    __shared__ float vsh[64];
    __shared__ float pnum[4][64], pden[4][64];

    int b   = blockIdx.x;
    int tid = threadIdx.x;
    int j = tid & 63, p = tid >> 6;

    for (int k = tid; k < 4096; k += 256) {
        smu[k] = mu[k]; ssg[k] = sigma[k]; sww[k] = w[k]; ser[k] = erev[k];
    }
    if (tid < 64) vsh[tid] = 0.0f;
    float gl  = gleak[j];
    float glvl = gl * vleak[j];
    float cmt = cm[j] * 6.0f;  // cm * ODE_UNFOLDS
    __syncthreads();

    for (int t = 0; t < T; ++t) {
        float ns = wnum_s[(b * T + t) * 64 + j];
        float ds = wden_s[(b * T + t) * 64 + j];
        for (int u = 0; u < 6; ++u) {
            float num = 0.0f, den = 0.0f;
            #pragma unroll
            for (int ii = 0; ii < 16; ++ii) {
                int i = p * 16 + ii;
                int o = i * 64 + j;
                float a = sww[o] * sigmoidf_fast((vsh[i] - smu[o]) * ssg[o]);
                num = fmaf(a, ser[o], num);
                den += a;
            }
            pnum[p][j] = num; pden[p][j] = den;
            __syncthreads();
            if (p == 0) {
                float wn = pnum[0][j] + pnum[1][j] + pnum[2][j] + pnum[3][j] + ns;
                float wd = pden[0][j] + pden[1][j] + pden[2][j] + pden[3][j] + ds;
                vsh[j] = (cmt * vsh[j] + glvl + wn) / (cmt + gl + wd + 1e-8f);
            }
            __syncthreads();
        }
        if (tid < 3) out[(b * T + t) * 3 + tid] = vsh[tid];
    }
}

// ---------------------------------------------------------------------------
// Launch
// ---------------------------------------------------------------------------
extern "C" void kernel_launch(void* const* d_in, const int* in_sizes, int n_in,
                              void* d_out, int out_size, void* d_ws, size_t ws_size,
                              hipStream_t stream)
{
    (void)in_sizes; (void)n_in; (void)out_size; (void)ws_size;

    const float* x    = (const float*)d_in[0];
    const float* w1   = (const float*)d_in[1];
    const float* b1   = (const float*)d_in[2];
    const float* w2   = (const float*)d_in[3];
    const float* b2   = (const float*)d_in[4];
    const float* w3   = (const float*)d_in[5];
    const float* b3   = (const float*)d_in[6];
    const float* w4   = (const float*)d_in[7];
    const float* b4   = (const float*)d_in[8];
    const float* w5   = (const float*)d_in[9];
    const float* b5   = (const float*)d_in[10];
    const float* fcw  = (const float*)d_in[11];
    const float* fcb  = (const float*)d_in[12];
    const float* smu  = (const float*)d_in[13];
    const float* ssig = (const float*)d_in[14];
    const float* sw   = (const float*)d_in[15];
    const float* serv = (const float*)d_in[16];
    const float* mu   = (const float*)d_in[17];
    const float* sig  = (const float*)d_in[18];
    const float* ww   = (const float*)d_in[19];
    const float* erev = (const float*)d_in[20];
    const float* gl   = (const float*)d_in[21];
    const float* vl   = (const float*)d_in[22];
    const float* cm   = (const float*)d_in[23];
    float* out = (float*)d_out;

    const int BT = 512; // B=32, T=16
    // scratch layout (floats)
    float* ws = (float*)d_ws;
    const size_t nA = (size_t)BT * 24 * 31 * 98;   // 37,330,944 (h1; reused for h3, h5)
    const size_t nB = (size_t)BT * 36 * 14 * 47;   // 12,128,256 (h2; reused for h4)
    float* bufA = ws;
    float* bufB = bufA + nA;
    float* feat = bufB + nB;                       // 512*128
    float* wnum = feat + (size_t)BT * 128;         // 512*64
    float* wden = wnum + (size_t)BT * 64;          // 512*64

    // conv1: [512,3,66,200] -> [512,24,31,98]
    {
        int total = BT * 24 * 31 * 98;
        conv_relu_kernel<3, 5, 5, 2><<<(total + 255) / 256, 256, 0, stream>>>(
            x, w1, b1, bufA, 24, 66, 200, 31, 98, total);
    }
    // conv2: -> [512,36,14,47]
    {
        int total = BT * 36 * 14 * 47;
        conv_relu_kernel<24, 5, 5, 2><<<(total + 255) / 256, 256, 0, stream>>>(
            bufA, w2, b2, bufB, 36, 31, 98, 14, 47, total);
    }
    // conv3: -> [512,48,5,22]
    {
        int total = BT * 48 * 5 * 22;
        conv_relu_kernel<36, 5, 5, 2><<<(total + 255) / 256, 256, 0, stream>>>(
            bufB, w3, b3, bufA, 48, 14, 47, 5, 22, total);
    }
    // conv4: -> [512,64,3,20]
    {
        int total = BT * 64 * 3 * 20;
        conv_relu_kernel<48, 3, 3, 1><<<(total + 255) / 256, 256, 0, stream>>>(
            bufA, w4, b4, bufB, 64, 5, 22, 3, 20, total);
    }
    // conv5: -> [512,64,1,18]
    {
        int total = BT * 64 * 1 * 18;
        conv_relu_kernel<64, 3, 3, 1><<<(total + 255) / 256, 256, 0, stream>>>(
            bufB, w5, b5, bufA, 64, 3, 20, 1, 18, total);
    }
    // fc: [512,1152] -> [512,128]
    fc_relu_kernel<<<BT, 128, 0, stream>>>(bufA, fcw, fcb, feat);
    // sensory: [512,128] -> wnum/wden [512,64]
    sensory_kernel<<<BT, 64, 0, stream>>>(feat, smu, ssig, sw, serv, wnum, wden);
    // LTC recurrence: 32 batches
    ltc_kernel<<<32, 256, 0, stream>>>(wnum, wden, mu, sig, ww, erev, gl, vl, cm,
                                       out, 16);
}

// Round 2
// 664.800 us; speedup vs baseline: 6.0712x; 6.0712x over previous
//
#include <hip/hip_runtime.h>
#include <hip/hip_bf16.h>

// ---------------------------------------------------------------------------
// NCP model: 5-layer conv head + FC + LTC recurrence.
// Round 1: register-blocked direct conv (CO_T x WO_T per thread), scalar
// weight loads (co block-uniform), cg-fastest block order for L2 reuse.
// ---------------------------------------------------------------------------

static __device__ __forceinline__ float sigmoidf_fast(float x) {
    return 1.0f / (1.0f + __expf(-x));
}

// ---------------------------------------------------------------------------
// Register-tiled direct conv + bias + relu. NCHW / OIHW, VALID.
// blockIdx.x = sm_block * n_cg + cg   (cg fastest -> input-sharing blocks
//                                      are dispatch-adjacent -> L2 hot)
// thread gid = sm_block*blockDim + tid covers (m, ho, wo_grp) linearly,
// wo_grp fastest -> coalesced input rows.
// Each thread: CO_T output channels x WO_T horizontal positions.
// Weights/bias indexed block-uniformly -> compiler emits scalar loads.
// ---------------------------------------------------------------------------
template<int CIN, int KH, int KW, int STRIDE, int CO_T, int WO_T>
__global__ __launch_bounds__(256)
void conv_tile_kernel(const float* __restrict__ in, const float* __restrict__ wt,
                      const float* __restrict__ bias, float* __restrict__ out,
                      int Cout, int Hin, int Win, int Hout, int Wout,
                      int n_cg, int n_wg, int M)
{
    constexpr int LOAD_W = (WO_T - 1) * STRIDE + KW;

    int bx = blockIdx.x;
    int cg = bx % n_cg;                       // block-uniform co group
    int gid = (bx / n_cg) * blockDim.x + threadIdx.x;
    int wg = gid % n_wg;
    int t  = gid / n_wg;
    int ho = t % Hout;
    int m  = t / Hout;
    if (m >= M) return;

    int wo0 = wg * WO_T;
    int co0 = cg * CO_T;

    const float* ip = in + ((size_t)(m * CIN) * Hin + (size_t)ho * STRIDE) * Win
                         + (size_t)wo0 * STRIDE;
    const float* wp = wt + (size_t)co0 * (CIN * KH * KW);

    float acc[CO_T][WO_T];
    #pragma unroll
    for (int c = 0; c < CO_T; ++c) {
        float b = bias[co0 + c];
        #pragma unroll
        for (int q = 0; q < WO_T; ++q) acc[c][q] = b;
    }

    #pragma unroll 1
    for (int ci = 0; ci < CIN; ++ci) {
        #pragma unroll
        for (int kh = 0; kh < KH; ++kh) {
            const float* row = ip + ((size_t)ci * Hin + kh) * Win;
            float xv[LOAD_W];
            #pragma unroll
            for (int l = 0; l < LOAD_W; ++l) xv[l] = row[l];
            const float* wrow = wp + (ci * KH + kh) * KW;
            #pragma unroll
            for (int c = 0; c < CO_T; ++c) {
                #pragma unroll
                for (int kw = 0; kw < KW; ++kw) {
                    float wv = wrow[c * (CIN * KH * KW) + kw];   // scalar load
                    #pragma unroll
                    for (int q = 0; q < WO_T; ++q)
                        acc[c][q] = fmaf(xv[q * STRIDE + kw], wv, acc[c][q]);
                }
            }
        }
    }

    #pragma unroll
    for (int c = 0; c < CO_T; ++c) {
        float* op = out + (((size_t)m * Cout + co0 + c) * Hout + ho) * Wout + wo0;
        #pragma unroll
        for (int q = 0; q < WO_T; ++q) {
            if (wo0 + q < Wout) op[q] = fmaxf(acc[c][q], 0.0f);
        }
    }
}

// ---------------------------------------------------------------------------
// FC (1152 -> 128) + relu. 8 frames per block: weight matrix streamed once
// per block (64 blocks) instead of once per frame (512).
// ---------------------------------------------------------------------------
__global__ __launch_bounds__(128)
void fc_relu_kernel(const float* __restrict__ h, const float* __restrict__ w,
                    const float* __restrict__ b, float* __restrict__ out)
{
    __shared__ float hs[8 * 1152];
    int f0 = blockIdx.x * 8;
    int j  = threadIdx.x; // 0..127
    for (int k = j; k < 8 * 1152; k += 128) hs[k] = h[(size_t)f0 * 1152 + k];
    __syncthreads();
    float acc[8];
    float bj = b[j];
    #pragma unroll
    for (int f = 0; f < 8; ++f) acc[f] = bj;
    for (int k = 0; k < 1152; ++k) {
        float wv = w[k * 128 + j];
        #pragma unroll
        for (int f = 0; f < 8; ++f)
            acc[f] = fmaf(hs[f * 1152 + k], wv, acc[f]);  // LDS broadcast
    }
    #pragma unroll
    for (int f = 0; f < 8; ++f)
        out[(size_t)(f0 + f) * 128 + j] = fmaxf(acc[f], 0.0f);
}

// ---------------------------------------------------------------------------
// Sensory synapse pre-computation (parallel over B*T).
// ---------------------------------------------------------------------------
__global__ __launch_bounds__(64)
void sensory_kernel(const float* __restrict__ feat,   // [BT, 128]
                    const float* __restrict__ s_mu,   // [128, 64]
                    const float* __restrict__ s_sigma,
                    const float* __restrict__ s_w,
                    const float* __restrict__ s_erev,
                    float* __restrict__ wnum,         // [BT, 64]
                    float* __restrict__ wden)         // [BT, 64]
{
    __shared__ float y[128];
    int bt = blockIdx.x;
    int n  = threadIdx.x; // 0..63
    for (int s = n; s < 128; s += 64) y[s] = feat[bt * 128 + s];
    __syncthreads();
    float num = 0.0f, den = 0.0f;
    for (int s = 0; s < 128; ++s) {
        int o = s * 64 + n;
        float a = s_w[o] * sigmoidf_fast((y[s] - s_mu[o]) * s_sigma[o]);
        num = fmaf(a, s_erev[o], num);
        den += a;
    }
    wnum[bt * 64 + n] = num;
    wden[bt * 64 + n] = den;
}

// ---------------------------------------------------------------------------
// LTC recurrence: one block per batch element (32 blocks), 256 threads.
// ---------------------------------------------------------------------------
__global__ __launch_bounds__(256)
void ltc_kernel(const float* __restrict__ wnum_s,  // [B*T, 64]
                const float* __restrict__ wden_s,  // [B*T, 64]
                const float* __restrict__ mu,      // [64, 64]
                const float* __restrict__ sigma,
                const float* __restrict__ w,
                const float* __restrict__ erev,
                const float* __restrict__ gleak,   // [64]
                const float* __restrict__ vleak,
                const float* __restrict__ cm,
                float* __restrict__ out,           // [B*T, 3]
                int T)
{
    __shared__ float smu[4096], ssg[4096], sww[4096], ser[4096];
    __shared__ float vsh[64];
    __shared__ float pnum[4][64], pden[4][64];

    int b   = blockIdx.x;
    int tid = threadIdx.x;
    int j = tid & 63, p = tid >> 6;

    for (int k = tid; k < 4096; k += 256) {
        smu[k] = mu[k]; ssg[k] = sigma[k]; sww[k] = w[k]; ser[k] = erev[k];
    }
    if (tid < 64) vsh[tid] = 0.0f;
    float gl   = gleak[j];
    float glvl = gl * vleak[j];
    float cmt  = cm[j] * 6.0f;  // cm * ODE_UNFOLDS
    __syncthreads();

    for (int t = 0; t < T; ++t) {
        float ns = wnum_s[(b * T + t) * 64 + j];
        float ds = wden_s[(b * T + t) * 64 + j];
        for (int u = 0; u < 6; ++u) {
            float num = 0.0f, den = 0.0f;
            #pragma unroll
            for (int ii = 0; ii < 16; ++ii) {
                int i = p * 16 + ii;
                int o = i * 64 + j;
                float a = sww[o] * sigmoidf_fast((vsh[i] - smu[o]) * ssg[o]);
                num = fmaf(a, ser[o], num);
                den += a;
            }
            pnum[p][j] = num; pden[p][j] = den;
            __syncthreads();
            if (p == 0) {
                float wn = pnum[0][j] + pnum[1][j] + pnum[2][j] + pnum[3][j] + ns;
                float wd = pden[0][j] + pden[1][j] + pden[2][j] + pden[3][j] + ds;
                vsh[j] = (cmt * vsh[j] + glvl + wn) / (cmt + gl + wd + 1e-8f);
            }
            __syncthreads();
        }
        if (tid < 3) out[(b * T + t) * 3 + tid] = vsh[tid];
    }
}

// ---------------------------------------------------------------------------
// Launch
// ---------------------------------------------------------------------------
extern "C" void kernel_launch(void* const* d_in, const int* in_sizes, int n_in,
                              void* d_out, int out_size, void* d_ws, size_t ws_size,
                              hipStream_t stream)
{
    (void)in_sizes; (void)n_in; (void)out_size; (void)ws_size;

    const float* x    = (const float*)d_in[0];
    const float* w1   = (const float*)d_in[1];
    const float* b1   = (const float*)d_in[2];
    const float* w2   = (const float*)d_in[3];
    const float* b2   = (const float*)d_in[4];
    const float* w3   = (const float*)d_in[5];
    const float* b3   = (const float*)d_in[6];
    const float* w4   = (const float*)d_in[7];
    const float* b4   = (const float*)d_in[8];
    const float* w5   = (const float*)d_in[9];
    const float* b5   = (const float*)d_in[10];
    const float* fcw  = (const float*)d_in[11];
    const float* fcb  = (const float*)d_in[12];
    const float* smu  = (const float*)d_in[13];
    const float* ssig = (const float*)d_in[14];
    const float* sw   = (const float*)d_in[15];
    const float* serv = (const float*)d_in[16];
    const float* mu   = (const float*)d_in[17];
    const float* sig  = (const float*)d_in[18];
    const float* ww   = (const float*)d_in[19];
    const float* erev = (const float*)d_in[20];
    const float* gl   = (const float*)d_in[21];
    const float* vl   = (const float*)d_in[22];
    const float* cm   = (const float*)d_in[23];
    float* out = (float*)d_out;

    const int BT = 512; // B=32, T=16

    float* ws = (float*)d_ws;
    const size_t nA = (size_t)BT * 24 * 31 * 98;   // h1 (reused h3, h5)
    const size_t nB = (size_t)BT * 36 * 14 * 47;   // h2 (reused h4)
    float* bufA = ws;
    float* bufB = bufA + nA;
    float* feat = bufB + nB;                       // 512*128
    float* wnum = feat + (size_t)BT * 128;
    float* wden = wnum + (size_t)BT * 64;

    // conv1: [512,3,66,200] -> [512,24,31,98]   CO_T=4,WO_T=4: n_cg=6,n_wg=25
    {
        int n_cg = 6, n_wg = 25;
        int sp_threads = BT * 31 * n_wg;           // 396800 = 1550*256
        int grid = (sp_threads + 255) / 256 * n_cg;
        conv_tile_kernel<3, 5, 5, 2, 4, 4><<<grid, 256, 0, stream>>>(
            x, w1, b1, bufA, 24, 66, 200, 31, 98, n_cg, n_wg, BT);
    }
    // conv2: -> [512,36,14,47]   n_cg=9, n_wg=12
    {
        int n_cg = 9, n_wg = 12;
        int sp_threads = BT * 14 * n_wg;           // 86016 = 336*256
        int grid = (sp_threads + 255) / 256 * n_cg;
        conv_tile_kernel<24, 5, 5, 2, 4, 4><<<grid, 256, 0, stream>>>(
            bufA, w2, b2, bufB, 36, 31, 98, 14, 47, n_cg, n_wg, BT);
    }
    // conv3: -> [512,48,5,22]    CO_T=4,WO_T=2: n_cg=12, n_wg=11
    {
        int n_cg = 12, n_wg = 11;
        int sp_threads = BT * 5 * n_wg;            // 28160 = 110*256
        int grid = (sp_threads + 255) / 256 * n_cg;
        conv_tile_kernel<36, 5, 5, 2, 4, 2><<<grid, 256, 0, stream>>>(
            bufB, w3, b3, bufA, 48, 14, 47, 5, 22, n_cg, n_wg, BT);
    }
    // conv4: -> [512,64,3,20]    CO_T=4,WO_T=4: n_cg=16, n_wg=5
    {
        int n_cg = 16, n_wg = 5;
        int sp_threads = BT * 3 * n_wg;            // 7680 = 30*256
        int grid = (sp_threads + 255) / 256 * n_cg;
        conv_tile_kernel<48, 3, 3, 1, 4, 4><<<grid, 256, 0, stream>>>(
            bufA, w4, b4, bufB, 64, 5, 22, 3, 20, n_cg, n_wg, BT);
    }
    // conv5: -> [512,64,1,18]    CO_T=4,WO_T=3: n_cg=16, n_wg=6
    {
        int n_cg = 16, n_wg = 6;
        int sp_threads = BT * 1 * n_wg;            // 3072 = 12*256
        int grid = (sp_threads + 255) / 256 * n_cg;
        conv_tile_kernel<64, 3, 3, 1, 4, 3><<<grid, 256, 0, stream>>>(
            bufB, w5, b5, bufA, 64, 3, 20, 1, 18, n_cg, n_wg, BT);
    }
    // fc: [512,1152] -> [512,128], 8 frames/block
    fc_relu_kernel<<<BT / 8, 128, 0, stream>>>(bufA, fcw, fcb, feat);
    // sensory
    sensory_kernel<<<BT, 64, 0, stream>>>(feat, smu, ssig, sw, serv, wnum, wden);
    // LTC recurrence
    ltc_kernel<<<32, 256, 0, stream>>>(wnum, wden, mu, sig, ww, erev, gl, vl, cm,
                                       out, 16);
}

// Round 3
// 507.370 us; speedup vs baseline: 7.9550x; 1.3103x over previous
//
#include <hip/hip_runtime.h>
#include <hip/hip_bf16.h>

// ---------------------------------------------------------------------------
// NCP model: conv head + FC + LTC recurrence.
// Round 2: conv1 = fp32 all-co register tile -> f16 swizzled-NHWC output.
//          conv2 = f16 MFMA (16x16x32) implicit GEMM from LDS tile.
//          conv3..ltc unchanged from round 1.
// ---------------------------------------------------------------------------

typedef _Float16 f16;
typedef _Float16 f16x8 __attribute__((ext_vector_type(8)));
typedef float    f32x4 __attribute__((ext_vector_type(4)));
typedef unsigned int u32;

static __device__ __forceinline__ float sigmoidf_fast(float x) {
    return 1.0f / (1.0f + __expf(-x));
}

// ---------------------------------------------------------------------------
// h1T layout: [512][31][296 slots][8 halves] f16. For output pixel (m,r,w)
// and channel-chunk c8 (channels 8*c8..8*c8+7), the 16-byte chunk lives at
// slot = (3*w + c8) ^ ((w>>1)&7)  within row r. Bijective within each row
// (XOR permutes aligned 8-blocks; verified periodic in w with period 16).
// Rows are 296 slots (294 used + 2 pad) so the XOR image stays in-row.
// ---------------------------------------------------------------------------

// conv1: x[512,3,66,200] fp32 -> h1T (relu applied). One thread: 24 co x 2 wo.
__global__ __launch_bounds__(256)
void conv1_kernel(const float* __restrict__ x, const float* __restrict__ w1,
                  const float* __restrict__ b1, f16* __restrict__ h1T)
{
    int gid = blockIdx.x * 256 + threadIdx.x;
    int wg = gid % 49;
    int t  = gid / 49;
    int r  = t % 31;
    int m  = t / 31;
    if (m >= 512) return;

    float acc[24][2];
    #pragma unroll
    for (int c = 0; c < 24; ++c) { float b = b1[c]; acc[c][0] = b; acc[c][1] = b; }

    const float* ip = x + ((size_t)(m * 3) * 66 + 2 * r) * 200 + 4 * wg;
    #pragma unroll 1
    for (int ci = 0; ci < 3; ++ci) {
        #pragma unroll
        for (int kh = 0; kh < 5; ++kh) {
            const float* row = ip + (ci * 66 + kh) * 200;
            float xv[7];
            #pragma unroll
            for (int l = 0; l < 7; ++l) xv[l] = row[l];
            const float* wr = w1 + (ci * 5 + kh) * 5;   // + c*75 + kw
            #pragma unroll
            for (int c = 0; c < 24; ++c) {
                #pragma unroll
                for (int kw = 0; kw < 5; ++kw) {
                    float wv = wr[c * 75 + kw];          // block-uniform -> scalar
                    acc[c][0] = fmaf(xv[kw],     wv, acc[c][0]);
                    acc[c][1] = fmaf(xv[kw + 2], wv, acc[c][1]);
                }
            }
        }
    }

    size_t imgbase = ((size_t)m * 31 + r) * 296;   // 16B units
    #pragma unroll
    for (int q = 0; q < 2; ++q) {
        int w = 2 * wg + q;
        int key = (w >> 1) & 7;
        #pragma unroll
        for (int c8 = 0; c8 < 3; ++c8) {
            f16x8 pk;
            #pragma unroll
            for (int j = 0; j < 8; ++j) pk[j] = (f16)fmaxf(acc[c8 * 8 + j][q], 0.0f);
            int sl = (3 * w + c8) ^ key;
            *(f16x8*)(h1T + (imgbase + (size_t)sl) * 8) = pk;
        }
    }
}

// ---------------------------------------------------------------------------
// Weight pack for conv2: w2[36,24,5,5] fp32 -> Wpk[48][616] f16.
// K enumeration: k = ((kh*5+kw)*3 + c8)*8 + j, ci = c8*8+j. k>=600, co>=36,
// and the 8-half row pad are zeros.
// ---------------------------------------------------------------------------
__global__ __launch_bounds__(256)
void wpack_kernel(const float* __restrict__ w2, f16* __restrict__ Wpk)
{
    int idx = blockIdx.x * 256 + threadIdx.x;
    if (idx >= 48 * 616) return;
    int co = idx / 616;
    int kk = idx % 616;
    float v = 0.0f;
    if (kk < 608 && co < 36) {
        int c = kk >> 3, j = kk & 7;
        if (c < 75) {
            int pq = c / 3, c8 = c - 3 * pq;
            int kh = pq / 5, kw = pq - 5 * kh;
            int ci = c8 * 8 + j;
            v = w2[(((size_t)co * 24 + ci) * 5 + kh) * 5 + kw];
        }
    }
    Wpk[idx] = (f16)v;
}

// ---------------------------------------------------------------------------
// conv2 via MFMA: h2[m][co][ho][wo] = relu(b2 + sum over K). Block = one m.
// 6 waves: wave = (ct = wv>>1 co-subtile of 16, sh = wv&1 half of 6 px-tiles).
// 7 ho-pair steps; tile = 7 input rows, double-buffered, reg-staged early.
// ---------------------------------------------------------------------------
__global__ __launch_bounds__(384)
void conv2_mfma(const f16* __restrict__ h1T, const f16* __restrict__ Wpk,
                const float* __restrict__ b2, float* __restrict__ h2)
{
    __shared__ __align__(16) f16 Wl[48 * 616];        // 59,136 B
    __shared__ __align__(16) f16 tl[2][7 * 2368];     // 2 x 33,152 B
    __shared__ u32 lutS[76];

    int m    = blockIdx.x;
    int tid  = threadIdx.x;
    int lane = tid & 63;
    int wv   = tid >> 6;          // 0..5
    int ct   = wv >> 1;           // co subtile 0..2
    int sh   = wv & 1;            // px-tile half
    int row4 = lane >> 4;         // kb / D-row group
    int col  = lane & 15;

    // lut: chunk c -> {kh*4736 (row bytes), kw>>1, 3*kw+c8}; c==75 -> zeros
    if (tid < 76) {
        int c = tid; u32 v = 0;
        if (c < 75) {
            int pq = c / 3, c8 = c - 3 * pq;
            int kh = pq / 5, kw = pq - 5 * kh;
            v = ((u32)(kh * 4736) << 8) | ((u32)(kw >> 1) << 4) | (u32)(3 * kw + c8);
        }
        lutS[c] = v;
    }

    // stage weights into LDS (once)
    for (int u = tid; u < 3696; u += 384) {
        uint4 v = *(const uint4*)((const char*)Wpk + (size_t)u * 16);
        *(uint4*)((char*)Wl + (size_t)u * 16) = v;
    }

    // per-lane constants
    int six_wo[3], wokey[3], rpoff[3], valid[3];
    #pragma unroll
    for (int si = 0; si < 3; ++si) {
        int s  = 3 * sh + si;
        int px = 16 * s + col;
        int rp = (px >= 48) ? 1 : 0;
        int wo = px - 48 * rp;
        valid[si] = (wo < 47);
        int wog = wo < 47 ? wo : 46;   // clamp pad lane in-bounds
        six_wo[si] = 6 * wog;
        wokey[si]  = wog;
        rpoff[si]  = rp * 9472;        // 2 rows * 4736 B
    }
    int Abase = (ct * 16 + col) * 1232 + row4 * 16;   // byte offset in Wl
    float bv[4];
    #pragma unroll
    for (int i = 0; i < 4; ++i) {
        int co = ct * 16 + row4 * 4 + i;
        bv[i] = (co < 36) ? b2[co] : 0.0f;
    }

    // staging registers (6 x 16B per thread covers 2072 units)
    uint4 stg[6];
    const f16* imgbase = h1T + (size_t)m * 31 * 2368;

    // prologue: tile 0 straight into LDS
    {
        const char* g = (const char*)(imgbase);
        #pragma unroll
        for (int i = 0; i < 6; ++i) {
            int u = tid + i * 384;
            if (u < 2072) *(uint4*)((char*)tl[0] + (size_t)u * 16) =
                              *(const uint4*)(g + (size_t)u * 16);
        }
    }
    __syncthreads();

    const char* Wc = (const char*)Wl;
    for (int p = 0; p < 7; ++p) {
        int cur = p & 1;
        // issue next tile's global loads early (latency hides under MFMA loop)
        if (p < 6) {
            const char* g = (const char*)(imgbase + (size_t)(4 * (p + 1)) * 2368);
            #pragma unroll
            for (int i = 0; i < 6; ++i) {
                int u = tid + i * 384;
                if (u < 2072) stg[i] = *(const uint4*)(g + (size_t)u * 16);
            }
        }

        const char* tb = (const char*)tl[cur];
        f32x4 acc0 = {0.f,0.f,0.f,0.f}, acc1 = {0.f,0.f,0.f,0.f}, acc2 = {0.f,0.f,0.f,0.f};
        #pragma unroll
        for (int t = 0; t < 19; ++t) {
            u32 lv   = lutS[4 * t + row4];
            int rowb = (int)(lv >> 8);
            int kwh  = (int)((lv >> 4) & 3);
            int ofs3 = (int)(lv & 15);
            f16x8 af = *(const f16x8*)(Wc + Abase + 64 * t);
            {
                int u0 = six_wo[0] + ofs3, k0 = (wokey[0] + kwh) & 7;
                f16x8 xf = *(const f16x8*)(tb + rpoff[0] + rowb + ((u0 ^ k0) << 4));
                acc0 = __builtin_amdgcn_mfma_f32_16x16x32_f16(af, xf, acc0, 0, 0, 0);
            }
            {
                int u1 = six_wo[1] + ofs3, k1 = (wokey[1] + kwh) & 7;
                f16x8 xf = *(const f16x8*)(tb + rpoff[1] + rowb + ((u1 ^ k1) << 4));
                acc1 = __builtin_amdgcn_mfma_f32_16x16x32_f16(af, xf, acc1, 0, 0, 0);
            }
            {
                int u2 = six_wo[2] + ofs3, k2 = (wokey[2] + kwh) & 7;
                f16x8 xf = *(const f16x8*)(tb + rpoff[2] + rowb + ((u2 ^ k2) << 4));
                acc2 = __builtin_amdgcn_mfma_f32_16x16x32_f16(af, xf, acc2, 0, 0, 0);
            }
        }

        // epilogue: D row = co (within subtile), col = px
        #pragma unroll
        for (int si = 0; si < 3; ++si) {
            f32x4 a = (si == 0) ? acc0 : (si == 1) ? acc1 : acc2;
            int s  = 3 * sh + si;
            int px = 16 * s + col;
            int rp = (px >= 48) ? 1 : 0;
            int wo = px - 48 * rp;
            int ho = 2 * p + rp;
            if (valid[si]) {
                #pragma unroll
                for (int i = 0; i < 4; ++i) {
                    int co = ct * 16 + row4 * 4 + i;
                    if (co < 36)
                        h2[(((size_t)m * 36 + co) * 14 + ho) * 47 + wo] =
                            fmaxf(a[i] + bv[i], 0.0f);
                }
            }
        }

        // write staged tile into the other buffer
        if (p < 6) {
            #pragma unroll
            for (int i = 0; i < 6; ++i) {
                int u = tid + i * 384;
                if (u < 2072) *(uint4*)((char*)tl[cur ^ 1] + (size_t)u * 16) = stg[i];
            }
        }
        __syncthreads();
    }
}

// ---------------------------------------------------------------------------
// Register-tiled fp32 direct conv (round 1) for conv3..conv5.
// ---------------------------------------------------------------------------
template<int CIN, int KH, int KW, int STRIDE, int CO_T, int WO_T>
__global__ __launch_bounds__(256)
void conv_tile_kernel(const float* __restrict__ in, const float* __restrict__ wt,
                      const float* __restrict__ bias, float* __restrict__ out,
                      int Cout, int Hin, int Win, int Hout, int Wout,
                      int n_cg, int n_wg, int M)
{
    constexpr int LOAD_W = (WO_T - 1) * STRIDE + KW;

    int bx = blockIdx.x;
    int cg = bx % n_cg;
    int gid = (bx / n_cg) * blockDim.x + threadIdx.x;
    int wg = gid % n_wg;
    int t  = gid / n_wg;
    int ho = t % Hout;
    int m  = t / Hout;
    if (m >= M) return;

    int wo0 = wg * WO_T;
    int co0 = cg * CO_T;

    const float* ip = in + ((size_t)(m * CIN) * Hin + (size_t)ho * STRIDE) * Win
                         + (size_t)wo0 * STRIDE;
    const float* wp = wt + (size_t)co0 * (CIN * KH * KW);

    float acc[CO_T][WO_T];
    #pragma unroll
    for (int c = 0; c < CO_T; ++c) {
        float b = bias[co0 + c];
        #pragma unroll
        for (int q = 0; q < WO_T; ++q) acc[c][q] = b;
    }

    #pragma unroll 1
    for (int ci = 0; ci < CIN; ++ci) {
        #pragma unroll
        for (int kh = 0; kh < KH; ++kh) {
            const float* row = ip + ((size_t)ci * Hin + kh) * Win;
            float xv[LOAD_W];
            #pragma unroll
            for (int l = 0; l < LOAD_W; ++l) xv[l] = row[l];
            const float* wrow = wp + (ci * KH + kh) * KW;
            #pragma unroll
            for (int c = 0; c < CO_T; ++c) {
                #pragma unroll
                for (int kw = 0; kw < KW; ++kw) {
                    float wv = wrow[c * (CIN * KH * KW) + kw];
                    #pragma unroll
                    for (int q = 0; q < WO_T; ++q)
                        acc[c][q] = fmaf(xv[q * STRIDE + kw], wv, acc[c][q]);
                }
            }
        }
    }

    #pragma unroll
    for (int c = 0; c < CO_T; ++c) {
        float* op = out + (((size_t)m * Cout + co0 + c) * Hout + ho) * Wout + wo0;
        #pragma unroll
        for (int q = 0; q < WO_T; ++q) {
            if (wo0 + q < Wout) op[q] = fmaxf(acc[c][q], 0.0f);
        }
    }
}

// ---------------------------------------------------------------------------
// FC (1152 -> 128) + relu, 8 frames/block.
// ---------------------------------------------------------------------------
__global__ __launch_bounds__(128)
void fc_relu_kernel(const float* __restrict__ h, const float* __restrict__ w,
                    const float* __restrict__ b, float* __restrict__ out)
{
    __shared__ float hs[8 * 1152];
    int f0 = blockIdx.x * 8;
    int j  = threadIdx.x;
    for (int k = j; k < 8 * 1152; k += 128) hs[k] = h[(size_t)f0 * 1152 + k];
    __syncthreads();
    float acc[8];
    float bj = b[j];
    #pragma unroll
    for (int f = 0; f < 8; ++f) acc[f] = bj;
    for (int k = 0; k < 1152; ++k) {
        float wv = w[k * 128 + j];
        #pragma unroll
        for (int f = 0; f < 8; ++f)
            acc[f] = fmaf(hs[f * 1152 + k], wv, acc[f]);
    }
    #pragma unroll
    for (int f = 0; f < 8; ++f)
        out[(size_t)(f0 + f) * 128 + j] = fmaxf(acc[f], 0.0f);
}

// ---------------------------------------------------------------------------
// Sensory synapse pre-computation.
// ---------------------------------------------------------------------------
__global__ __launch_bounds__(64)
void sensory_kernel(const float* __restrict__ feat,
                    const float* __restrict__ s_mu,
                    const float* __restrict__ s_sigma,
                    const float* __restrict__ s_w,
                    const float* __restrict__ s_erev,
                    float* __restrict__ wnum, float* __restrict__ wden)
{
    __shared__ float y[128];
    int bt = blockIdx.x;
    int n  = threadIdx.x;
    for (int s = n; s < 128; s += 64) y[s] = feat[bt * 128 + s];
    __syncthreads();
    float num = 0.0f, den = 0.0f;
    for (int s = 0; s < 128; ++s) {
        int o = s * 64 + n;
        float a = s_w[o] * sigmoidf_fast((y[s] - s_mu[o]) * s_sigma[o]);
        num = fmaf(a, s_erev[o], num);
        den += a;
    }
    wnum[bt * 64 + n] = num;
    wden[bt * 64 + n] = den;
}

// ---------------------------------------------------------------------------
// LTC recurrence.
// ---------------------------------------------------------------------------
__global__ __launch_bounds__(256)
void ltc_kernel(const float* __restrict__ wnum_s, const float* __restrict__ wden_s,
                const float* __restrict__ mu, const float* __restrict__ sigma,
                const float* __restrict__ w, const float* __restrict__ erev,
                const float* __restrict__ gleak, const float* __restrict__ vleak,
                const float* __restrict__ cm, float* __restrict__ out, int T)
{
    __shared__ float smu[4096], ssg[4096], sww[4096], ser[4096];
    __shared__ float vsh[64];
    __shared__ float pnum[4][64], pden[4][64];

    int b   = blockIdx.x;
    int tid = threadIdx.x;
    int j = tid & 63, p = tid >> 6;

    for (int k = tid; k < 4096; k += 256) {
        smu[k] = mu[k]; ssg[k] = sigma[k]; sww[k] = w[k]; ser[k] = erev[k];
    }
    if (tid < 64) vsh[tid] = 0.0f;
    float gl   = gleak[j];
    float glvl = gl * vleak[j];
    float cmt  = cm[j] * 6.0f;
    __syncthreads();

    for (int t = 0; t < T; ++t) {
        float ns = wnum_s[(b * T + t) * 64 + j];
        float ds = wden_s[(b * T + t) * 64 + j];
        for (int u = 0; u < 6; ++u) {
            float num = 0.0f, den = 0.0f;
            #pragma unroll
            for (int ii = 0; ii < 16; ++ii) {
                int i = p * 16 + ii;
                int o = i * 64 + j;
                float a = sww[o] * sigmoidf_fast((vsh[i] - smu[o]) * ssg[o]);
                num = fmaf(a, ser[o], num);
                den += a;
            }
            pnum[p][j] = num; pden[p][j] = den;
            __syncthreads();
            if (p == 0) {
                float wn = pnum[0][j] + pnum[1][j] + pnum[2][j] + pnum[3][j] + ns;
                float wd = pden[0][j] + pden[1][j] + pden[2][j] + pden[3][j] + ds;
                vsh[j] = (cmt * vsh[j] + glvl + wn) / (cmt + gl + wd + 1e-8f);
            }
            __syncthreads();
        }
        if (tid < 3) out[(b * T + t) * 3 + tid] = vsh[tid];
    }
}

// ---------------------------------------------------------------------------
// Launch
// ---------------------------------------------------------------------------
extern "C" void kernel_launch(void* const* d_in, const int* in_sizes, int n_in,
                              void* d_out, int out_size, void* d_ws, size_t ws_size,
                              hipStream_t stream)
{
    (void)in_sizes; (void)n_in; (void)out_size; (void)ws_size;

    const float* x    = (const float*)d_in[0];
    const float* w1   = (const float*)d_in[1];
    const float* b1   = (const float*)d_in[2];
    const float* w2   = (const float*)d_in[3];
    const float* b2   = (const float*)d_in[4];
    const float* w3   = (const float*)d_in[5];
    const float* b3   = (const float*)d_in[6];
    const float* w4   = (const float*)d_in[7];
    const float* b4   = (const float*)d_in[8];
    const float* w5   = (const float*)d_in[9];
    const float* b5   = (const float*)d_in[10];
    const float* fcw  = (const float*)d_in[11];
    const float* fcb  = (const float*)d_in[12];
    const float* smu  = (const float*)d_in[13];
    const float* ssig = (const float*)d_in[14];
    const float* sw   = (const float*)d_in[15];
    const float* serv = (const float*)d_in[16];
    const float* mu   = (const float*)d_in[17];
    const float* sig  = (const float*)d_in[18];
    const float* ww   = (const float*)d_in[19];
    const float* erev = (const float*)d_in[20];
    const float* gl   = (const float*)d_in[21];
    const float* vl   = (const float*)d_in[22];
    const float* cm   = (const float*)d_in[23];
    float* out = (float*)d_out;

    const int BT = 512;

    char* wsB = (char*)d_ws;
    size_t off = 0;
    f16*   h1T = (f16*)(wsB + off); off += (size_t)512 * 31 * 2368 * 2;  // 75.2 MB
    f16*   Wpk = (f16*)(wsB + off); off += 65536;                        // 59,136 B used
    float* h2  = (float*)(wsB + off); off += (size_t)512 * 36 * 14 * 47 * 4;
    float* h3  = (float*)(wsB + off); off += (size_t)512 * 48 * 5 * 22 * 4;
    float* h4  = (float*)(wsB + off); off += (size_t)512 * 64 * 3 * 20 * 4;
    float* h5  = (float*)(wsB + off); off += (size_t)512 * 64 * 18 * 4;
    float* feat = (float*)(wsB + off); off += (size_t)BT * 128 * 4;
    float* wnum = (float*)(wsB + off); off += (size_t)BT * 64 * 4;
    float* wden = (float*)(wsB + off); off += (size_t)BT * 64 * 4;

    // weight pack + conv1 (independent)
    wpack_kernel<<<(48 * 616 + 255) / 256, 256, 0, stream>>>(w2, Wpk);
    conv1_kernel<<<(512 * 31 * 49 + 255) / 256, 256, 0, stream>>>(x, w1, b1, h1T);

    // conv2 MFMA: one block per image
    conv2_mfma<<<512, 384, 0, stream>>>(h1T, Wpk, b2, h2);

    // conv3: [512,36,14,47] -> [512,48,5,22]
    {
        int n_cg = 12, n_wg = 11;
        int sp_threads = BT * 5 * n_wg;
        int grid = (sp_threads + 255) / 256 * n_cg;
        conv_tile_kernel<36, 5, 5, 2, 4, 2><<<grid, 256, 0, stream>>>(
            h2, w3, b3, h3, 48, 14, 47, 5, 22, n_cg, n_wg, BT);
    }
    // conv4: -> [512,64,3,20]
    {
        int n_cg = 16, n_wg = 5;
        int sp_threads = BT * 3 * n_wg;
        int grid = (sp_threads + 255) / 256 * n_cg;
        conv_tile_kernel<48, 3, 3, 1, 4, 4><<<grid, 256, 0, stream>>>(
            h3, w4, b4, h4, 64, 5, 22, 3, 20, n_cg, n_wg, BT);
    }
    // conv5: -> [512,64,1,18]
    {
        int n_cg = 16, n_wg = 6;
        int sp_threads = BT * 1 * n_wg;
        int grid = (sp_threads + 255) / 256 * n_cg;
        conv_tile_kernel<64, 3, 3, 1, 4, 3><<<grid, 256, 0, stream>>>(
            h4, w5, b5, h5, 64, 3, 20, 1, 18, n_cg, n_wg, BT);
    }
    // fc + sensory + ltc
    fc_relu_kernel<<<BT / 8, 128, 0, stream>>>(h5, fcw, fcb, feat);
    sensory_kernel<<<BT, 64, 0, stream>>>(feat, smu, ssig, sw, serv, wnum, wden);
    ltc_kernel<<<32, 256, 0, stream>>>(wnum, wden, mu, sig, ww, erev, gl, vl, cm,
                                       out, 16);
}

// Round 4
// 435.045 us; speedup vs baseline: 9.2775x; 1.1662x over previous
//
#include <hip/hip_runtime.h>
#include <hip/hip_bf16.h>

// ---------------------------------------------------------------------------
// NCP model: conv head + FC + LTC recurrence.
// Round 3: LTC rewritten — 8 waves/batch, matrix rows in registers,
//          one barrier per unfold (redundant update in all waves), v_rcp.
//          conv1/conv2(MFMA)/conv3-5/fc/sensory as round 2.
// ---------------------------------------------------------------------------

typedef _Float16 f16;
typedef _Float16 f16x8 __attribute__((ext_vector_type(8)));
typedef float    f32x4 __attribute__((ext_vector_type(4)));
typedef unsigned int u32;

static __device__ __forceinline__ float sigmoidf_fast(float x) {
    return __builtin_amdgcn_rcpf(1.0f + __expf(-x));
}

// ---------------------------------------------------------------------------
// h1T layout: [512][31][296 slots][8 halves] f16; slot = (3*w + c8) ^ ((w>>1)&7).
// ---------------------------------------------------------------------------

// conv1: x[512,3,66,200] fp32 -> h1T (relu applied). One thread: 24 co x 2 wo.
__global__ __launch_bounds__(256)
void conv1_kernel(const float* __restrict__ x, const float* __restrict__ w1,
                  const float* __restrict__ b1, f16* __restrict__ h1T)
{
    int gid = blockIdx.x * 256 + threadIdx.x;
    int wg = gid % 49;
    int t  = gid / 49;
    int r  = t % 31;
    int m  = t / 31;
    if (m >= 512) return;

    float acc[24][2];
    #pragma unroll
    for (int c = 0; c < 24; ++c) { float b = b1[c]; acc[c][0] = b; acc[c][1] = b; }

    const float* ip = x + ((size_t)(m * 3) * 66 + 2 * r) * 200 + 4 * wg;
    #pragma unroll 1
    for (int ci = 0; ci < 3; ++ci) {
        #pragma unroll
        for (int kh = 0; kh < 5; ++kh) {
            const float* row = ip + (ci * 66 + kh) * 200;
            float xv[7];
            #pragma unroll
            for (int l = 0; l < 7; ++l) xv[l] = row[l];
            const float* wr = w1 + (ci * 5 + kh) * 5;
            #pragma unroll
            for (int c = 0; c < 24; ++c) {
                #pragma unroll
                for (int kw = 0; kw < 5; ++kw) {
                    float wv = wr[c * 75 + kw];
                    acc[c][0] = fmaf(xv[kw],     wv, acc[c][0]);
                    acc[c][1] = fmaf(xv[kw + 2], wv, acc[c][1]);
                }
            }
        }
    }

    size_t imgbase = ((size_t)m * 31 + r) * 296;
    #pragma unroll
    for (int q = 0; q < 2; ++q) {
        int w = 2 * wg + q;
        int key = (w >> 1) & 7;
        #pragma unroll
        for (int c8 = 0; c8 < 3; ++c8) {
            f16x8 pk;
            #pragma unroll
            for (int j = 0; j < 8; ++j) pk[j] = (f16)fmaxf(acc[c8 * 8 + j][q], 0.0f);
            int sl = (3 * w + c8) ^ key;
            *(f16x8*)(h1T + (imgbase + (size_t)sl) * 8) = pk;
        }
    }
}

// Weight pack for conv2: w2[36,24,5,5] fp32 -> Wpk[48][616] f16.
__global__ __launch_bounds__(256)
void wpack_kernel(const float* __restrict__ w2, f16* __restrict__ Wpk)
{
    int idx = blockIdx.x * 256 + threadIdx.x;
    if (idx >= 48 * 616) return;
    int co = idx / 616;
    int kk = idx % 616;
    float v = 0.0f;
    if (kk < 608 && co < 36) {
        int c = kk >> 3, j = kk & 7;
        if (c < 75) {
            int pq = c / 3, c8 = c - 3 * pq;
            int kh = pq / 5, kw = pq - 5 * kh;
            int ci = c8 * 8 + j;
            v = w2[(((size_t)co * 24 + ci) * 5 + kh) * 5 + kw];
        }
    }
    Wpk[idx] = (f16)v;
}

// conv2 via MFMA implicit GEMM. Block = one image, 6 waves, 7 ho-pair steps.
__global__ __launch_bounds__(384)
void conv2_mfma(const f16* __restrict__ h1T, const f16* __restrict__ Wpk,
                const float* __restrict__ b2, float* __restrict__ h2)
{
    __shared__ __align__(16) f16 Wl[48 * 616];
    __shared__ __align__(16) f16 tl[2][7 * 2368];
    __shared__ u32 lutS[76];

    int m    = blockIdx.x;
    int tid  = threadIdx.x;
    int lane = tid & 63;
    int wv   = tid >> 6;
    int ct   = wv >> 1;
    int sh   = wv & 1;
    int row4 = lane >> 4;
    int col  = lane & 15;

    if (tid < 76) {
        int c = tid; u32 v = 0;
        if (c < 75) {
            int pq = c / 3, c8 = c - 3 * pq;
            int kh = pq / 5, kw = pq - 5 * kh;
            v = ((u32)(kh * 4736) << 8) | ((u32)(kw >> 1) << 4) | (u32)(3 * kw + c8);
        }
        lutS[c] = v;
    }

    for (int u = tid; u < 3696; u += 384) {
        uint4 v = *(const uint4*)((const char*)Wpk + (size_t)u * 16);
        *(uint4*)((char*)Wl + (size_t)u * 16) = v;
    }

    int six_wo[3], wokey[3], rpoff[3], valid[3];
    #pragma unroll
    for (int si = 0; si < 3; ++si) {
        int s  = 3 * sh + si;
        int px = 16 * s + col;
        int rp = (px >= 48) ? 1 : 0;
        int wo = px - 48 * rp;
        valid[si] = (wo < 47);
        int wog = wo < 47 ? wo : 46;
        six_wo[si] = 6 * wog;
        wokey[si]  = wog;
        rpoff[si]  = rp * 9472;
    }
    int Abase = (ct * 16 + col) * 1232 + row4 * 16;
    float bv[4];
    #pragma unroll
    for (int i = 0; i < 4; ++i) {
        int co = ct * 16 + row4 * 4 + i;
        bv[i] = (co < 36) ? b2[co] : 0.0f;
    }

    uint4 stg[6];
    const f16* imgbase = h1T + (size_t)m * 31 * 2368;

    {
        const char* g = (const char*)(imgbase);
        #pragma unroll
        for (int i = 0; i < 6; ++i) {
            int u = tid + i * 384;
            if (u < 2072) *(uint4*)((char*)tl[0] + (size_t)u * 16) =
                              *(const uint4*)(g + (size_t)u * 16);
        }
    }
    __syncthreads();

    const char* Wc = (const char*)Wl;
    for (int p = 0; p < 7; ++p) {
        int cur = p & 1;
        if (p < 6) {
            const char* g = (const char*)(imgbase + (size_t)(4 * (p + 1)) * 2368);
            #pragma unroll
            for (int i = 0; i < 6; ++i) {
                int u = tid + i * 384;
                if (u < 2072) stg[i] = *(const uint4*)(g + (size_t)u * 16);
            }
        }

        const char* tb = (const char*)tl[cur];
        f32x4 acc0 = {0.f,0.f,0.f,0.f}, acc1 = {0.f,0.f,0.f,0.f}, acc2 = {0.f,0.f,0.f,0.f};
        #pragma unroll
        for (int t = 0; t < 19; ++t) {
            u32 lv   = lutS[4 * t + row4];
            int rowb = (int)(lv >> 8);
            int kwh  = (int)((lv >> 4) & 3);
            int ofs3 = (int)(lv & 15);
            f16x8 af = *(const f16x8*)(Wc + Abase + 64 * t);
            {
                int u0 = six_wo[0] + ofs3, k0 = (wokey[0] + kwh) & 7;
                f16x8 xf = *(const f16x8*)(tb + rpoff[0] + rowb + ((u0 ^ k0) << 4));
                acc0 = __builtin_amdgcn_mfma_f32_16x16x32_f16(af, xf, acc0, 0, 0, 0);
            }
            {
                int u1 = six_wo[1] + ofs3, k1 = (wokey[1] + kwh) & 7;
                f16x8 xf = *(const f16x8*)(tb + rpoff[1] + rowb + ((u1 ^ k1) << 4));
                acc1 = __builtin_amdgcn_mfma_f32_16x16x32_f16(af, xf, acc1, 0, 0, 0);
            }
            {
                int u2 = six_wo[2] + ofs3, k2 = (wokey[2] + kwh) & 7;
                f16x8 xf = *(const f16x8*)(tb + rpoff[2] + rowb + ((u2 ^ k2) << 4));
                acc2 = __builtin_amdgcn_mfma_f32_16x16x32_f16(af, xf, acc2, 0, 0, 0);
            }
        }

        #pragma unroll
        for (int si = 0; si < 3; ++si) {
            f32x4 a = (si == 0) ? acc0 : (si == 1) ? acc1 : acc2;
            int s  = 3 * sh + si;
            int px = 16 * s + col;
            int rp = (px >= 48) ? 1 : 0;
            int wo = px - 48 * rp;
            int ho = 2 * p + rp;
            if (valid[si]) {
                #pragma unroll
                for (int i = 0; i < 4; ++i) {
                    int co = ct * 16 + row4 * 4 + i;
                    if (co < 36)
                        h2[(((size_t)m * 36 + co) * 14 + ho) * 47 + wo] =
                            fmaxf(a[i] + bv[i], 0.0f);
                }
            }
        }

        if (p < 6) {
            #pragma unroll
            for (int i = 0; i < 6; ++i) {
                int u = tid + i * 384;
                if (u < 2072) *(uint4*)((char*)tl[cur ^ 1] + (size_t)u * 16) = stg[i];
            }
        }
        __syncthreads();
    }
}

// Register-tiled fp32 direct conv for conv3..conv5.
template<int CIN, int KH, int KW, int STRIDE, int CO_T, int WO_T>
__global__ __launch_bounds__(256)
void conv_tile_kernel(const float* __restrict__ in, const float* __restrict__ wt,
                      const float* __restrict__ bias, float* __restrict__ out,
                      int Cout, int Hin, int Win, int Hout, int Wout,
                      int n_cg, int n_wg, int M)
{
    constexpr int LOAD_W = (WO_T - 1) * STRIDE + KW;

    int bx = blockIdx.x;
    int cg = bx % n_cg;
    int gid = (bx / n_cg) * blockDim.x + threadIdx.x;
    int wg = gid % n_wg;
    int t  = gid / n_wg;
    int ho = t % Hout;
    int m  = t / Hout;
    if (m >= M) return;

    int wo0 = wg * WO_T;
    int co0 = cg * CO_T;

    const float* ip = in + ((size_t)(m * CIN) * Hin + (size_t)ho * STRIDE) * Win
                         + (size_t)wo0 * STRIDE;
    const float* wp = wt + (size_t)co0 * (CIN * KH * KW);

    float acc[CO_T][WO_T];
    #pragma unroll
    for (int c = 0; c < CO_T; ++c) {
        float b = bias[co0 + c];
        #pragma unroll
        for (int q = 0; q < WO_T; ++q) acc[c][q] = b;
    }

    #pragma unroll 1
    for (int ci = 0; ci < CIN; ++ci) {
        #pragma unroll
        for (int kh = 0; kh < KH; ++kh) {
            const float* row = ip + ((size_t)ci * Hin + kh) * Win;
            float xv[LOAD_W];
            #pragma unroll
            for (int l = 0; l < LOAD_W; ++l) xv[l] = row[l];
            const float* wrow = wp + (ci * KH + kh) * KW;
            #pragma unroll
            for (int c = 0; c < CO_T; ++c) {
                #pragma unroll
                for (int kw = 0; kw < KW; ++kw) {
                    float wv = wrow[c * (CIN * KH * KW) + kw];
                    #pragma unroll
                    for (int q = 0; q < WO_T; ++q)
                        acc[c][q] = fmaf(xv[q * STRIDE + kw], wv, acc[c][q]);
                }
            }
        }
    }

    #pragma unroll
    for (int c = 0; c < CO_T; ++c) {
        float* op = out + (((size_t)m * Cout + co0 + c) * Hout + ho) * Wout + wo0;
        #pragma unroll
        for (int q = 0; q < WO_T; ++q) {
            if (wo0 + q < Wout) op[q] = fmaxf(acc[c][q], 0.0f);
        }
    }
}

// FC (1152 -> 128) + relu, 8 frames/block.
__global__ __launch_bounds__(128)
void fc_relu_kernel(const float* __restrict__ h, const float* __restrict__ w,
                    const float* __restrict__ b, float* __restrict__ out)
{
    __shared__ float hs[8 * 1152];
    int f0 = blockIdx.x * 8;
    int j  = threadIdx.x;
    for (int k = j; k < 8 * 1152; k += 128) hs[k] = h[(size_t)f0 * 1152 + k];
    __syncthreads();
    float acc[8];
    float bj = b[j];
    #pragma unroll
    for (int f = 0; f < 8; ++f) acc[f] = bj;
    for (int k = 0; k < 1152; ++k) {
        float wv = w[k * 128 + j];
        #pragma unroll
        for (int f = 0; f < 8; ++f)
            acc[f] = fmaf(hs[f * 1152 + k], wv, acc[f]);
    }
    #pragma unroll
    for (int f = 0; f < 8; ++f)
        out[(size_t)(f0 + f) * 128 + j] = fmaxf(acc[f], 0.0f);
}

// Sensory synapse pre-computation.
__global__ __launch_bounds__(64)
void sensory_kernel(const float* __restrict__ feat,
                    const float* __restrict__ s_mu,
                    const float* __restrict__ s_sigma,
                    const float* __restrict__ s_w,
                    const float* __restrict__ s_erev,
                    float* __restrict__ wnum, float* __restrict__ wden)
{
    __shared__ float y[128];
    int bt = blockIdx.x;
    int n  = threadIdx.x;
    for (int s = n; s < 128; s += 64) y[s] = feat[bt * 128 + s];
    __syncthreads();
    float num = 0.0f, den = 0.0f;
    for (int s = 0; s < 128; ++s) {
        int o = s * 64 + n;
        float a = s_w[o] * sigmoidf_fast((y[s] - s_mu[o]) * s_sigma[o]);
        num = fmaf(a, s_erev[o], num);
        den += a;
    }
    wnum[bt * 64 + n] = num;
    wden[bt * 64 + n] = den;
}

// ---------------------------------------------------------------------------
// LTC recurrence, round 3: one block (8 waves, 512 thr) per batch element.
// Wave p owns i in [8p, 8p+8); lane = neuron j. Matrix data in registers
// (loaded once). Every wave keeps the full v vector in its lanes and
// redundantly computes the identical update -> ONE barrier per unfold.
// Partials double-buffered so the single barrier is WAR-safe.
// ---------------------------------------------------------------------------
__global__ __launch_bounds__(512)
void ltc_wave_kernel(const float* __restrict__ wnum_s,  // [B*T, 64]
                     const float* __restrict__ wden_s,  // [B*T, 64]
                     const float* __restrict__ mu, const float* __restrict__ sigma,
                     const float* __restrict__ w, const float* __restrict__ erev,
                     const float* __restrict__ gleak, const float* __restrict__ vleak,
                     const float* __restrict__ cm, float* __restrict__ out, int T)
{
    __shared__ float2 pnd[2][8][64];

    int b    = blockIdx.x;
    int tid  = threadIdx.x;
    int lane = tid & 63;   // neuron j
    int p    = tid >> 6;   // wave / i-octant

    // per-lane matrix registers: i = 8p+ii, j = lane
    float musig[8], nsg[8], wv[8], wev[8];
    #pragma unroll
    for (int ii = 0; ii < 8; ++ii) {
        int o = (8 * p + ii) * 64 + lane;
        float sg = sigma[o];
        musig[ii] = mu[o] * sg;     // arg = mu*sg - v*sg = -(v-mu)*sg
        nsg[ii]   = -sg;
        float wl  = w[o];
        wv[ii]    = wl;
        wev[ii]   = wl * erev[o];
    }
    float gl   = gleak[lane];
    float glvl = gl * vleak[lane];
    float cmt  = cm[lane] * 6.0f;   // cm * ODE_UNFOLDS
    float v    = 0.0f;
    int   buf  = 0;

    for (int t = 0; t < T; ++t) {
        float ns = wnum_s[(b * T + t) * 64 + lane];
        float ds = wden_s[(b * T + t) * 64 + lane];
        #pragma unroll 1
        for (int u = 0; u < 6; ++u) {
            float num = 0.0f, den = 0.0f;
            #pragma unroll
            for (int ii = 0; ii < 8; ++ii) {
                float vi  = __shfl(v, 8 * p + ii);
                float arg = fmaf(vi, nsg[ii], musig[ii]);
                float e   = __expf(arg);
                float s   = __builtin_amdgcn_rcpf(1.0f + e);
                den = fmaf(wv[ii], s, den);
                num = fmaf(wev[ii], s, num);
            }
            pnd[buf][p][lane] = make_float2(num, den);
            __syncthreads();
            float wn = ns, wd = ds;
            #pragma unroll
            for (int q = 0; q < 8; ++q) {
                float2 pq = pnd[buf][q][lane];
                wn += pq.x; wd += pq.y;
            }
            v = (fmaf(cmt, v, glvl) + wn) *
                __builtin_amdgcn_rcpf(cmt + gl + wd + 1e-8f);
            buf ^= 1;
        }
        if (tid < 3) out[(b * T + t) * 3 + tid] = v;
    }
}

// ---------------------------------------------------------------------------
// Launch
// ---------------------------------------------------------------------------
extern "C" void kernel_launch(void* const* d_in, const int* in_sizes, int n_in,
                              void* d_out, int out_size, void* d_ws, size_t ws_size,
                              hipStream_t stream)
{
    (void)in_sizes; (void)n_in; (void)out_size; (void)ws_size;

    const float* x    = (const float*)d_in[0];
    const float* w1   = (const float*)d_in[1];
    const float* b1   = (const float*)d_in[2];
    const float* w2   = (const float*)d_in[3];
    const float* b2   = (const float*)d_in[4];
    const float* w3   = (const float*)d_in[5];
    const float* b3   = (const float*)d_in[6];
    const float* w4   = (const float*)d_in[7];
    const float* b4   = (const float*)d_in[8];
    const float* w5   = (const float*)d_in[9];
    const float* b5   = (const float*)d_in[10];
    const float* fcw  = (const float*)d_in[11];
    const float* fcb  = (const float*)d_in[12];
    const float* smu  = (const float*)d_in[13];
    const float* ssig = (const float*)d_in[14];
    const float* sw   = (const float*)d_in[15];
    const float* serv = (const float*)d_in[16];
    const float* mu   = (const float*)d_in[17];
    const float* sig  = (const float*)d_in[18];
    const float* ww   = (const float*)d_in[19];
    const float* erev = (const float*)d_in[20];
    const float* gl   = (const float*)d_in[21];
    const float* vl   = (const float*)d_in[22];
    const float* cm   = (const float*)d_in[23];
    float* out = (float*)d_out;

    const int BT = 512;

    char* wsB = (char*)d_ws;
    size_t off = 0;
    f16*   h1T = (f16*)(wsB + off); off += (size_t)512 * 31 * 2368 * 2;
    f16*   Wpk = (f16*)(wsB + off); off += 65536;
    float* h2  = (float*)(wsB + off); off += (size_t)512 * 36 * 14 * 47 * 4;
    float* h3  = (float*)(wsB + off); off += (size_t)512 * 48 * 5 * 22 * 4;
    float* h4  = (float*)(wsB + off); off += (size_t)512 * 64 * 3 * 20 * 4;
    float* h5  = (float*)(wsB + off); off += (size_t)512 * 64 * 18 * 4;
    float* feat = (float*)(wsB + off); off += (size_t)BT * 128 * 4;
    float* wnum = (float*)(wsB + off); off += (size_t)BT * 64 * 4;
    float* wden = (float*)(wsB + off); off += (size_t)BT * 64 * 4;

    wpack_kernel<<<(48 * 616 + 255) / 256, 256, 0, stream>>>(w2, Wpk);
    conv1_kernel<<<(512 * 31 * 49 + 255) / 256, 256, 0, stream>>>(x, w1, b1, h1T);
    conv2_mfma<<<512, 384, 0, stream>>>(h1T, Wpk, b2, h2);

    {
        int n_cg = 12, n_wg = 11;
        int sp_threads = BT * 5 * n_wg;
        int grid = (sp_threads + 255) / 256 * n_cg;
        conv_tile_kernel<36, 5, 5, 2, 4, 2><<<grid, 256, 0, stream>>>(
            h2, w3, b3, h3, 48, 14, 47, 5, 22, n_cg, n_wg, BT);
    }
    {
        int n_cg = 16, n_wg = 5;
        int sp_threads = BT * 3 * n_wg;
        int grid = (sp_threads + 255) / 256 * n_cg;
        conv_tile_kernel<48, 3, 3, 1, 4, 4><<<grid, 256, 0, stream>>>(
            h3, w4, b4, h4, 64, 5, 22, 3, 20, n_cg, n_wg, BT);
    }
    {
        int n_cg = 16, n_wg = 6;
        int sp_threads = BT * 1 * n_wg;
        int grid = (sp_threads + 255) / 256 * n_cg;
        conv_tile_kernel<64, 3, 3, 1, 4, 3><<<grid, 256, 0, stream>>>(
            h4, w5, b5, h5, 64, 3, 20, 1, 18, n_cg, n_wg, BT);
    }
    fc_relu_kernel<<<BT / 8, 128, 0, stream>>>(h5, fcw, fcb, feat);
    sensory_kernel<<<BT, 64, 0, stream>>>(feat, smu, ssig, sw, serv, wnum, wden);
    ltc_wave_kernel<<<32, 512, 0, stream>>>(wnum, wden, mu, sig, ww, erev,
                                            gl, vl, cm, out, 16);
}

// Round 5
// 373.103 us; speedup vs baseline: 10.8177x; 1.1660x over previous
//
#include <hip/hip_runtime.h>
#include <hip/hip_bf16.h>

// ---------------------------------------------------------------------------
// NCP model: conv head + FC + LTC recurrence.
// Round 4: conv2 writes packed/swizzled f16 h2f directly; conv3 becomes an
//          f16 MFMA implicit GEMM with the whole image in LDS (153.5 KB).
//          conv1/conv4/conv5/fc/sensory/ltc unchanged from round 3.
// ---------------------------------------------------------------------------

typedef _Float16 f16;
typedef _Float16 f16x8 __attribute__((ext_vector_type(8)));
typedef _Float16 f16x4 __attribute__((ext_vector_type(4)));
typedef float    f32x4 __attribute__((ext_vector_type(4)));
typedef unsigned int u32;

static __device__ __forceinline__ float sigmoidf_fast(float x) {
    return __builtin_amdgcn_rcpf(1.0f + __expf(-x));
}

// ---------------------------------------------------------------------------
// h1T layout: [512][31][296 slots][8 halves] f16; slot = (3*w + c8) ^ ((w>>1)&7).
// h2f layout: [512][14 rows][241 slots][8 halves] f16;
//             slot = (5*wo + c8) ^ ((wo>>1)&7)   (chunk c8 = channels 8c8..8c8+7)
// ---------------------------------------------------------------------------

// conv1: x[512,3,66,200] fp32 -> h1T (relu applied). One thread: 24 co x 2 wo.
__global__ __launch_bounds__(256)
void conv1_kernel(const float* __restrict__ x, const float* __restrict__ w1,
                  const float* __restrict__ b1, f16* __restrict__ h1T)
{
    int gid = blockIdx.x * 256 + threadIdx.x;
    int wg = gid % 49;
    int t  = gid / 49;
    int r  = t % 31;
    int m  = t / 31;
    if (m >= 512) return;

    float acc[24][2];
    #pragma unroll
    for (int c = 0; c < 24; ++c) { float b = b1[c]; acc[c][0] = b; acc[c][1] = b; }

    const float* ip = x + ((size_t)(m * 3) * 66 + 2 * r) * 200 + 4 * wg;
    #pragma unroll 1
    for (int ci = 0; ci < 3; ++ci) {
        #pragma unroll
        for (int kh = 0; kh < 5; ++kh) {
            const float* row = ip + (ci * 66 + kh) * 200;
            float xv[7];
            #pragma unroll
            for (int l = 0; l < 7; ++l) xv[l] = row[l];
            const float* wr = w1 + (ci * 5 + kh) * 5;
            #pragma unroll
            for (int c = 0; c < 24; ++c) {
                #pragma unroll
                for (int kw = 0; kw < 5; ++kw) {
                    float wv = wr[c * 75 + kw];
                    acc[c][0] = fmaf(xv[kw],     wv, acc[c][0]);
                    acc[c][1] = fmaf(xv[kw + 2], wv, acc[c][1]);
                }
            }
        }
    }

    size_t imgbase = ((size_t)m * 31 + r) * 296;
    #pragma unroll
    for (int q = 0; q < 2; ++q) {
        int w = 2 * wg + q;
        int key = (w >> 1) & 7;
        #pragma unroll
        for (int c8 = 0; c8 < 3; ++c8) {
            f16x8 pk;
            #pragma unroll
            for (int j = 0; j < 8; ++j) pk[j] = (f16)fmaxf(acc[c8 * 8 + j][q], 0.0f);
            int sl = (3 * w + c8) ^ key;
            *(f16x8*)(h1T + (imgbase + (size_t)sl) * 8) = pk;
        }
    }
}

// Weight pack conv2: w2[36,24,5,5] fp32 -> Wpk[48][616] f16.
__global__ __launch_bounds__(256)
void wpack_kernel(const float* __restrict__ w2, f16* __restrict__ Wpk)
{
    int idx = blockIdx.x * 256 + threadIdx.x;
    if (idx >= 48 * 616) return;
    int co = idx / 616;
    int kk = idx % 616;
    float v = 0.0f;
    if (kk < 608 && co < 36) {
        int c = kk >> 3, j = kk & 7;
        if (c < 75) {
            int pq = c / 3, c8 = c - 3 * pq;
            int kh = pq / 5, kw = pq - 5 * kh;
            int ci = c8 * 8 + j;
            v = w2[(((size_t)co * 24 + ci) * 5 + kh) * 5 + kw];
        }
    }
    Wpk[idx] = (f16)v;
}

// Weight pack conv3: w3[48,36,5,5] fp32 -> Wpk3[48][1032] f16.
// k = c*8 + j, c = (kh*5+kw)*5 + c8 (125 chunks, padded to 128), ci = c8*8+j.
__global__ __launch_bounds__(256)
void wpack3_kernel(const float* __restrict__ w3, f16* __restrict__ Wpk3)
{
    int idx = blockIdx.x * 256 + threadIdx.x;
    if (idx >= 48 * 1032) return;
    int co = idx / 1032;
    int kk = idx % 1032;
    float v = 0.0f;
    if (kk < 1024) {
        int c = kk >> 3, j = kk & 7;
        int pq = c / 5, c8 = c - 5 * pq;
        if (pq < 25) {
            int kh = pq / 5, kw = pq - 5 * kh;
            int ci = c8 * 8 + j;
            if (ci < 36)
                v = w3[(((size_t)co * 36 + ci) * 5 + kh) * 5 + kw];
        }
    }
    Wpk3[idx] = (f16)v;
}

// conv2 via MFMA implicit GEMM. Block = one image, 6 waves, 7 ho-pair steps.
// Output: h2f packed/swizzled f16 (see layout above).
__global__ __launch_bounds__(384)
void conv2_mfma(const f16* __restrict__ h1T, const f16* __restrict__ Wpk,
                const float* __restrict__ b2, f16* __restrict__ h2f)
{
    __shared__ __align__(16) f16 Wl[48 * 616];
    __shared__ __align__(16) f16 tl[2][7 * 2368];
    __shared__ u32 lutS[76];

    int m    = blockIdx.x;
    int tid  = threadIdx.x;
    int lane = tid & 63;
    int wv   = tid >> 6;
    int ct   = wv >> 1;
    int sh   = wv & 1;
    int row4 = lane >> 4;
    int col  = lane & 15;

    if (tid < 76) {
        int c = tid; u32 v = 0;
        if (c < 75) {
            int pq = c / 3, c8 = c - 3 * pq;
            int kh = pq / 5, kw = pq - 5 * kh;
            v = ((u32)(kh * 4736) << 8) | ((u32)(kw >> 1) << 4) | (u32)(3 * kw + c8);
        }
        lutS[c] = v;
    }

    for (int u = tid; u < 3696; u += 384) {
        uint4 v = *(const uint4*)((const char*)Wpk + (size_t)u * 16);
        *(uint4*)((char*)Wl + (size_t)u * 16) = v;
    }

    int six_wo[3], wokey[3], rpoff[3], valid[3];
    #pragma unroll
    for (int si = 0; si < 3; ++si) {
        int s  = 3 * sh + si;
        int px = 16 * s + col;
        int rp = (px >= 48) ? 1 : 0;
        int wo = px - 48 * rp;
        valid[si] = (wo < 47);
        int wog = wo < 47 ? wo : 46;
        six_wo[si] = 6 * wog;
        wokey[si]  = wog;
        rpoff[si]  = rp * 9472;
    }
    int Abase = (ct * 16 + col) * 1232 + row4 * 16;
    float bv[4];
    #pragma unroll
    for (int i = 0; i < 4; ++i) {
        int co = ct * 16 + row4 * 4 + i;
        bv[i] = (co < 36) ? b2[co] : 0.0f;
    }
    int c8o = ct * 2 + (row4 >> 1);     // output chunk index (0..5; 5 = unused)
    int hsel = (row4 & 1) * 4;          // half offset within chunk

    uint4 stg[6];
    const f16* imgbase = h1T + (size_t)m * 31 * 2368;

    {
        const char* g = (const char*)(imgbase);
        #pragma unroll
        for (int i = 0; i < 6; ++i) {
            int u = tid + i * 384;
            if (u < 2072) *(uint4*)((char*)tl[0] + (size_t)u * 16) =
                              *(const uint4*)(g + (size_t)u * 16);
        }
    }
    __syncthreads();

    const char* Wc = (const char*)Wl;
    for (int p = 0; p < 7; ++p) {
        int cur = p & 1;
        if (p < 6) {
            const char* g = (const char*)(imgbase + (size_t)(4 * (p + 1)) * 2368);
            #pragma unroll
            for (int i = 0; i < 6; ++i) {
                int u = tid + i * 384;
                if (u < 2072) stg[i] = *(const uint4*)(g + (size_t)u * 16);
            }
        }

        const char* tb = (const char*)tl[cur];
        f32x4 acc0 = {0.f,0.f,0.f,0.f}, acc1 = {0.f,0.f,0.f,0.f}, acc2 = {0.f,0.f,0.f,0.f};
        #pragma unroll
        for (int t = 0; t < 19; ++t) {
            u32 lv   = lutS[4 * t + row4];
            int rowb = (int)(lv >> 8);
            int kwh  = (int)((lv >> 4) & 3);
            int ofs3 = (int)(lv & 15);
            f16x8 af = *(const f16x8*)(Wc + Abase + 64 * t);
            {
                int u0 = six_wo[0] + ofs3, k0 = (wokey[0] + kwh) & 7;
                f16x8 xf = *(const f16x8*)(tb + rpoff[0] + rowb + ((u0 ^ k0) << 4));
                acc0 = __builtin_amdgcn_mfma_f32_16x16x32_f16(af, xf, acc0, 0, 0, 0);
            }
            {
                int u1 = six_wo[1] + ofs3, k1 = (wokey[1] + kwh) & 7;
                f16x8 xf = *(const f16x8*)(tb + rpoff[1] + rowb + ((u1 ^ k1) << 4));
                acc1 = __builtin_amdgcn_mfma_f32_16x16x32_f16(af, xf, acc1, 0, 0, 0);
            }
            {
                int u2 = six_wo[2] + ofs3, k2 = (wokey[2] + kwh) & 7;
                f16x8 xf = *(const f16x8*)(tb + rpoff[2] + rowb + ((u2 ^ k2) << 4));
                acc2 = __builtin_amdgcn_mfma_f32_16x16x32_f16(af, xf, acc2, 0, 0, 0);
            }
        }

        // epilogue: pack 4 co values -> one f16x4 chunk-half of h2f
        #pragma unroll
        for (int si = 0; si < 3; ++si) {
            f32x4 a = (si == 0) ? acc0 : (si == 1) ? acc1 : acc2;
            int s  = 3 * sh + si;
            int px = 16 * s + col;
            int rp = (px >= 48) ? 1 : 0;
            int wo = px - 48 * rp;
            int ho = 2 * p + rp;
            if (valid[si] && c8o < 5) {
                f16x4 pk;
                #pragma unroll
                for (int i = 0; i < 4; ++i) pk[i] = (f16)fmaxf(a[i] + bv[i], 0.0f);
                int sl = (5 * wo + c8o) ^ ((wo >> 1) & 7);
                *(f16x4*)(h2f + ((size_t)m * 3374 + (size_t)ho * 241 + sl) * 8 + hsel) = pk;
            }
        }

        if (p < 6) {
            #pragma unroll
            for (int i = 0; i < 6; ++i) {
                int u = tid + i * 384;
                if (u < 2072) *(uint4*)((char*)tl[cur ^ 1] + (size_t)u * 16) = stg[i];
            }
        }
        __syncthreads();
    }
}

// ---------------------------------------------------------------------------
// conv3 via MFMA: h3[m][co][ho][wo] = relu(b3 + sum). Block = one image.
// Whole image (54 KB) + weights (97 KB) in LDS. 6 waves = 3 co-subtiles x
// 2 px-tile halves (sh=0: tiles 0-3, sh=1: tiles 4-6 + masked dup).
// K = 1024 = 128 chunks; chunk c -> (kh,kw,c8) with pq = c/5 (pq=25 dummy).
// ---------------------------------------------------------------------------
__global__ __launch_bounds__(384)
void conv3_mfma(const f16* __restrict__ h2f, const f16* __restrict__ Wpk3,
                const float* __restrict__ b3, float* __restrict__ h3)
{
    __shared__ __align__(16) f16 Wl[48 * 1032];    // 99,072 B
    __shared__ __align__(16) f16 img[3374 * 8];    // 53,984 B
    __shared__ u32 lut[128];

    int m    = blockIdx.x;
    int tid  = threadIdx.x;
    int lane = tid & 63;
    int wv   = tid >> 6;        // 0..5
    int ct   = wv >> 1;         // co subtile
    int sh   = wv & 1;
    int row4 = lane >> 4;
    int col  = lane & 15;

    if (tid < 128) {
        int c  = tid;
        int pq = c / 5, c8 = c - 5 * pq;           // pq=25 for pad chunks
        int kh = pq / 5, kw = pq - 5 * kh;         // kh=5,kw=0 for pads (addr safe)
        lut[c] = ((u32)(kh * 3856) << 8) | ((u32)(kw >> 1) << 5) | (u32)(5 * kw + c8);
    }
    for (int u = tid; u < 6192; u += 384)
        *(uint4*)((char*)Wl + (size_t)u * 16) =
            *(const uint4*)((const char*)Wpk3 + (size_t)u * 16);
    {
        const char* g = (const char*)(h2f + (size_t)m * 3374 * 8);
        for (int u = tid; u < 3374; u += 384)
            *(uint4*)((char*)img + (size_t)u * 16) = *(const uint4*)(g + (size_t)u * 16);
    }
    __syncthreads();

    // per-si lane constants (px-tile s = 4*sh + si; sh=1,si=3 is a masked dup)
    int rb[4], wo10[4], wkey[4], valid[4], hov[4], wov[4];
    int nsi = 4 - sh;
    #pragma unroll
    for (int si = 0; si < 4; ++si) {
        int s  = 4 * sh + si;
        int px = 16 * s + col;
        valid[si] = (si < nsi) && (px < 110);
        int pc = px < 110 ? px : 109;
        int ho = pc / 22, wo = pc - 22 * ho;
        rb[si]   = ho * 7712;        // 2*ho * 3856 B (row stride 241*16)
        wo10[si] = 10 * wo;
        wkey[si] = wo;
        hov[si]  = ho; wov[si] = wo;
    }

    float bv[4];
    #pragma unroll
    for (int i = 0; i < 4; ++i) bv[i] = b3[ct * 16 + row4 * 4 + i];

    int Abase = (ct * 16 + col) * 2064 + row4 * 16;
    const char* Wc = (const char*)Wl;
    const char* ic = (const char*)img;

    f32x4 a0 = {0.f,0.f,0.f,0.f}, a1 = {0.f,0.f,0.f,0.f};
    f32x4 a2 = {0.f,0.f,0.f,0.f}, a3 = {0.f,0.f,0.f,0.f};
    #pragma unroll 8
    for (int t = 0; t < 32; ++t) {
        u32 lv     = lut[4 * t + row4];
        int rowoff = (int)(lv >> 8);
        int kwh    = (int)((lv >> 5) & 7);
        int b5     = (int)(lv & 31);
        f16x8 af = *(const f16x8*)(Wc + Abase + 64 * t);
        {
            int u = wo10[0] + b5, k = (wkey[0] + kwh) & 7;
            f16x8 xf = *(const f16x8*)(ic + rb[0] + rowoff + ((u ^ k) << 4));
            a0 = __builtin_amdgcn_mfma_f32_16x16x32_f16(af, xf, a0, 0, 0, 0);
        }
        {
            int u = wo10[1] + b5, k = (wkey[1] + kwh) & 7;
            f16x8 xf = *(const f16x8*)(ic + rb[1] + rowoff + ((u ^ k) << 4));
            a1 = __builtin_amdgcn_mfma_f32_16x16x32_f16(af, xf, a1, 0, 0, 0);
        }
        {
            int u = wo10[2] + b5, k = (wkey[2] + kwh) & 7;
            f16x8 xf = *(const f16x8*)(ic + rb[2] + rowoff + ((u ^ k) << 4));
            a2 = __builtin_amdgcn_mfma_f32_16x16x32_f16(af, xf, a2, 0, 0, 0);
        }
        {
            int u = wo10[3] + b5, k = (wkey[3] + kwh) & 7;
            f16x8 xf = *(const f16x8*)(ic + rb[3] + rowoff + ((u ^ k) << 4));
            a3 = __builtin_amdgcn_mfma_f32_16x16x32_f16(af, xf, a3, 0, 0, 0);
        }
    }

    int co0 = ct * 16 + row4 * 4;
    #pragma unroll
    for (int si = 0; si < 4; ++si) {
        if (!valid[si]) continue;
        f32x4 a = (si == 0) ? a0 : (si == 1) ? a1 : (si == 2) ? a2 : a3;
        float* op = h3 + (((size_t)m * 48 + co0) * 5 + hov[si]) * 22 + wov[si];
        #pragma unroll
        for (int i = 0; i < 4; ++i)
            op[(size_t)i * 110] = fmaxf(a[i] + bv[i], 0.0f);
    }
}

// Register-tiled fp32 direct conv for conv4..conv5.
template<int CIN, int KH, int KW, int STRIDE, int CO_T, int WO_T>
__global__ __launch_bounds__(256)
void conv_tile_kernel(const float* __restrict__ in, const float* __restrict__ wt,
                      const float* __restrict__ bias, float* __restrict__ out,
                      int Cout, int Hin, int Win, int Hout, int Wout,
                      int n_cg, int n_wg, int M)
{
    constexpr int LOAD_W = (WO_T - 1) * STRIDE + KW;

    int bx = blockIdx.x;
    int cg = bx % n_cg;
    int gid = (bx / n_cg) * blockDim.x + threadIdx.x;
    int wg = gid % n_wg;
    int t  = gid / n_wg;
    int ho = t % Hout;
    int m  = t / Hout;
    if (m >= M) return;

    int wo0 = wg * WO_T;
    int co0 = cg * CO_T;

    const float* ip = in + ((size_t)(m * CIN) * Hin + (size_t)ho * STRIDE) * Win
                         + (size_t)wo0 * STRIDE;
    const float* wp = wt + (size_t)co0 * (CIN * KH * KW);

    float acc[CO_T][WO_T];
    #pragma unroll
    for (int c = 0; c < CO_T; ++c) {
        float b = bias[co0 + c];
        #pragma unroll
        for (int q = 0; q < WO_T; ++q) acc[c][q] = b;
    }

    #pragma unroll 1
    for (int ci = 0; ci < CIN; ++ci) {
        #pragma unroll
        for (int kh = 0; kh < KH; ++kh) {
            const float* row = ip + ((size_t)ci * Hin + kh) * Win;
            float xv[LOAD_W];
            #pragma unroll
            for (int l = 0; l < LOAD_W; ++l) xv[l] = row[l];
            const float* wrow = wp + (ci * KH + kh) * KW;
            #pragma unroll
            for (int c = 0; c < CO_T; ++c) {
                #pragma unroll
                for (int kw = 0; kw < KW; ++kw) {
                    float wv = wrow[c * (CIN * KH * KW) + kw];
                    #pragma unroll
                    for (int q = 0; q < WO_T; ++q)
                        acc[c][q] = fmaf(xv[q * STRIDE + kw], wv, acc[c][q]);
                }
            }
        }
    }

    #pragma unroll
    for (int c = 0; c < CO_T; ++c) {
        float* op = out + (((size_t)m * Cout + co0 + c) * Hout + ho) * Wout + wo0;
        #pragma unroll
        for (int q = 0; q < WO_T; ++q) {
            if (wo0 + q < Wout) op[q] = fmaxf(acc[c][q], 0.0f);
        }
    }
}

// FC (1152 -> 128) + relu, 8 frames/block.
__global__ __launch_bounds__(128)
void fc_relu_kernel(const float* __restrict__ h, const float* __restrict__ w,
                    const float* __restrict__ b, float* __restrict__ out)
{
    __shared__ float hs[8 * 1152];
    int f0 = blockIdx.x * 8;
    int j  = threadIdx.x;
    for (int k = j; k < 8 * 1152; k += 128) hs[k] = h[(size_t)f0 * 1152 + k];
    __syncthreads();
    float acc[8];
    float bj = b[j];
    #pragma unroll
    for (int f = 0; f < 8; ++f) acc[f] = bj;
    for (int k = 0; k < 1152; ++k) {
        float wv = w[k * 128 + j];
        #pragma unroll
        for (int f = 0; f < 8; ++f)
            acc[f] = fmaf(hs[f * 1152 + k], wv, acc[f]);
    }
    #pragma unroll
    for (int f = 0; f < 8; ++f)
        out[(size_t)(f0 + f) * 128 + j] = fmaxf(acc[f], 0.0f);
}

// Sensory synapse pre-computation.
__global__ __launch_bounds__(64)
void sensory_kernel(const float* __restrict__ feat,
                    const float* __restrict__ s_mu,
                    const float* __restrict__ s_sigma,
                    const float* __restrict__ s_w,
                    const float* __restrict__ s_erev,
                    float* __restrict__ wnum, float* __restrict__ wden)
{
    __shared__ float y[128];
    int bt = blockIdx.x;
    int n  = threadIdx.x;
    for (int s = n; s < 128; s += 64) y[s] = feat[bt * 128 + s];
    __syncthreads();
    float num = 0.0f, den = 0.0f;
    for (int s = 0; s < 128; ++s) {
        int o = s * 64 + n;
        float a = s_w[o] * sigmoidf_fast((y[s] - s_mu[o]) * s_sigma[o]);
        num = fmaf(a, s_erev[o], num);
        den += a;
    }
    wnum[bt * 64 + n] = num;
    wden[bt * 64 + n] = den;
}

// LTC recurrence: 8 waves/batch, matrix in registers, one barrier per unfold.
__global__ __launch_bounds__(512)
void ltc_wave_kernel(const float* __restrict__ wnum_s,
                     const float* __restrict__ wden_s,
                     const float* __restrict__ mu, const float* __restrict__ sigma,
                     const float* __restrict__ w, const float* __restrict__ erev,
                     const float* __restrict__ gleak, const float* __restrict__ vleak,
                     const float* __restrict__ cm, float* __restrict__ out, int T)
{
    __shared__ float2 pnd[2][8][64];

    int b    = blockIdx.x;
    int tid  = threadIdx.x;
    int lane = tid & 63;
    int p    = tid >> 6;

    float musig[8], nsg[8], wv[8], wev[8];
    #pragma unroll
    for (int ii = 0; ii < 8; ++ii) {
        int o = (8 * p + ii) * 64 + lane;
        float sg = sigma[o];
        musig[ii] = mu[o] * sg;
        nsg[ii]   = -sg;
        float wl  = w[o];
        wv[ii]    = wl;
        wev[ii]   = wl * erev[o];
    }
    float gl   = gleak[lane];
    float glvl = gl * vleak[lane];
    float cmt  = cm[lane] * 6.0f;
    float v    = 0.0f;
    int   buf  = 0;

    for (int t = 0; t < T; ++t) {
        float ns = wnum_s[(b * T + t) * 64 + lane];
        float ds = wden_s[(b * T + t) * 64 + lane];
        #pragma unroll 1
        for (int u = 0; u < 6; ++u) {
            float num = 0.0f, den = 0.0f;
            #pragma unroll
            for (int ii = 0; ii < 8; ++ii) {
                float vi  = __shfl(v, 8 * p + ii);
                float arg = fmaf(vi, nsg[ii], musig[ii]);
                float e   = __expf(arg);
                float s   = __builtin_amdgcn_rcpf(1.0f + e);
                den = fmaf(wv[ii], s, den);
                num = fmaf(wev[ii], s, num);
            }
            pnd[buf][p][lane] = make_float2(num, den);
            __syncthreads();
            float wn = ns, wd = ds;
            #pragma unroll
            for (int q = 0; q < 8; ++q) {
                float2 pq = pnd[buf][q][lane];
                wn += pq.x; wd += pq.y;
            }
            v = (fmaf(cmt, v, glvl) + wn) *
                __builtin_amdgcn_rcpf(cmt + gl + wd + 1e-8f);
            buf ^= 1;
        }
        if (tid < 3) out[(b * T + t) * 3 + tid] = v;
    }
}

// ---------------------------------------------------------------------------
// Launch
// ---------------------------------------------------------------------------
extern "C" void kernel_launch(void* const* d_in, const int* in_sizes, int n_in,
                              void* d_out, int out_size, void* d_ws, size_t ws_size,
                              hipStream_t stream)
{
    (void)in_sizes; (void)n_in; (void)out_size; (void)ws_size;

    const float* x    = (const float*)d_in[0];
    const float* w1   = (const float*)d_in[1];
    const float* b1   = (const float*)d_in[2];
    const float* w2   = (const float*)d_in[3];
    const float* b2   = (const float*)d_in[4];
    const float* w3   = (const float*)d_in[5];
    const float* b3   = (const float*)d_in[6];
    const float* w4   = (const float*)d_in[7];
    const float* b4   = (const float*)d_in[8];
    const float* w5   = (const float*)d_in[9];
    const float* b5   = (const float*)d_in[10];
    const float* fcw  = (const float*)d_in[11];
    const float* fcb  = (const float*)d_in[12];
    const float* smu  = (const float*)d_in[13];
    const float* ssig = (const float*)d_in[14];
    const float* sw   = (const float*)d_in[15];
    const float* serv = (const float*)d_in[16];
    const float* mu   = (const float*)d_in[17];
    const float* sig  = (const float*)d_in[18];
    const float* ww   = (const float*)d_in[19];
    const float* erev = (const float*)d_in[20];
    const float* gl   = (const float*)d_in[21];
    const float* vl   = (const float*)d_in[22];
    const float* cm   = (const float*)d_in[23];
    float* out = (float*)d_out;

    const int BT = 512;

    char* wsB = (char*)d_ws;
    size_t off = 0;
    f16*   h1T  = (f16*)(wsB + off); off += (size_t)512 * 31 * 2368 * 2;   // 75.2 MB
    f16*   Wpk  = (f16*)(wsB + off); off += 65536;
    f16*   h2f  = (f16*)(wsB + off); off += (size_t)512 * 3374 * 16;       // 27.6 MB
    f16*   Wpk3 = (f16*)(wsB + off); off += 48 * 1032 * 2;                 // 99,072 B
    float* h3   = (float*)(wsB + off); off += (size_t)512 * 48 * 5 * 22 * 4;
    float* h4   = (float*)(wsB + off); off += (size_t)512 * 64 * 3 * 20 * 4;
    float* h5   = (float*)(wsB + off); off += (size_t)512 * 64 * 18 * 4;
    float* feat = (float*)(wsB + off); off += (size_t)BT * 128 * 4;
    float* wnum = (float*)(wsB + off); off += (size_t)BT * 64 * 4;
    float* wden = (float*)(wsB + off); off += (size_t)BT * 64 * 4;

    wpack_kernel<<<(48 * 616 + 255) / 256, 256, 0, stream>>>(w2, Wpk);
    wpack3_kernel<<<(48 * 1032 + 255) / 256, 256, 0, stream>>>(w3, Wpk3);
    conv1_kernel<<<(512 * 31 * 49 + 255) / 256, 256, 0, stream>>>(x, w1, b1, h1T);
    conv2_mfma<<<512, 384, 0, stream>>>(h1T, Wpk, b2, h2f);
    conv3_mfma<<<512, 384, 0, stream>>>(h2f, Wpk3, b3, h3);

    // conv4: [512,48,5,22] -> [512,64,3,20]
    {
        int n_cg = 16, n_wg = 5;
        int sp_threads = BT * 3 * n_wg;
        int grid = (sp_threads + 255) / 256 * n_cg;
        conv_tile_kernel<48, 3, 3, 1, 4, 4><<<grid, 256, 0, stream>>>(
            h3, w4, b4, h4, 64, 5, 22, 3, 20, n_cg, n_wg, BT);
    }
    // conv5: -> [512,64,1,18]
    {
        int n_cg = 16, n_wg = 6;
        int sp_threads = BT * 1 * n_wg;
        int grid = (sp_threads + 255) / 256 * n_cg;
        conv_tile_kernel<64, 3, 3, 1, 4, 3><<<grid, 256, 0, stream>>>(
            h4, w5, b5, h5, 64, 3, 20, 1, 18, n_cg, n_wg, BT);
    }
    fc_relu_kernel<<<BT / 8, 128, 0, stream>>>(h5, fcw, fcb, feat);
    sensory_kernel<<<BT, 64, 0, stream>>>(feat, smu, ssig, sw, serv, wnum, wden);
    ltc_wave_kernel<<<32, 512, 0, stream>>>(wnum, wden, mu, sig, ww, erev,
                                            gl, vl, cm, out, 16);
}

// Round 6
// 296.764 us; speedup vs baseline: 13.6005x; 1.2572x over previous
//
#include <hip/hip_runtime.h>
#include <hip/hip_bf16.h>

// ---------------------------------------------------------------------------
// NCP model: conv head + FC + LTC recurrence.
// Round 5: conv1 -> f16 MFMA implicit GEMM (image in LDS, K=(kh,kwp,kws,ci4));
//          FC -> 512 blocks, 8-way split-K, float4 weight loads.
//          conv2/conv3 MFMA, conv4/5 fp32 tile, sensory, ltc as round 4.
// ---------------------------------------------------------------------------

typedef _Float16 f16;
typedef _Float16 f16x8 __attribute__((ext_vector_type(8)));
typedef _Float16 f16x4 __attribute__((ext_vector_type(4)));
typedef float    f32x4 __attribute__((ext_vector_type(4)));
typedef unsigned int u32;

static __device__ __forceinline__ float sigmoidf_fast(float x) {
    return __builtin_amdgcn_rcpf(1.0f + __expf(-x));
}

// ---------------------------------------------------------------------------
// h1T layout: [512][31][296 slots][8 halves] f16; slot = (3*w + c8) ^ ((w>>1)&7).
// h2f layout: [512][14 rows][241 slots][8 halves] f16;
//             slot = (5*wo + c8) ^ ((wo>>1)&7)
// ---------------------------------------------------------------------------

// Weight pack conv1: w1[24,3,5,5] fp32 -> Wpk1[32][136] f16.
// k = p*8 + kws*4 + ci, p = kh*3 + kwp, kw = 2*kwp + kws. Pads zero.
__global__ __launch_bounds__(256)
void wpack1_kernel(const float* __restrict__ w1, f16* __restrict__ Wpk1)
{
    int idx = blockIdx.x * 256 + threadIdx.x;
    if (idx >= 32 * 136) return;
    int co = idx / 136;
    int kk = idx % 136;
    float v = 0.0f;
    if (co < 24 && kk < 120) {
        int p = kk >> 3, jj = kk & 7;
        int kh = p / 3, kwp = p % 3;
        int kws = jj >> 2, ci = jj & 3;
        int kw = 2 * kwp + kws;
        if (kw < 5 && ci < 3)
            v = w1[(((size_t)co * 3 + ci) * 5 + kh) * 5 + kw];
    }
    Wpk1[idx] = (f16)v;
}

// conv1 via MFMA: block = one image. Image staged [66][200][ci4] f16 in LDS
// (105.6 KB), weights [32][136] f16 (8.7 KB). 8 waves x 24 px-tiles.
// B-frag: 16B read at (2ho+kh)*1600 + (wo+kwp)*16. Output -> swizzled h1T.
__global__ __launch_bounds__(512)
void conv1_mfma(const float* __restrict__ x, const f16* __restrict__ Wpk1,
                const float* __restrict__ b1, f16* __restrict__ h1T)
{
    __shared__ __align__(16) f16 img[52800];   // [66][200][4]
    __shared__ __align__(16) f16 Wl[4352];     // [32][136]

    int m    = blockIdx.x;
    int tid  = threadIdx.x;
    int lane = tid & 63;
    int wv   = tid >> 6;        // 0..7
    int col  = lane & 15;
    int row4 = lane >> 4;

    for (int u = tid; u < 544; u += 512)
        *(uint4*)((char*)Wl + (size_t)u * 16) =
            *(const uint4*)((const char*)Wpk1 + (size_t)u * 16);

    // stage image: [ci][hw] fp32 -> [hw][ci4] f16 (ci=3 zero)
    const float* xb = x + (size_t)m * 39600;
    for (int u = tid; u < 13200; u += 512) {
        float a = xb[u], b = xb[13200 + u], c = xb[26400 + u];
        f16x4 pk = { (f16)a, (f16)b, (f16)c, (f16)0.0f };
        *(f16x4*)(&img[(size_t)u * 4]) = pk;
    }
    __syncthreads();

    f16x8 af[2][4];
    #pragma unroll
    for (int Mt = 0; Mt < 2; ++Mt)
        #pragma unroll
        for (int t = 0; t < 4; ++t)
            af[Mt][t] = *(const f16x8*)((const char*)Wl +
                           (Mt * 16 + col) * 272 + t * 64 + row4 * 16);

    int rowB[4], kwpv[4];
    #pragma unroll
    for (int t = 0; t < 4; ++t) {
        int p = 4 * t + row4; if (p > 14) p = 14;   // k>=120 rows are zero
        rowB[t] = (p / 3) * 1600;
        kwpv[t] = (p % 3) * 16;
    }

    float bvv[2][4];
    #pragma unroll
    for (int Mt = 0; Mt < 2; ++Mt)
        #pragma unroll
        for (int i = 0; i < 4; ++i) {
            int co = Mt * 16 + row4 * 4 + i;
            bvv[Mt][i] = (co < 24) ? b1[co] : 0.0f;
        }

    const char* ic = (const char*)img;
    for (int it = 0; it < 24; ++it) {
        int s = wv + it * 8;                 // px tile 0..191
        if (s * 16 >= 3038) continue;
        int px = s * 16 + col;
        bool pv = (px < 3038);
        int pc = pv ? px : 3037;
        int ho = pc / 98;
        int wo = pc - ho * 98;
        int base = ho * 3200 + wo * 16;

        f32x4 a0 = {0.f,0.f,0.f,0.f}, a1 = {0.f,0.f,0.f,0.f};
        #pragma unroll
        for (int t = 0; t < 4; ++t) {
            f16x8 xf = *(const f16x8*)(ic + base + rowB[t] + kwpv[t]);
            a0 = __builtin_amdgcn_mfma_f32_16x16x32_f16(af[0][t], xf, a0, 0, 0, 0);
            a1 = __builtin_amdgcn_mfma_f32_16x16x32_f16(af[1][t], xf, a1, 0, 0, 0);
        }

        if (pv) {
            int key = (wo >> 1) & 7;
            size_t rowbase = ((size_t)m * 31 + ho) * 296;
            int j0 = (row4 & 1) * 4;
            {   // Mt=0: co 0..15, c8 = row4>>1
                int c8 = row4 >> 1;
                f16x4 pk = { (f16)fmaxf(a0[0] + bvv[0][0], 0.0f),
                             (f16)fmaxf(a0[1] + bvv[0][1], 0.0f),
                             (f16)fmaxf(a0[2] + bvv[0][2], 0.0f),
                             (f16)fmaxf(a0[3] + bvv[0][3], 0.0f) };
                int sl = (3 * wo + c8) ^ key;
                *(f16x4*)(h1T + (rowbase + sl) * 8 + j0) = pk;
            }
            if (row4 < 2) {  // Mt=1: co 16..23, c8 = 2
                f16x4 pk = { (f16)fmaxf(a1[0] + bvv[1][0], 0.0f),
                             (f16)fmaxf(a1[1] + bvv[1][1], 0.0f),
                             (f16)fmaxf(a1[2] + bvv[1][2], 0.0f),
                             (f16)fmaxf(a1[3] + bvv[1][3], 0.0f) };
                int sl = (3 * wo + 2) ^ key;
                *(f16x4*)(h1T + (rowbase + sl) * 8 + j0) = pk;
            }
        }
    }
}

// Weight pack conv2: w2[36,24,5,5] fp32 -> Wpk[48][616] f16.
__global__ __launch_bounds__(256)
void wpack_kernel(const float* __restrict__ w2, f16* __restrict__ Wpk)
{
    int idx = blockIdx.x * 256 + threadIdx.x;
    if (idx >= 48 * 616) return;
    int co = idx / 616;
    int kk = idx % 616;
    float v = 0.0f;
    if (kk < 608 && co < 36) {
        int c = kk >> 3, j = kk & 7;
        if (c < 75) {
            int pq = c / 3, c8 = c - 3 * pq;
            int kh = pq / 5, kw = pq - 5 * kh;
            int ci = c8 * 8 + j;
            v = w2[(((size_t)co * 24 + ci) * 5 + kh) * 5 + kw];
        }
    }
    Wpk[idx] = (f16)v;
}

// Weight pack conv3: w3[48,36,5,5] fp32 -> Wpk3[48][1032] f16.
__global__ __launch_bounds__(256)
void wpack3_kernel(const float* __restrict__ w3, f16* __restrict__ Wpk3)
{
    int idx = blockIdx.x * 256 + threadIdx.x;
    if (idx >= 48 * 1032) return;
    int co = idx / 1032;
    int kk = idx % 1032;
    float v = 0.0f;
    if (kk < 1024) {
        int c = kk >> 3, j = kk & 7;
        int pq = c / 5, c8 = c - 5 * pq;
        if (pq < 25) {
            int kh = pq / 5, kw = pq - 5 * kh;
            int ci = c8 * 8 + j;
            if (ci < 36)
                v = w3[(((size_t)co * 36 + ci) * 5 + kh) * 5 + kw];
        }
    }
    Wpk3[idx] = (f16)v;
}

// conv2 via MFMA implicit GEMM. Block = one image, 6 waves, 7 ho-pair steps.
__global__ __launch_bounds__(384)
void conv2_mfma(const f16* __restrict__ h1T, const f16* __restrict__ Wpk,
                const float* __restrict__ b2, f16* __restrict__ h2f)
{
    __shared__ __align__(16) f16 Wl[48 * 616];
    __shared__ __align__(16) f16 tl[2][7 * 2368];
    __shared__ u32 lutS[76];

    int m    = blockIdx.x;
    int tid  = threadIdx.x;
    int lane = tid & 63;
    int wv   = tid >> 6;
    int ct   = wv >> 1;
    int sh   = wv & 1;
    int row4 = lane >> 4;
    int col  = lane & 15;

    if (tid < 76) {
        int c = tid; u32 v = 0;
        if (c < 75) {
            int pq = c / 3, c8 = c - 3 * pq;
            int kh = pq / 5, kw = pq - 5 * kh;
            v = ((u32)(kh * 4736) << 8) | ((u32)(kw >> 1) << 4) | (u32)(3 * kw + c8);
        }
        lutS[c] = v;
    }

    for (int u = tid; u < 3696; u += 384) {
        uint4 v = *(const uint4*)((const char*)Wpk + (size_t)u * 16);
        *(uint4*)((char*)Wl + (size_t)u * 16) = v;
    }

    int six_wo[3], wokey[3], rpoff[3], valid[3];
    #pragma unroll
    for (int si = 0; si < 3; ++si) {
        int s  = 3 * sh + si;
        int px = 16 * s + col;
        int rp = (px >= 48) ? 1 : 0;
        int wo = px - 48 * rp;
        valid[si] = (wo < 47);
        int wog = wo < 47 ? wo : 46;
        six_wo[si] = 6 * wog;
        wokey[si]  = wog;
        rpoff[si]  = rp * 9472;
    }
    int Abase = (ct * 16 + col) * 1232 + row4 * 16;
    float bv[4];
    #pragma unroll
    for (int i = 0; i < 4; ++i) {
        int co = ct * 16 + row4 * 4 + i;
        bv[i] = (co < 36) ? b2[co] : 0.0f;
    }
    int c8o = ct * 2 + (row4 >> 1);
    int hsel = (row4 & 1) * 4;

    uint4 stg[6];
    const f16* imgbase = h1T + (size_t)m * 31 * 2368;

    {
        const char* g = (const char*)(imgbase);
        #pragma unroll
        for (int i = 0; i < 6; ++i) {
            int u = tid + i * 384;
            if (u < 2072) *(uint4*)((char*)tl[0] + (size_t)u * 16) =
                              *(const uint4*)(g + (size_t)u * 16);
        }
    }
    __syncthreads();

    const char* Wc = (const char*)Wl;
    for (int p = 0; p < 7; ++p) {
        int cur = p & 1;
        if (p < 6) {
            const char* g = (const char*)(imgbase + (size_t)(4 * (p + 1)) * 2368);
            #pragma unroll
            for (int i = 0; i < 6; ++i) {
                int u = tid + i * 384;
                if (u < 2072) stg[i] = *(const uint4*)(g + (size_t)u * 16);
            }
        }

        const char* tb = (const char*)tl[cur];
        f32x4 acc0 = {0.f,0.f,0.f,0.f}, acc1 = {0.f,0.f,0.f,0.f}, acc2 = {0.f,0.f,0.f,0.f};
        #pragma unroll
        for (int t = 0; t < 19; ++t) {
            u32 lv   = lutS[4 * t + row4];
            int rowb = (int)(lv >> 8);
            int kwh  = (int)((lv >> 4) & 3);
            int ofs3 = (int)(lv & 15);
            f16x8 af = *(const f16x8*)(Wc + Abase + 64 * t);
            {
                int u0 = six_wo[0] + ofs3, k0 = (wokey[0] + kwh) & 7;
                f16x8 xf = *(const f16x8*)(tb + rpoff[0] + rowb + ((u0 ^ k0) << 4));
                acc0 = __builtin_amdgcn_mfma_f32_16x16x32_f16(af, xf, acc0, 0, 0, 0);
            }
            {
                int u1 = six_wo[1] + ofs3, k1 = (wokey[1] + kwh) & 7;
                f16x8 xf = *(const f16x8*)(tb + rpoff[1] + rowb + ((u1 ^ k1) << 4));
                acc1 = __builtin_amdgcn_mfma_f32_16x16x32_f16(af, xf, acc1, 0, 0, 0);
            }
            {
                int u2 = six_wo[2] + ofs3, k2 = (wokey[2] + kwh) & 7;
                f16x8 xf = *(const f16x8*)(tb + rpoff[2] + rowb + ((u2 ^ k2) << 4));
                acc2 = __builtin_amdgcn_mfma_f32_16x16x32_f16(af, xf, acc2, 0, 0, 0);
            }
        }

        #pragma unroll
        for (int si = 0; si < 3; ++si) {
            f32x4 a = (si == 0) ? acc0 : (si == 1) ? acc1 : acc2;
            int s  = 3 * sh + si;
            int px = 16 * s + col;
            int rp = (px >= 48) ? 1 : 0;
            int wo = px - 48 * rp;
            int ho = 2 * p + rp;
            if (valid[si] && c8o < 5) {
                f16x4 pk;
                #pragma unroll
                for (int i = 0; i < 4; ++i) pk[i] = (f16)fmaxf(a[i] + bv[i], 0.0f);
                int sl = (5 * wo + c8o) ^ ((wo >> 1) & 7);
                *(f16x4*)(h2f + ((size_t)m * 3374 + (size_t)ho * 241 + sl) * 8 + hsel) = pk;
            }
        }

        if (p < 6) {
            #pragma unroll
            for (int i = 0; i < 6; ++i) {
                int u = tid + i * 384;
                if (u < 2072) *(uint4*)((char*)tl[cur ^ 1] + (size_t)u * 16) = stg[i];
            }
        }
        __syncthreads();
    }
}

// conv3 via MFMA: whole image + weights in LDS.
__global__ __launch_bounds__(384)
void conv3_mfma(const f16* __restrict__ h2f, const f16* __restrict__ Wpk3,
                const float* __restrict__ b3, float* __restrict__ h3)
{
    __shared__ __align__(16) f16 Wl[48 * 1032];
    __shared__ __align__(16) f16 img[3374 * 8];
    __shared__ u32 lut[128];

    int m    = blockIdx.x;
    int tid  = threadIdx.x;
    int lane = tid & 63;
    int wv   = tid >> 6;
    int ct   = wv >> 1;
    int sh   = wv & 1;
    int row4 = lane >> 4;
    int col  = lane & 15;

    if (tid < 128) {
        int c  = tid;
        int pq = c / 5, c8 = c - 5 * pq;
        int kh = pq / 5, kw = pq - 5 * kh;
        lut[c] = ((u32)(kh * 3856) << 8) | ((u32)(kw >> 1) << 5) | (u32)(5 * kw + c8);
    }
    for (int u = tid; u < 6192; u += 384)
        *(uint4*)((char*)Wl + (size_t)u * 16) =
            *(const uint4*)((const char*)Wpk3 + (size_t)u * 16);
    {
        const char* g = (const char*)(h2f + (size_t)m * 3374 * 8);
        for (int u = tid; u < 3374; u += 384)
            *(uint4*)((char*)img + (size_t)u * 16) = *(const uint4*)(g + (size_t)u * 16);
    }
    __syncthreads();

    int rb[4], wo10[4], wkey[4], valid[4], hov[4], wov[4];
    int nsi = 4 - sh;
    #pragma unroll
    for (int si = 0; si < 4; ++si) {
        int s  = 4 * sh + si;
        int px = 16 * s + col;
        valid[si] = (si < nsi) && (px < 110);
        int pc = px < 110 ? px : 109;
        int ho = pc / 22, wo = pc - 22 * ho;
        rb[si]   = ho * 7712;
        wo10[si] = 10 * wo;
        wkey[si] = wo;
        hov[si]  = ho; wov[si] = wo;
    }

    float bv[4];
    #pragma unroll
    for (int i = 0; i < 4; ++i) bv[i] = b3[ct * 16 + row4 * 4 + i];

    int Abase = (ct * 16 + col) * 2064 + row4 * 16;
    const char* Wc = (const char*)Wl;
    const char* ic = (const char*)img;

    f32x4 a0 = {0.f,0.f,0.f,0.f}, a1 = {0.f,0.f,0.f,0.f};
    f32x4 a2 = {0.f,0.f,0.f,0.f}, a3 = {0.f,0.f,0.f,0.f};
    #pragma unroll 8
    for (int t = 0; t < 32; ++t) {
        u32 lv     = lut[4 * t + row4];
        int rowoff = (int)(lv >> 8);
        int kwh    = (int)((lv >> 5) & 7);
        int b5     = (int)(lv & 31);
        f16x8 af = *(const f16x8*)(Wc + Abase + 64 * t);
        {
            int u = wo10[0] + b5, k = (wkey[0] + kwh) & 7;
            f16x8 xf = *(const f16x8*)(ic + rb[0] + rowoff + ((u ^ k) << 4));
            a0 = __builtin_amdgcn_mfma_f32_16x16x32_f16(af, xf, a0, 0, 0, 0);
        }
        {
            int u = wo10[1] + b5, k = (wkey[1] + kwh) & 7;
            f16x8 xf = *(const f16x8*)(ic + rb[1] + rowoff + ((u ^ k) << 4));
            a1 = __builtin_amdgcn_mfma_f32_16x16x32_f16(af, xf, a1, 0, 0, 0);
        }
        {
            int u = wo10[2] + b5, k = (wkey[2] + kwh) & 7;
            f16x8 xf = *(const f16x8*)(ic + rb[2] + rowoff + ((u ^ k) << 4));
            a2 = __builtin_amdgcn_mfma_f32_16x16x32_f16(af, xf, a2, 0, 0, 0);
        }
        {
            int u = wo10[3] + b5, k = (wkey[3] + kwh) & 7;
            f16x8 xf = *(const f16x8*)(ic + rb[3] + rowoff + ((u ^ k) << 4));
            a3 = __builtin_amdgcn_mfma_f32_16x16x32_f16(af, xf, a3, 0, 0, 0);
        }
    }

    int co0 = ct * 16 + row4 * 4;
    #pragma unroll
    for (int si = 0; si < 4; ++si) {
        if (!valid[si]) continue;
        f32x4 a = (si == 0) ? a0 : (si == 1) ? a1 : (si == 2) ? a2 : a3;
        float* op = h3 + (((size_t)m * 48 + co0) * 5 + hov[si]) * 22 + wov[si];
        #pragma unroll
        for (int i = 0; i < 4; ++i)
            op[(size_t)i * 110] = fmaxf(a[i] + bv[i], 0.0f);
    }
}

// Register-tiled fp32 direct conv for conv4..conv5.
template<int CIN, int KH, int KW, int STRIDE, int CO_T, int WO_T>
__global__ __launch_bounds__(256)
void conv_tile_kernel(const float* __restrict__ in, const float* __restrict__ wt,
                      const float* __restrict__ bias, float* __restrict__ out,
                      int Cout, int Hin, int Win, int Hout, int Wout,
                      int n_cg, int n_wg, int M)
{
    constexpr int LOAD_W = (WO_T - 1) * STRIDE + KW;

    int bx = blockIdx.x;
    int cg = bx % n_cg;
    int gid = (bx / n_cg) * blockDim.x + threadIdx.x;
    int wg = gid % n_wg;
    int t  = gid / n_wg;
    int ho = t % Hout;
    int m  = t / Hout;
    if (m >= M) return;

    int wo0 = wg * WO_T;
    int co0 = cg * CO_T;

    const float* ip = in + ((size_t)(m * CIN) * Hin + (size_t)ho * STRIDE) * Win
                         + (size_t)wo0 * STRIDE;
    const float* wp = wt + (size_t)co0 * (CIN * KH * KW);

    float acc[CO_T][WO_T];
    #pragma unroll
    for (int c = 0; c < CO_T; ++c) {
        float b = bias[co0 + c];
        #pragma unroll
        for (int q = 0; q < WO_T; ++q) acc[c][q] = b;
    }

    #pragma unroll 1
    for (int ci = 0; ci < CIN; ++ci) {
        #pragma unroll
        for (int kh = 0; kh < KH; ++kh) {
            const float* row = ip + ((size_t)ci * Hin + kh) * Win;
            float xv[LOAD_W];
            #pragma unroll
            for (int l = 0; l < LOAD_W; ++l) xv[l] = row[l];
            const float* wrow = wp + (ci * KH + kh) * KW;
            #pragma unroll
            for (int c = 0; c < CO_T; ++c) {
                #pragma unroll
                for (int kw = 0; kw < KW; ++kw) {
                    float wv = wrow[c * (CIN * KH * KW) + kw];
                    #pragma unroll
                    for (int q = 0; q < WO_T; ++q)
                        acc[c][q] = fmaf(xv[q * STRIDE + kw], wv, acc[c][q]);
                }
            }
        }
    }

    #pragma unroll
    for (int c = 0; c < CO_T; ++c) {
        float* op = out + (((size_t)m * Cout + co0 + c) * Hout + ho) * Wout + wo0;
        #pragma unroll
        for (int q = 0; q < WO_T; ++q) {
            if (wo0 + q < Wout) op[q] = fmaxf(acc[c][q], 0.0f);
        }
    }
}

// FC (1152 -> 128) + relu. One frame per block, 8-way split-K, float4 loads.
__global__ __launch_bounds__(256)
void fc_relu_kernel(const float* __restrict__ h, const float* __restrict__ w,
                    const float* __restrict__ b, float* __restrict__ out)
{
    __shared__ float hs[1152];
    __shared__ float part[8][32][4];
    int f   = blockIdx.x;
    int tid = threadIdx.x;
    int ks  = tid >> 5;          // 0..7
    int j4  = tid & 31;          // output quad
    for (int k = tid; k < 1152; k += 256) hs[k] = h[(size_t)f * 1152 + k];
    __syncthreads();
    const float4* w4 = (const float4*)w;   // [1152][32]
    float4 acc = {0.f, 0.f, 0.f, 0.f};
    int k0 = ks * 144;
    #pragma unroll 4
    for (int kk = 0; kk < 144; ++kk) {
        int k = k0 + kk;
        float4 wv = w4[(size_t)k * 32 + j4];
        float hb = hs[k];
        acc.x = fmaf(wv.x, hb, acc.x);
        acc.y = fmaf(wv.y, hb, acc.y);
        acc.z = fmaf(wv.z, hb, acc.z);
        acc.w = fmaf(wv.w, hb, acc.w);
    }
    *(float4*)&part[ks][j4][0] = acc;
    __syncthreads();
    if (tid < 128) {
        int j = tid, jq = j >> 2, r = j & 3;
        float s = b[j];
        #pragma unroll
        for (int q = 0; q < 8; ++q) s += part[q][jq][r];
        out[(size_t)f * 128 + j] = fmaxf(s, 0.0f);
    }
}

// Sensory synapse pre-computation.
__global__ __launch_bounds__(64)
void sensory_kernel(const float* __restrict__ feat,
                    const float* __restrict__ s_mu,
                    const float* __restrict__ s_sigma,
                    const float* __restrict__ s_w,
                    const float* __restrict__ s_erev,
                    float* __restrict__ wnum, float* __restrict__ wden)
{
    __shared__ float y[128];
    int bt = blockIdx.x;
    int n  = threadIdx.x;
    for (int s = n; s < 128; s += 64) y[s] = feat[bt * 128 + s];
    __syncthreads();
    float num = 0.0f, den = 0.0f;
    for (int s = 0; s < 128; ++s) {
        int o = s * 64 + n;
        float a = s_w[o] * sigmoidf_fast((y[s] - s_mu[o]) * s_sigma[o]);
        num = fmaf(a, s_erev[o], num);
        den += a;
    }
    wnum[bt * 64 + n] = num;
    wden[bt * 64 + n] = den;
}

// LTC recurrence: 8 waves/batch, matrix in registers, one barrier per unfold.
__global__ __launch_bounds__(512)
void ltc_wave_kernel(const float* __restrict__ wnum_s,
                     const float* __restrict__ wden_s,
                     const float* __restrict__ mu, const float* __restrict__ sigma,
                     const float* __restrict__ w, const float* __restrict__ erev,
                     const float* __restrict__ gleak, const float* __restrict__ vleak,
                     const float* __restrict__ cm, float* __restrict__ out, int T)
{
    __shared__ float2 pnd[2][8][64];

    int b    = blockIdx.x;
    int tid  = threadIdx.x;
    int lane = tid & 63;
    int p    = tid >> 6;

    float musig[8], nsg[8], wv[8], wev[8];
    #pragma unroll
    for (int ii = 0; ii < 8; ++ii) {
        int o = (8 * p + ii) * 64 + lane;
        float sg = sigma[o];
        musig[ii] = mu[o] * sg;
        nsg[ii]   = -sg;
        float wl  = w[o];
        wv[ii]    = wl;
        wev[ii]   = wl * erev[o];
    }
    float gl   = gleak[lane];
    float glvl = gl * vleak[lane];
    float cmt  = cm[lane] * 6.0f;
    float v    = 0.0f;
    int   buf  = 0;

    for (int t = 0; t < T; ++t) {
        float ns = wnum_s[(b * T + t) * 64 + lane];
        float ds = wden_s[(b * T + t) * 64 + lane];
        #pragma unroll 1
        for (int u = 0; u < 6; ++u) {
            float num = 0.0f, den = 0.0f;
            #pragma unroll
            for (int ii = 0; ii < 8; ++ii) {
                float vi  = __shfl(v, 8 * p + ii);
                float arg = fmaf(vi, nsg[ii], musig[ii]);
                float e   = __expf(arg);
                float s   = __builtin_amdgcn_rcpf(1.0f + e);
                den = fmaf(wv[ii], s, den);
                num = fmaf(wev[ii], s, num);
            }
            pnd[buf][p][lane] = make_float2(num, den);
            __syncthreads();
            float wn = ns, wd = ds;
            #pragma unroll
            for (int q = 0; q < 8; ++q) {
                float2 pq = pnd[buf][q][lane];
                wn += pq.x; wd += pq.y;
            }
            v = (fmaf(cmt, v, glvl) + wn) *
                __builtin_amdgcn_rcpf(cmt + gl + wd + 1e-8f);
            buf ^= 1;
        }
        if (tid < 3) out[(b * T + t) * 3 + tid] = v;
    }
}

// ---------------------------------------------------------------------------
// Launch
// ---------------------------------------------------------------------------
extern "C" void kernel_launch(void* const* d_in, const int* in_sizes, int n_in,
                              void* d_out, int out_size, void* d_ws, size_t ws_size,
                              hipStream_t stream)
{
    (void)in_sizes; (void)n_in; (void)out_size; (void)ws_size;

    const float* x    = (const float*)d_in[0];
    const float* w1   = (const float*)d_in[1];
    const float* b1   = (const float*)d_in[2];
    const float* w2   = (const float*)d_in[3];
    const float* b2   = (const float*)d_in[4];
    const float* w3   = (const float*)d_in[5];
    const float* b3   = (const float*)d_in[6];
    const float* w4   = (const float*)d_in[7];
    const float* b4   = (const float*)d_in[8];
    const float* w5   = (const float*)d_in[9];
    const float* b5   = (const float*)d_in[10];
    const float* fcw  = (const float*)d_in[11];
    const float* fcb  = (const float*)d_in[12];
    const float* smu  = (const float*)d_in[13];
    const float* ssig = (const float*)d_in[14];
    const float* sw   = (const float*)d_in[15];
    const float* serv = (const float*)d_in[16];
    const float* mu   = (const float*)d_in[17];
    const float* sig  = (const float*)d_in[18];
    const float* ww   = (const float*)d_in[19];
    const float* erev = (const float*)d_in[20];
    const float* gl   = (const float*)d_in[21];
    const float* vl   = (const float*)d_in[22];
    const float* cm   = (const float*)d_in[23];
    float* out = (float*)d_out;

    const int BT = 512;

    char* wsB = (char*)d_ws;
    size_t off = 0;
    f16*   h1T  = (f16*)(wsB + off); off += (size_t)512 * 31 * 2368 * 2;   // 75.2 MB
    f16*   Wpk  = (f16*)(wsB + off); off += 65536;
    f16*   h2f  = (f16*)(wsB + off); off += (size_t)512 * 3374 * 16;       // 27.6 MB
    f16*   Wpk3 = (f16*)(wsB + off); off += 48 * 1032 * 2;
    f16*   Wpk1 = (f16*)(wsB + off); off += 32 * 136 * 2;
    float* h3   = (float*)(wsB + off); off += (size_t)512 * 48 * 5 * 22 * 4;
    float* h4   = (float*)(wsB + off); off += (size_t)512 * 64 * 3 * 20 * 4;
    float* h5   = (float*)(wsB + off); off += (size_t)512 * 64 * 18 * 4;
    float* feat = (float*)(wsB + off); off += (size_t)BT * 128 * 4;
    float* wnum = (float*)(wsB + off); off += (size_t)BT * 64 * 4;
    float* wden = (float*)(wsB + off); off += (size_t)BT * 64 * 4;

    wpack1_kernel<<<(32 * 136 + 255) / 256, 256, 0, stream>>>(w1, Wpk1);
    wpack_kernel<<<(48 * 616 + 255) / 256, 256, 0, stream>>>(w2, Wpk);
    wpack3_kernel<<<(48 * 1032 + 255) / 256, 256, 0, stream>>>(w3, Wpk3);

    conv1_mfma<<<512, 512, 0, stream>>>(x, Wpk1, b1, h1T);
    conv2_mfma<<<512, 384, 0, stream>>>(h1T, Wpk, b2, h2f);
    conv3_mfma<<<512, 384, 0, stream>>>(h2f, Wpk3, b3, h3);

    // conv4: [512,48,5,22] -> [512,64,3,20]
    {
        int n_cg = 16, n_wg = 5;
        int sp_threads = BT * 3 * n_wg;
        int grid = (sp_threads + 255) / 256 * n_cg;
        conv_tile_kernel<48, 3, 3, 1, 4, 4><<<grid, 256, 0, stream>>>(
            h3, w4, b4, h4, 64, 5, 22, 3, 20, n_cg, n_wg, BT);
    }
    // conv5: -> [512,64,1,18]
    {
        int n_cg = 16, n_wg = 6;
        int sp_threads = BT * 1 * n_wg;
        int grid = (sp_threads + 255) / 256 * n_cg;
        conv_tile_kernel<64, 3, 3, 1, 4, 3><<<grid, 256, 0, stream>>>(
            h4, w5, b5, h5, 64, 3, 20, 1, 18, n_cg, n_wg, BT);
    }
    fc_relu_kernel<<<512, 256, 0, stream>>>(h5, fcw, fcb, feat);
    sensory_kernel<<<BT, 64, 0, stream>>>(feat, smu, ssig, sw, serv, wnum, wden);
    ltc_wave_kernel<<<32, 512, 0, stream>>>(wnum, wden, mu, sig, ww, erev,
                                            gl, vl, cm, out, 16);
}

// Round 7
// 286.752 us; speedup vs baseline: 14.0754x; 1.0349x over previous
//
#include <hip/hip_runtime.h>
#include <hip/hip_bf16.h>

// ---------------------------------------------------------------------------
// NCP model: conv head + FC + LTC recurrence.
// Round 6: even/odd-split (parity) chunk layouts for h1T and h2f make all
//          MFMA B-fragment ds_reads conflict-free (lane stride = 1 chunk);
//          conv2 keeps A-fragments in registers (no Wl LDS -> 2 blocks/CU).
// ---------------------------------------------------------------------------

typedef _Float16 f16;
typedef _Float16 f16x8 __attribute__((ext_vector_type(8)));
typedef _Float16 f16x4 __attribute__((ext_vector_type(4)));
typedef float    f32x4 __attribute__((ext_vector_type(4)));
typedef unsigned int u32;

static __device__ __forceinline__ float sigmoidf_fast(float x) {
    return __builtin_amdgcn_rcpf(1.0f + __expf(-x));
}

// ---------------------------------------------------------------------------
// h1T layout: [512][31 rows][296 slots][8 halves] f16 (rows of 98 cols, 3 c8):
//   slot(w,c8) = c8*98 + (w&1)*49 + (w>>1)        (294 used + 2 pad)
// h2f layout: [512][14 rows][241 slots][8 halves] f16 (47 cols, 5 c8):
//   slot(w,c8) = c8*47 + (w&1)*24 + (w>>1)        (235 used + 6 pad)
// For stride-2 convs, fixed (kw,c8) => fixed parity and consecutive wo read
// consecutive slots -> conflict-free ds_read_b128.
// ---------------------------------------------------------------------------

// Weight pack conv1: w1[24,3,5,5] fp32 -> Wpk1[32][136] f16.
// k = p*8 + kws*4 + ci, p = kh*3 + kwp, kw = 2*kwp + kws. Pads zero.
__global__ __launch_bounds__(256)
void wpack1_kernel(const float* __restrict__ w1, f16* __restrict__ Wpk1)
{
    int idx = blockIdx.x * 256 + threadIdx.x;
    if (idx >= 32 * 136) return;
    int co = idx / 136;
    int kk = idx % 136;
    float v = 0.0f;
    if (co < 24 && kk < 120) {
        int p = kk >> 3, jj = kk & 7;
        int kh = p / 3, kwp = p % 3;
        int kws = jj >> 2, ci = jj & 3;
        int kw = 2 * kwp + kws;
        if (kw < 5 && ci < 3)
            v = w1[(((size_t)co * 3 + ci) * 5 + kh) * 5 + kw];
    }
    Wpk1[idx] = (f16)v;
}

// conv1 via MFMA: block = one image. Image staged [66][200][ci4] f16 in LDS.
__global__ __launch_bounds__(512)
void conv1_mfma(const float* __restrict__ x, const f16* __restrict__ Wpk1,
                const float* __restrict__ b1, f16* __restrict__ h1T)
{
    __shared__ __align__(16) f16 img[52800];   // [66][200][4]
    __shared__ __align__(16) f16 Wl[4352];     // [32][136]

    int m    = blockIdx.x;
    int tid  = threadIdx.x;
    int lane = tid & 63;
    int wv   = tid >> 6;        // 0..7
    int col  = lane & 15;
    int row4 = lane >> 4;

    for (int u = tid; u < 544; u += 512)
        *(uint4*)((char*)Wl + (size_t)u * 16) =
            *(const uint4*)((const char*)Wpk1 + (size_t)u * 16);

    const float* xb = x + (size_t)m * 39600;
    for (int u = tid; u < 13200; u += 512) {
        float a = xb[u], b = xb[13200 + u], c = xb[26400 + u];
        f16x4 pk = { (f16)a, (f16)b, (f16)c, (f16)0.0f };
        *(f16x4*)(&img[(size_t)u * 4]) = pk;
    }
    __syncthreads();

    f16x8 af[2][4];
    #pragma unroll
    for (int Mt = 0; Mt < 2; ++Mt)
        #pragma unroll
        for (int t = 0; t < 4; ++t)
            af[Mt][t] = *(const f16x8*)((const char*)Wl +
                           (Mt * 16 + col) * 272 + t * 64 + row4 * 16);

    int rowB[4], kwpv[4];
    #pragma unroll
    for (int t = 0; t < 4; ++t) {
        int p = 4 * t + row4; if (p > 14) p = 14;   // k>=120 rows are zero
        rowB[t] = (p / 3) * 1600;
        kwpv[t] = (p % 3) * 16;
    }

    float bvv[2][4];
    #pragma unroll
    for (int Mt = 0; Mt < 2; ++Mt)
        #pragma unroll
        for (int i = 0; i < 4; ++i) {
            int co = Mt * 16 + row4 * 4 + i;
            bvv[Mt][i] = (co < 24) ? b1[co] : 0.0f;
        }

    const char* ic = (const char*)img;
    for (int it = 0; it < 24; ++it) {
        int s = wv + it * 8;                 // px tile 0..191
        if (s * 16 >= 3038) continue;
        int px = s * 16 + col;
        bool pv = (px < 3038);
        int pc = pv ? px : 3037;
        int ho = pc / 98;
        int wo = pc - ho * 98;
        int base = ho * 3200 + wo * 16;

        f32x4 a0 = {0.f,0.f,0.f,0.f}, a1 = {0.f,0.f,0.f,0.f};
        #pragma unroll
        for (int t = 0; t < 4; ++t) {
            f16x8 xf = *(const f16x8*)(ic + base + rowB[t] + kwpv[t]);
            a0 = __builtin_amdgcn_mfma_f32_16x16x32_f16(af[0][t], xf, a0, 0, 0, 0);
            a1 = __builtin_amdgcn_mfma_f32_16x16x32_f16(af[1][t], xf, a1, 0, 0, 0);
        }

        if (pv) {
            size_t rowbase = ((size_t)m * 31 + ho) * 296;
            int par = (wo & 1) * 49, wh = wo >> 1;
            int j0 = (row4 & 1) * 4;
            {   // Mt=0: co 0..15, c8 = row4>>1
                int c8 = row4 >> 1;
                f16x4 pk = { (f16)fmaxf(a0[0] + bvv[0][0], 0.0f),
                             (f16)fmaxf(a0[1] + bvv[0][1], 0.0f),
                             (f16)fmaxf(a0[2] + bvv[0][2], 0.0f),
                             (f16)fmaxf(a0[3] + bvv[0][3], 0.0f) };
                int sl = c8 * 98 + par + wh;
                *(f16x4*)(h1T + (rowbase + sl) * 8 + j0) = pk;
            }
            if (row4 < 2) {  // Mt=1: co 16..23, c8 = 2
                f16x4 pk = { (f16)fmaxf(a1[0] + bvv[1][0], 0.0f),
                             (f16)fmaxf(a1[1] + bvv[1][1], 0.0f),
                             (f16)fmaxf(a1[2] + bvv[1][2], 0.0f),
                             (f16)fmaxf(a1[3] + bvv[1][3], 0.0f) };
                int sl = 2 * 98 + par + wh;
                *(f16x4*)(h1T + (rowbase + sl) * 8 + j0) = pk;
            }
        }
    }
}

// Weight pack conv2: w2[36,24,5,5] fp32 -> Wpk[48][616] f16.
__global__ __launch_bounds__(256)
void wpack_kernel(const float* __restrict__ w2, f16* __restrict__ Wpk)
{
    int idx = blockIdx.x * 256 + threadIdx.x;
    if (idx >= 48 * 616) return;
    int co = idx / 616;
    int kk = idx % 616;
    float v = 0.0f;
    if (kk < 608 && co < 36) {
        int c = kk >> 3, j = kk & 7;
        if (c < 75) {
            int pq = c / 3, c8 = c - 3 * pq;
            int kh = pq / 5, kw = pq - 5 * kh;
            int ci = c8 * 8 + j;
            v = w2[(((size_t)co * 24 + ci) * 5 + kh) * 5 + kw];
        }
    }
    Wpk[idx] = (f16)v;
}

// Weight pack conv3: w3[48,36,5,5] fp32 -> Wpk3[48][1032] f16.
__global__ __launch_bounds__(256)
void wpack3_kernel(const float* __restrict__ w3, f16* __restrict__ Wpk3)
{
    int idx = blockIdx.x * 256 + threadIdx.x;
    if (idx >= 48 * 1032) return;
    int co = idx / 1032;
    int kk = idx % 1032;
    float v = 0.0f;
    if (kk < 1024) {
        int c = kk >> 3, j = kk & 7;
        int pq = c / 5, c8 = c - 5 * pq;
        if (pq < 25) {
            int kh = pq / 5, kw = pq - 5 * kh;
            int ci = c8 * 8 + j;
            if (ci < 36)
                v = w3[(((size_t)co * 36 + ci) * 5 + kh) * 5 + kw];
        }
    }
    Wpk3[idx] = (f16)v;
}

// conv2 via MFMA implicit GEMM. Block = one image, 6 waves, 7 ho-pair steps.
// A-fragments in registers (19 x f16x8, from L2-hot global); B reads
// conflict-free via parity layout. LDS = tile double-buffer only (66.6 KB).
__global__ __launch_bounds__(384, 3)
void conv2_mfma(const f16* __restrict__ h1T, const f16* __restrict__ Wpk,
                const float* __restrict__ b2, f16* __restrict__ h2f)
{
    __shared__ __align__(16) f16 tl[2][7 * 2368];   // 2 x 33,152 B
    __shared__ u32 lutS[76];

    int m    = blockIdx.x;
    int tid  = threadIdx.x;
    int lane = tid & 63;
    int wv   = tid >> 6;
    int ct   = wv >> 1;
    int sh   = wv & 1;
    int row4 = lane >> 4;
    int col  = lane & 15;

    // lut: chunk c -> {kh*4736 (tile-row bytes), base slot offset}
    if (tid < 76) {
        int c = tid; u32 v = 0;
        if (c < 75) {
            int pq = c / 3, c8 = c - 3 * pq;
            int kh = pq / 5, kw = pq - 5 * kh;
            u32 ofs = (u32)(c8 * 98 + (kw & 1) * 49 + (kw >> 1));
            v = ((u32)(kh * 4736) << 8) | ofs;
        }
        lutS[c] = v;
    }

    // A-fragments -> registers (rows k zero-padded in Wpk handle M/K pads)
    f16x8 af[19];
    {
        const char* wb = (const char*)Wpk + (size_t)(ct * 16 + col) * 1232 + row4 * 16;
        #pragma unroll
        for (int t = 0; t < 19; ++t)
            af[t] = *(const f16x8*)(wb + t * 64);
    }

    int wo16[3], rpoff[3], valid[3], wov[3];
    #pragma unroll
    for (int si = 0; si < 3; ++si) {
        int s  = 3 * sh + si;
        int px = 16 * s + col;
        int rp = (px >= 48) ? 1 : 0;
        int wo = px - 48 * rp;
        valid[si] = (wo < 47);
        int wog = wo < 47 ? wo : 46;   // clamp pad lane (same-addr broadcast ok)
        wo16[si]  = wog * 16;
        wov[si]   = wo;
        rpoff[si] = rp * 9472;         // 2 rows * 4736 B
    }
    float bv[4];
    #pragma unroll
    for (int i = 0; i < 4; ++i) {
        int co = ct * 16 + row4 * 4 + i;
        bv[i] = (co < 36) ? b2[co] : 0.0f;
    }
    int c8o  = ct * 2 + (row4 >> 1);   // output chunk (0..5; 5 unused)
    int hsel = (row4 & 1) * 4;

    uint4 stg[6];
    const f16* imgbase = h1T + (size_t)m * 31 * 2368;

    {
        const char* g = (const char*)(imgbase);
        #pragma unroll
        for (int i = 0; i < 6; ++i) {
            int u = tid + i * 384;
            if (u < 2072) *(uint4*)((char*)tl[0] + (size_t)u * 16) =
                              *(const uint4*)(g + (size_t)u * 16);
        }
    }
    __syncthreads();

    for (int p = 0; p < 7; ++p) {
        int cur = p & 1;
        if (p < 6) {
            const char* g = (const char*)(imgbase + (size_t)(4 * (p + 1)) * 2368);
            #pragma unroll
            for (int i = 0; i < 6; ++i) {
                int u = tid + i * 384;
                if (u < 2072) stg[i] = *(const uint4*)(g + (size_t)u * 16);
            }
        }

        const char* tb = (const char*)tl[cur];
        f32x4 acc0 = {0.f,0.f,0.f,0.f}, acc1 = {0.f,0.f,0.f,0.f}, acc2 = {0.f,0.f,0.f,0.f};
        #pragma unroll
        for (int t = 0; t < 19; ++t) {
            u32 lv   = lutS[4 * t + row4];
            int rowb = (int)(lv >> 8);
            int boff = (int)(lv & 255) << 4;
            f16x8 a = af[t];
            {
                f16x8 xf = *(const f16x8*)(tb + rpoff[0] + rowb + boff + wo16[0]);
                acc0 = __builtin_amdgcn_mfma_f32_16x16x32_f16(a, xf, acc0, 0, 0, 0);
            }
            {
                f16x8 xf = *(const f16x8*)(tb + rpoff[1] + rowb + boff + wo16[1]);
                acc1 = __builtin_amdgcn_mfma_f32_16x16x32_f16(a, xf, acc1, 0, 0, 0);
            }
            {
                f16x8 xf = *(const f16x8*)(tb + rpoff[2] + rowb + boff + wo16[2]);
                acc2 = __builtin_amdgcn_mfma_f32_16x16x32_f16(a, xf, acc2, 0, 0, 0);
            }
        }

        // epilogue: pack 4 co values -> one f16x4 chunk-half of h2f (parity slot)
        #pragma unroll
        for (int si = 0; si < 3; ++si) {
            f32x4 a = (si == 0) ? acc0 : (si == 1) ? acc1 : acc2;
            int s  = 3 * sh + si;
            int px = 16 * s + col;
            int rp = (px >= 48) ? 1 : 0;
            int wo = px - 48 * rp;
            int ho = 2 * p + rp;
            if (valid[si] && c8o < 5) {
                f16x4 pk;
                #pragma unroll
                for (int i = 0; i < 4; ++i) pk[i] = (f16)fmaxf(a[i] + bv[i], 0.0f);
                int sl = c8o * 47 + (wo & 1) * 24 + (wo >> 1);
                *(f16x4*)(h2f + ((size_t)m * 3374 + (size_t)ho * 241 + sl) * 8 + hsel) = pk;
            }
        }

        if (p < 6) {
            #pragma unroll
            for (int i = 0; i < 6; ++i) {
                int u = tid + i * 384;
                if (u < 2072) *(uint4*)((char*)tl[cur ^ 1] + (size_t)u * 16) = stg[i];
            }
        }
        __syncthreads();
    }
}

// conv3 via MFMA: whole image + weights in LDS. B reads conflict-free via
// parity layout (no XOR); A reads already conflict-free (odd chunk stride).
__global__ __launch_bounds__(384)
void conv3_mfma(const f16* __restrict__ h2f, const f16* __restrict__ Wpk3,
                const float* __restrict__ b3, float* __restrict__ h3)
{
    __shared__ __align__(16) f16 Wl[48 * 1032];
    __shared__ __align__(16) f16 img[3374 * 8];
    __shared__ u32 lut[128];

    int m    = blockIdx.x;
    int tid  = threadIdx.x;
    int lane = tid & 63;
    int wv   = tid >> 6;
    int ct   = wv >> 1;
    int sh   = wv & 1;
    int row4 = lane >> 4;
    int col  = lane & 15;

    if (tid < 128) {
        int c  = tid;
        int pq = c / 5, c8 = c - 5 * pq;           // pq=25 pad (addr stays in-bounds)
        int kh = pq / 5, kw = pq - 5 * kh;
        lut[c] = ((u32)(kh * 3856) << 8) |
                 (u32)(c8 * 47 + (kw & 1) * 24 + (kw >> 1));
    }
    for (int u = tid; u < 6192; u += 384)
        *(uint4*)((char*)Wl + (size_t)u * 16) =
            *(const uint4*)((const char*)Wpk3 + (size_t)u * 16);
    {
        const char* g = (const char*)(h2f + (size_t)m * 3374 * 8);
        for (int u = tid; u < 3374; u += 384)
            *(uint4*)((char*)img + (size_t)u * 16) = *(const uint4*)(g + (size_t)u * 16);
    }
    __syncthreads();

    int rb[4], wo16[4], valid[4], hov[4], wov[4];
    int nsi = 4 - sh;
    #pragma unroll
    for (int si = 0; si < 4; ++si) {
        int s  = 4 * sh + si;
        int px = 16 * s + col;
        valid[si] = (si < nsi) && (px < 110);
        int pc = px < 110 ? px : 109;
        int ho = pc / 22, wo = pc - 22 * ho;
        rb[si]   = ho * 7712;        // 2*ho rows * 3856 B
        wo16[si] = wo * 16;
        hov[si]  = ho; wov[si] = wo;
    }

    float bv[4];
    #pragma unroll
    for (int i = 0; i < 4; ++i) bv[i] = b3[ct * 16 + row4 * 4 + i];

    int Abase = (ct * 16 + col) * 2064 + row4 * 16;
    const char* Wc = (const char*)Wl;
    const char* ic = (const char*)img;

    f32x4 a0 = {0.f,0.f,0.f,0.f}, a1 = {0.f,0.f,0.f,0.f};
    f32x4 a2 = {0.f,0.f,0.f,0.f}, a3 = {0.f,0.f,0.f,0.f};
    #pragma unroll 8
    for (int t = 0; t < 32; ++t) {
        u32 lv     = lut[4 * t + row4];
        int rowoff = (int)(lv >> 8);
        int boff   = (int)(lv & 255) << 4;
        f16x8 af = *(const f16x8*)(Wc + Abase + 64 * t);
        {
            f16x8 xf = *(const f16x8*)(ic + rb[0] + rowoff + boff + wo16[0]);
            a0 = __builtin_amdgcn_mfma_f32_16x16x32_f16(af, xf, a0, 0, 0, 0);
        }
        {
            f16x8 xf = *(const f16x8*)(ic + rb[1] + rowoff + boff + wo16[1]);
            a1 = __builtin_amdgcn_mfma_f32_16x16x32_f16(af, xf, a1, 0, 0, 0);
        }
        {
            f16x8 xf = *(const f16x8*)(ic + rb[2] + rowoff + boff + wo16[2]);
            a2 = __builtin_amdgcn_mfma_f32_16x16x32_f16(af, xf, a2, 0, 0, 0);
        }
        {
            f16x8 xf = *(const f16x8*)(ic + rb[3] + rowoff + boff + wo16[3]);
            a3 = __builtin_amdgcn_mfma_f32_16x16x32_f16(af, xf, a3, 0, 0, 0);
        }
    }

    int co0 = ct * 16 + row4 * 4;
    #pragma unroll
    for (int si = 0; si < 4; ++si) {
        if (!valid[si]) continue;
        f32x4 a = (si == 0) ? a0 : (si == 1) ? a1 : (si == 2) ? a2 : a3;
        float* op = h3 + (((size_t)m * 48 + co0) * 5 + hov[si]) * 22 + wov[si];
        #pragma unroll
        for (int i = 0; i < 4; ++i)
            op[(size_t)i * 110] = fmaxf(a[i] + bv[i], 0.0f);
    }
}

// Register-tiled fp32 direct conv for conv4..conv5.
template<int CIN, int KH, int KW, int STRIDE, int CO_T, int WO_T>
__global__ __launch_bounds__(256)
void conv_tile_kernel(const float* __restrict__ in, const float* __restrict__ wt,
                      const float* __restrict__ bias, float* __restrict__ out,
                      int Cout, int Hin, int Win, int Hout, int Wout,
                      int n_cg, int n_wg, int M)
{
    constexpr int LOAD_W = (WO_T - 1) * STRIDE + KW;

    int bx = blockIdx.x;
    int cg = bx % n_cg;
    int gid = (bx / n_cg) * blockDim.x + threadIdx.x;
    int wg = gid % n_wg;
    int t  = gid / n_wg;
    int ho = t % Hout;
    int m  = t / Hout;
    if (m >= M) return;

    int wo0 = wg * WO_T;
    int co0 = cg * CO_T;

    const float* ip = in + ((size_t)(m * CIN) * Hin + (size_t)ho * STRIDE) * Win
                         + (size_t)wo0 * STRIDE;
    const float* wp = wt + (size_t)co0 * (CIN * KH * KW);

    float acc[CO_T][WO_T];
    #pragma unroll
    for (int c = 0; c < CO_T; ++c) {
        float b = bias[co0 + c];
        #pragma unroll
        for (int q = 0; q < WO_T; ++q) acc[c][q] = b;
    }

    #pragma unroll 1
    for (int ci = 0; ci < CIN; ++ci) {
        #pragma unroll
        for (int kh = 0; kh < KH; ++kh) {
            const float* row = ip + ((size_t)ci * Hin + kh) * Win;
            float xv[LOAD_W];
            #pragma unroll
            for (int l = 0; l < LOAD_W; ++l) xv[l] = row[l];
            const float* wrow = wp + (ci * KH + kh) * KW;
            #pragma unroll
            for (int c = 0; c < CO_T; ++c) {
                #pragma unroll
                for (int kw = 0; kw < KW; ++kw) {
                    float wv = wrow[c * (CIN * KH * KW) + kw];
                    #pragma unroll
                    for (int q = 0; q < WO_T; ++q)
                        acc[c][q] = fmaf(xv[q * STRIDE + kw], wv, acc[c][q]);
                }
            }
        }
    }

    #pragma unroll
    for (int c = 0; c < CO_T; ++c) {
        float* op = out + (((size_t)m * Cout + co0 + c) * Hout + ho) * Wout + wo0;
        #pragma unroll
        for (int q = 0; q < WO_T; ++q) {
            if (wo0 + q < Wout) op[q] = fmaxf(acc[c][q], 0.0f);
        }
    }
}

// FC (1152 -> 128) + relu. One frame per block, 8-way split-K, float4 loads.
__global__ __launch_bounds__(256)
void fc_relu_kernel(const float* __restrict__ h, const float* __restrict__ w,
                    const float* __restrict__ b, float* __restrict__ out)
{
    __shared__ float hs[1152];
    __shared__ float part[8][32][4];
    int f   = blockIdx.x;
    int tid = threadIdx.x;
    int ks  = tid >> 5;
    int j4  = tid & 31;
    for (int k = tid; k < 1152; k += 256) hs[k] = h[(size_t)f * 1152 + k];
    __syncthreads();
    const float4* w4 = (const float4*)w;
    float4 acc = {0.f, 0.f, 0.f, 0.f};
    int k0 = ks * 144;
    #pragma unroll 4
    for (int kk = 0; kk < 144; ++kk) {
        int k = k0 + kk;
        float4 wv = w4[(size_t)k * 32 + j4];
        float hb = hs[k];
        acc.x = fmaf(wv.x, hb, acc.x);
        acc.y = fmaf(wv.y, hb, acc.y);
        acc.z = fmaf(wv.z, hb, acc.z);
        acc.w = fmaf(wv.w, hb, acc.w);
    }
    *(float4*)&part[ks][j4][0] = acc;
    __syncthreads();
    if (tid < 128) {
        int j = tid, jq = j >> 2, r = j & 3;
        float s = b[j];
        #pragma unroll
        for (int q = 0; q < 8; ++q) s += part[q][jq][r];
        out[(size_t)f * 128 + j] = fmaxf(s, 0.0f);
    }
}

// Sensory synapse pre-computation.
__global__ __launch_bounds__(64)
void sensory_kernel(const float* __restrict__ feat,
                    const float* __restrict__ s_mu,
                    const float* __restrict__ s_sigma,
                    const float* __restrict__ s_w,
                    const float* __restrict__ s_erev,
                    float* __restrict__ wnum, float* __restrict__ wden)
{
    __shared__ float y[128];
    int bt = blockIdx.x;
    int n  = threadIdx.x;
    for (int s = n; s < 128; s += 64) y[s] = feat[bt * 128 + s];
    __syncthreads();
    float num = 0.0f, den = 0.0f;
    for (int s = 0; s < 128; ++s) {
        int o = s * 64 + n;
        float a = s_w[o] * sigmoidf_fast((y[s] - s_mu[o]) * s_sigma[o]);
        num = fmaf(a, s_erev[o], num);
        den += a;
    }
    wnum[bt * 64 + n] = num;
    wden[bt * 64 + n] = den;
}

// LTC recurrence: 8 waves/batch, matrix in registers, one barrier per unfold.
__global__ __launch_bounds__(512)
void ltc_wave_kernel(const float* __restrict__ wnum_s,
                     const float* __restrict__ wden_s,
                     const float* __restrict__ mu, const float* __restrict__ sigma,
                     const float* __restrict__ w, const float* __restrict__ erev,
                     const float* __restrict__ gleak, const float* __restrict__ vleak,
                     const float* __restrict__ cm, float* __restrict__ out, int T)
{
    __shared__ float2 pnd[2][8][64];

    int b    = blockIdx.x;
    int tid  = threadIdx.x;
    int lane = tid & 63;
    int p    = tid >> 6;

    float musig[8], nsg[8], wv[8], wev[8];
    #pragma unroll
    for (int ii = 0; ii < 8; ++ii) {
        int o = (8 * p + ii) * 64 + lane;
        float sg = sigma[o];
        musig[ii] = mu[o] * sg;
        nsg[ii]   = -sg;
        float wl  = w[o];
        wv[ii]    = wl;
        wev[ii]   = wl * erev[o];
    }
    float gl   = gleak[lane];
    float glvl = gl * vleak[lane];
    float cmt  = cm[lane] * 6.0f;
    float v    = 0.0f;
    int   buf  = 0;

    for (int t = 0; t < T; ++t) {
        float ns = wnum_s[(b * T + t) * 64 + lane];
        float ds = wden_s[(b * T + t) * 64 + lane];
        #pragma unroll 1
        for (int u = 0; u < 6; ++u) {
            float num = 0.0f, den = 0.0f;
            #pragma unroll
            for (int ii = 0; ii < 8; ++ii) {
                float vi  = __shfl(v, 8 * p + ii);
                float arg = fmaf(vi, nsg[ii], musig[ii]);
                float e   = __expf(arg);
                float s   = __builtin_amdgcn_rcpf(1.0f + e);
                den = fmaf(wv[ii], s, den);
                num = fmaf(wev[ii], s, num);
            }
            pnd[buf][p][lane] = make_float2(num, den);
            __syncthreads();
            float wn = ns, wd = ds;
            #pragma unroll
            for (int q = 0; q < 8; ++q) {
                float2 pq = pnd[buf][q][lane];
                wn += pq.x; wd += pq.y;
            }
            v = (fmaf(cmt, v, glvl) + wn) *
                __builtin_amdgcn_rcpf(cmt + gl + wd + 1e-8f);
            buf ^= 1;
        }
        if (tid < 3) out[(b * T + t) * 3 + tid] = v;
    }
}

// ---------------------------------------------------------------------------
// Launch
// ---------------------------------------------------------------------------
extern "C" void kernel_launch(void* const* d_in, const int* in_sizes, int n_in,
                              void* d_out, int out_size, void* d_ws, size_t ws_size,
                              hipStream_t stream)
{
    (void)in_sizes; (void)n_in; (void)out_size; (void)ws_size;

    const float* x    = (const float*)d_in[0];
    const float* w1   = (const float*)d_in[1];
    const float* b1   = (const float*)d_in[2];
    const float* w2   = (const float*)d_in[3];
    const float* b2   = (const float*)d_in[4];
    const float* w3   = (const float*)d_in[5];
    const float* b3   = (const float*)d_in[6];
    const float* w4   = (const float*)d_in[7];
    const float* b4   = (const float*)d_in[8];
    const float* w5   = (const float*)d_in[9];
    const float* b5   = (const float*)d_in[10];
    const float* fcw  = (const float*)d_in[11];
    const float* fcb  = (const float*)d_in[12];
    const float* smu  = (const float*)d_in[13];
    const float* ssig = (const float*)d_in[14];
    const float* sw   = (const float*)d_in[15];
    const float* serv = (const float*)d_in[16];
    const float* mu   = (const float*)d_in[17];
    const float* sig  = (const float*)d_in[18];
    const float* ww   = (const float*)d_in[19];
    const float* erev = (const float*)d_in[20];
    const float* gl   = (const float*)d_in[21];
    const float* vl   = (const float*)d_in[22];
    const float* cm   = (const float*)d_in[23];
    float* out = (float*)d_out;

    const int BT = 512;

    char* wsB = (char*)d_ws;
    size_t off = 0;
    f16*   h1T  = (f16*)(wsB + off); off += (size_t)512 * 31 * 2368 * 2;   // 75.2 MB
    f16*   Wpk  = (f16*)(wsB + off); off += 65536;
    f16*   h2f  = (f16*)(wsB + off); off += (size_t)512 * 3374 * 16;       // 27.6 MB
    f16*   Wpk3 = (f16*)(wsB + off); off += 48 * 1032 * 2;
    f16*   Wpk1 = (f16*)(wsB + off); off += 32 * 136 * 2;
    float* h3   = (float*)(wsB + off); off += (size_t)512 * 48 * 5 * 22 * 4;
    float* h4   = (float*)(wsB + off); off += (size_t)512 * 64 * 3 * 20 * 4;
    float* h5   = (float*)(wsB + off); off += (size_t)512 * 64 * 18 * 4;
    float* feat = (float*)(wsB + off); off += (size_t)BT * 128 * 4;
    float* wnum = (float*)(wsB + off); off += (size_t)BT * 64 * 4;
    float* wden = (float*)(wsB + off); off += (size_t)BT * 64 * 4;

    wpack1_kernel<<<(32 * 136 + 255) / 256, 256, 0, stream>>>(w1, Wpk1);
    wpack_kernel<<<(48 * 616 + 255) / 256, 256, 0, stream>>>(w2, Wpk);
    wpack3_kernel<<<(48 * 1032 + 255) / 256, 256, 0, stream>>>(w3, Wpk3);

    conv1_mfma<<<512, 512, 0, stream>>>(x, Wpk1, b1, h1T);
    conv2_mfma<<<512, 384, 0, stream>>>(h1T, Wpk, b2, h2f);
    conv3_mfma<<<512, 384, 0, stream>>>(h2f, Wpk3, b3, h3);

    // conv4: [512,48,5,22] -> [512,64,3,20]
    {
        int n_cg = 16, n_wg = 5;
        int sp_threads = BT * 3 * n_wg;
        int grid = (sp_threads + 255) / 256 * n_cg;
        conv_tile_kernel<48, 3, 3, 1, 4, 4><<<grid, 256, 0, stream>>>(
            h3, w4, b4, h4, 64, 5, 22, 3, 20, n_cg, n_wg, BT);
    }
    // conv5: -> [512,64,1,18]
    {
        int n_cg = 16, n_wg = 6;
        int sp_threads = BT * 1 * n_wg;
        int grid = (sp_threads + 255) / 256 * n_cg;
        conv_tile_kernel<64, 3, 3, 1, 4, 3><<<grid, 256, 0, stream>>>(
            h4, w5, b5, h5, 64, 3, 20, 1, 18, n_cg, n_wg, BT);
    }
    fc_relu_kernel<<<512, 256, 0, stream>>>(h5, fcw, fcb, feat);
    sensory_kernel<<<BT, 64, 0, stream>>>(feat, smu, ssig, sw, serv, wnum, wden);
    ltc_wave_kernel<<<32, 512, 0, stream>>>(wnum, wden, mu, sig, ww, erev,
                                            gl, vl, cm, out, 16);
}

// Round 8
// 268.538 us; speedup vs baseline: 15.0300x; 1.0678x over previous
//
#include <hip/hip_runtime.h>
#include <hip/hip_bf16.h>

// ---------------------------------------------------------------------------
// NCP model: conv head + FC + LTC recurrence.
// Round 7: conv2 restructured to whole-image LDS staging (146.8 KB, one
//          barrier, burst loads) — R6 showed it was HBM-latency-bound on its
//          7-stage pipeline (554 GB/s, MfmaUtil 10%). Flattened px tiling:
//          6 waves x 7 iters x 3 chains over 42 tiles of 16 px.
//          Everything else unchanged from round 6.
// ---------------------------------------------------------------------------

typedef _Float16 f16;
typedef _Float16 f16x8 __attribute__((ext_vector_type(8)));
typedef _Float16 f16x4 __attribute__((ext_vector_type(4)));
typedef float    f32x4 __attribute__((ext_vector_type(4)));
typedef unsigned int u32;

static __device__ __forceinline__ float sigmoidf_fast(float x) {
    return __builtin_amdgcn_rcpf(1.0f + __expf(-x));
}

// ---------------------------------------------------------------------------
// h1T layout: [512][31 rows][296 slots][8 halves] f16 (rows of 98 cols, 3 c8):
//   slot(w,c8) = c8*98 + (w&1)*49 + (w>>1)
// h2f layout: [512][14 rows][241 slots][8 halves] f16 (47 cols, 5 c8):
//   slot(w,c8) = c8*47 + (w&1)*24 + (w>>1)
// ---------------------------------------------------------------------------

// Weight pack conv1: w1[24,3,5,5] fp32 -> Wpk1[32][136] f16.
__global__ __launch_bounds__(256)
void wpack1_kernel(const float* __restrict__ w1, f16* __restrict__ Wpk1)
{
    int idx = blockIdx.x * 256 + threadIdx.x;
    if (idx >= 32 * 136) return;
    int co = idx / 136;
    int kk = idx % 136;
    float v = 0.0f;
    if (co < 24 && kk < 120) {
        int p = kk >> 3, jj = kk & 7;
        int kh = p / 3, kwp = p % 3;
        int kws = jj >> 2, ci = jj & 3;
        int kw = 2 * kwp + kws;
        if (kw < 5 && ci < 3)
            v = w1[(((size_t)co * 3 + ci) * 5 + kh) * 5 + kw];
    }
    Wpk1[idx] = (f16)v;
}

// conv1 via MFMA: block = one image. Image staged [66][200][ci4] f16 in LDS.
__global__ __launch_bounds__(512)
void conv1_mfma(const float* __restrict__ x, const f16* __restrict__ Wpk1,
                const float* __restrict__ b1, f16* __restrict__ h1T)
{
    __shared__ __align__(16) f16 img[52800];   // [66][200][4]
    __shared__ __align__(16) f16 Wl[4352];     // [32][136]

    int m    = blockIdx.x;
    int tid  = threadIdx.x;
    int lane = tid & 63;
    int wv   = tid >> 6;        // 0..7
    int col  = lane & 15;
    int row4 = lane >> 4;

    for (int u = tid; u < 544; u += 512)
        *(uint4*)((char*)Wl + (size_t)u * 16) =
            *(const uint4*)((const char*)Wpk1 + (size_t)u * 16);

    const float* xb = x + (size_t)m * 39600;
    for (int u = tid; u < 13200; u += 512) {
        float a = xb[u], b = xb[13200 + u], c = xb[26400 + u];
        f16x4 pk = { (f16)a, (f16)b, (f16)c, (f16)0.0f };
        *(f16x4*)(&img[(size_t)u * 4]) = pk;
    }
    __syncthreads();

    f16x8 af[2][4];
    #pragma unroll
    for (int Mt = 0; Mt < 2; ++Mt)
        #pragma unroll
        for (int t = 0; t < 4; ++t)
            af[Mt][t] = *(const f16x8*)((const char*)Wl +
                           (Mt * 16 + col) * 272 + t * 64 + row4 * 16);

    int rowB[4], kwpv[4];
    #pragma unroll
    for (int t = 0; t < 4; ++t) {
        int p = 4 * t + row4; if (p > 14) p = 14;   // k>=120 rows are zero
        rowB[t] = (p / 3) * 1600;
        kwpv[t] = (p % 3) * 16;
    }

    float bvv[2][4];
    #pragma unroll
    for (int Mt = 0; Mt < 2; ++Mt)
        #pragma unroll
        for (int i = 0; i < 4; ++i) {
            int co = Mt * 16 + row4 * 4 + i;
            bvv[Mt][i] = (co < 24) ? b1[co] : 0.0f;
        }

    const char* ic = (const char*)img;
    for (int it = 0; it < 24; ++it) {
        int s = wv + it * 8;                 // px tile 0..191
        if (s * 16 >= 3038) continue;
        int px = s * 16 + col;
        bool pv = (px < 3038);
        int pc = pv ? px : 3037;
        int ho = pc / 98;
        int wo = pc - ho * 98;
        int base = ho * 3200 + wo * 16;

        f32x4 a0 = {0.f,0.f,0.f,0.f}, a1 = {0.f,0.f,0.f,0.f};
        #pragma unroll
        for (int t = 0; t < 4; ++t) {
            f16x8 xf = *(const f16x8*)(ic + base + rowB[t] + kwpv[t]);
            a0 = __builtin_amdgcn_mfma_f32_16x16x32_f16(af[0][t], xf, a0, 0, 0, 0);
            a1 = __builtin_amdgcn_mfma_f32_16x16x32_f16(af[1][t], xf, a1, 0, 0, 0);
        }

        if (pv) {
            size_t rowbase = ((size_t)m * 31 + ho) * 296;
            int par = (wo & 1) * 49, wh = wo >> 1;
            int j0 = (row4 & 1) * 4;
            {   // Mt=0: co 0..15, c8 = row4>>1
                int c8 = row4 >> 1;
                f16x4 pk = { (f16)fmaxf(a0[0] + bvv[0][0], 0.0f),
                             (f16)fmaxf(a0[1] + bvv[0][1], 0.0f),
                             (f16)fmaxf(a0[2] + bvv[0][2], 0.0f),
                             (f16)fmaxf(a0[3] + bvv[0][3], 0.0f) };
                int sl = c8 * 98 + par + wh;
                *(f16x4*)(h1T + (rowbase + sl) * 8 + j0) = pk;
            }
            if (row4 < 2) {  // Mt=1: co 16..23, c8 = 2
                f16x4 pk = { (f16)fmaxf(a1[0] + bvv[1][0], 0.0f),
                             (f16)fmaxf(a1[1] + bvv[1][1], 0.0f),
                             (f16)fmaxf(a1[2] + bvv[1][2], 0.0f),
                             (f16)fmaxf(a1[3] + bvv[1][3], 0.0f) };
                int sl = 2 * 98 + par + wh;
                *(f16x4*)(h1T + (rowbase + sl) * 8 + j0) = pk;
            }
        }
    }
}

// Weight pack conv2: w2[36,24,5,5] fp32 -> Wpk[48][616] f16.
__global__ __launch_bounds__(256)
void wpack_kernel(const float* __restrict__ w2, f16* __restrict__ Wpk)
{
    int idx = blockIdx.x * 256 + threadIdx.x;
    if (idx >= 48 * 616) return;
    int co = idx / 616;
    int kk = idx % 616;
    float v = 0.0f;
    if (kk < 608 && co < 36) {
        int c = kk >> 3, j = kk & 7;
        if (c < 75) {
            int pq = c / 3, c8 = c - 3 * pq;
            int kh = pq / 5, kw = pq - 5 * kh;
            int ci = c8 * 8 + j;
            v = w2[(((size_t)co * 24 + ci) * 5 + kh) * 5 + kw];
        }
    }
    Wpk[idx] = (f16)v;
}

// Weight pack conv3: w3[48,36,5,5] fp32 -> Wpk3[48][1032] f16.
__global__ __launch_bounds__(256)
void wpack3_kernel(const float* __restrict__ w3, f16* __restrict__ Wpk3)
{
    int idx = blockIdx.x * 256 + threadIdx.x;
    if (idx >= 48 * 1032) return;
    int co = idx / 1032;
    int kk = idx % 1032;
    float v = 0.0f;
    if (kk < 1024) {
        int c = kk >> 3, j = kk & 7;
        int pq = c / 5, c8 = c - 5 * pq;
        if (pq < 25) {
            int kh = pq / 5, kw = pq - 5 * kh;
            int ci = c8 * 8 + j;
            if (ci < 36)
                v = w3[(((size_t)co * 36 + ci) * 5 + kh) * 5 + kw];
        }
    }
    Wpk3[idx] = (f16)v;
}

// conv2 via MFMA: block = one image, WHOLE image in LDS (146.8 KB), one
// barrier. 6 waves = (ct co-subtile, sh px-half). 42 px-tiles of 16; wave
// (ct,sh) does tiles sh*21 + it*3 + si (it 0..6, si 0..2 = 3 indep chains).
// A-fragments in registers. B reads conflict-free (parity layout).
__global__ __launch_bounds__(384)
void conv2_mfma(const f16* __restrict__ h1T, const f16* __restrict__ Wpk,
                const float* __restrict__ b2, f16* __restrict__ h2f)
{
    __shared__ __align__(16) f16 img[73408];   // [31][296][8] = 146,816 B
    __shared__ u32 lutS[76];

    int m    = blockIdx.x;
    int tid  = threadIdx.x;
    int lane = tid & 63;
    int wv   = tid >> 6;
    int ct   = wv >> 1;
    int sh   = wv & 1;
    int row4 = lane >> 4;
    int col  = lane & 15;

    // lut: chunk c -> {kh*4736 (input-row bytes), parity slot offset}
    if (tid < 76) {
        int c = tid; u32 v = 0;
        if (c < 75) {
            int pq = c / 3, c8 = c - 3 * pq;
            int kh = pq / 5, kw = pq - 5 * kh;
            u32 ofs = (u32)(c8 * 98 + (kw & 1) * 49 + (kw >> 1));
            v = ((u32)(kh * 4736) << 8) | ofs;
        }
        lutS[c] = v;
    }

    // A-fragments -> registers
    f16x8 af[19];
    {
        const char* wb = (const char*)Wpk + (size_t)(ct * 16 + col) * 1232 + row4 * 16;
        #pragma unroll
        for (int t = 0; t < 19; ++t)
            af[t] = *(const f16x8*)(wb + t * 64);
    }

    // burst-stage the whole image: 9176 x 16B, ~24 independent loads/thread
    {
        const char* g = (const char*)(h1T + (size_t)m * 73408);
        for (int u = tid; u < 9176; u += 384)
            *(uint4*)((char*)img + (size_t)u * 16) = *(const uint4*)(g + (size_t)u * 16);
    }

    float bv[4];
    #pragma unroll
    for (int i = 0; i < 4; ++i) {
        int co = ct * 16 + row4 * 4 + i;
        bv[i] = (co < 36) ? b2[co] : 0.0f;
    }
    int c8o  = ct * 2 + (row4 >> 1);   // output chunk (0..5; 5 unused)
    int hsel = (row4 & 1) * 4;

    __syncthreads();

    const char* ic = (const char*)img;
    for (int it = 0; it < 7; ++it) {
        int rbase[3], valid[3], hov[3], wov[3];
        #pragma unroll
        for (int si = 0; si < 3; ++si) {
            int tile = sh * 21 + it * 3 + si;
            int px   = tile * 16 + col;
            valid[si] = (px < 658);                 // 14*47 output px
            int pc = valid[si] ? px : 657;
            int ho = pc / 47;
            int wo = pc - 47 * ho;
            rbase[si] = ho * 9472 + wo * 16;        // 2*ho input rows * 4736 B
            hov[si] = ho; wov[si] = wo;
        }

        f32x4 acc0 = {0.f,0.f,0.f,0.f}, acc1 = {0.f,0.f,0.f,0.f}, acc2 = {0.f,0.f,0.f,0.f};
        #pragma unroll
        for (int t = 0; t < 19; ++t) {
            u32 lv   = lutS[4 * t + row4];
            int rowb = (int)(lv >> 8);
            int boff = (int)(lv & 255) << 4;
            f16x8 a = af[t];
            {
                f16x8 xf = *(const f16x8*)(ic + rbase[0] + rowb + boff);
                acc0 = __builtin_amdgcn_mfma_f32_16x16x32_f16(a, xf, acc0, 0, 0, 0);
            }
            {
                f16x8 xf = *(const f16x8*)(ic + rbase[1] + rowb + boff);
                acc1 = __builtin_amdgcn_mfma_f32_16x16x32_f16(a, xf, acc1, 0, 0, 0);
            }
            {
                f16x8 xf = *(const f16x8*)(ic + rbase[2] + rowb + boff);
                acc2 = __builtin_amdgcn_mfma_f32_16x16x32_f16(a, xf, acc2, 0, 0, 0);
            }
        }

        #pragma unroll
        for (int si = 0; si < 3; ++si) {
            f32x4 a = (si == 0) ? acc0 : (si == 1) ? acc1 : acc2;
            if (valid[si] && c8o < 5) {
                int wo = wov[si], ho = hov[si];
                f16x4 pk;
                #pragma unroll
                for (int i = 0; i < 4; ++i) pk[i] = (f16)fmaxf(a[i] + bv[i], 0.0f);
                int sl = c8o * 47 + (wo & 1) * 24 + (wo >> 1);
                *(f16x4*)(h2f + ((size_t)m * 3374 + (size_t)ho * 241 + sl) * 8 + hsel) = pk;
            }
        }
    }
}

// conv3 via MFMA: whole image + weights in LDS (unchanged).
__global__ __launch_bounds__(384)
void conv3_mfma(const f16* __restrict__ h2f, const f16* __restrict__ Wpk3,
                const float* __restrict__ b3, float* __restrict__ h3)
{
    __shared__ __align__(16) f16 Wl[48 * 1032];
    __shared__ __align__(16) f16 img[3374 * 8];
    __shared__ u32 lut[128];

    int m    = blockIdx.x;
    int tid  = threadIdx.x;
    int lane = tid & 63;
    int wv   = tid >> 6;
    int ct   = wv >> 1;
    int sh   = wv & 1;
    int row4 = lane >> 4;
    int col  = lane & 15;

    if (tid < 128) {
        int c  = tid;
        int pq = c / 5, c8 = c - 5 * pq;           // pq=25 pad (addr in-bounds)
        int kh = pq / 5, kw = pq - 5 * kh;
        lut[c] = ((u32)(kh * 3856) << 8) |
                 (u32)(c8 * 47 + (kw & 1) * 24 + (kw >> 1));
    }
    for (int u = tid; u < 6192; u += 384)
        *(uint4*)((char*)Wl + (size_t)u * 16) =
            *(const uint4*)((const char*)Wpk3 + (size_t)u * 16);
    {
        const char* g = (const char*)(h2f + (size_t)m * 3374 * 8);
        for (int u = tid; u < 3374; u += 384)
            *(uint4*)((char*)img + (size_t)u * 16) = *(const uint4*)(g + (size_t)u * 16);
    }
    __syncthreads();

    int rb[4], wo16[4], valid[4], hov[4], wov[4];
    int nsi = 4 - sh;
    #pragma unroll
    for (int si = 0; si < 4; ++si) {
        int s  = 4 * sh + si;
        int px = 16 * s + col;
        valid[si] = (si < nsi) && (px < 110);
        int pc = px < 110 ? px : 109;
        int ho = pc / 22, wo = pc - 22 * ho;
        rb[si]   = ho * 7712;
        wo16[si] = wo * 16;
        hov[si]  = ho; wov[si] = wo;
    }

    float bv[4];
    #pragma unroll
    for (int i = 0; i < 4; ++i) bv[i] = b3[ct * 16 + row4 * 4 + i];

    int Abase = (ct * 16 + col) * 2064 + row4 * 16;
    const char* Wc = (const char*)Wl;
    const char* ic = (const char*)img;

    f32x4 a0 = {0.f,0.f,0.f,0.f}, a1 = {0.f,0.f,0.f,0.f};
    f32x4 a2 = {0.f,0.f,0.f,0.f}, a3 = {0.f,0.f,0.f,0.f};
    #pragma unroll 8
    for (int t = 0; t < 32; ++t) {
        u32 lv     = lut[4 * t + row4];
        int rowoff = (int)(lv >> 8);
        int boff   = (int)(lv & 255) << 4;
        f16x8 af = *(const f16x8*)(Wc + Abase + 64 * t);
        {
            f16x8 xf = *(const f16x8*)(ic + rb[0] + rowoff + boff + wo16[0]);
            a0 = __builtin_amdgcn_mfma_f32_16x16x32_f16(af, xf, a0, 0, 0, 0);
        }
        {
            f16x8 xf = *(const f16x8*)(ic + rb[1] + rowoff + boff + wo16[1]);
            a1 = __builtin_amdgcn_mfma_f32_16x16x32_f16(af, xf, a1, 0, 0, 0);
        }
        {
            f16x8 xf = *(const f16x8*)(ic + rb[2] + rowoff + boff + wo16[2]);
            a2 = __builtin_amdgcn_mfma_f32_16x16x32_f16(af, xf, a2, 0, 0, 0);
        }
        {
            f16x8 xf = *(const f16x8*)(ic + rb[3] + rowoff + boff + wo16[3]);
            a3 = __builtin_amdgcn_mfma_f32_16x16x32_f16(af, xf, a3, 0, 0, 0);
        }
    }

    int co0 = ct * 16 + row4 * 4;
    #pragma unroll
    for (int si = 0; si < 4; ++si) {
        if (!valid[si]) continue;
        f32x4 a = (si == 0) ? a0 : (si == 1) ? a1 : (si == 2) ? a2 : a3;
        float* op = h3 + (((size_t)m * 48 + co0) * 5 + hov[si]) * 22 + wov[si];
        #pragma unroll
        for (int i = 0; i < 4; ++i)
            op[(size_t)i * 110] = fmaxf(a[i] + bv[i], 0.0f);
    }
}

// Register-tiled fp32 direct conv for conv4..conv5.
template<int CIN, int KH, int KW, int STRIDE, int CO_T, int WO_T>
__global__ __launch_bounds__(256)
void conv_tile_kernel(const float* __restrict__ in, const float* __restrict__ wt,
                      const float* __restrict__ bias, float* __restrict__ out,
                      int Cout, int Hin, int Win, int Hout, int Wout,
                      int n_cg, int n_wg, int M)
{
    constexpr int LOAD_W = (WO_T - 1) * STRIDE + KW;

    int bx = blockIdx.x;
    int cg = bx % n_cg;
    int gid = (bx / n_cg) * blockDim.x + threadIdx.x;
    int wg = gid % n_wg;
    int t  = gid / n_wg;
    int ho = t % Hout;
    int m  = t / Hout;
    if (m >= M) return;

    int wo0 = wg * WO_T;
    int co0 = cg * CO_T;

    const float* ip = in + ((size_t)(m * CIN) * Hin + (size_t)ho * STRIDE) * Win
                         + (size_t)wo0 * STRIDE;
    const float* wp = wt + (size_t)co0 * (CIN * KH * KW);

    float acc[CO_T][WO_T];
    #pragma unroll
    for (int c = 0; c < CO_T; ++c) {
        float b = bias[co0 + c];
        #pragma unroll
        for (int q = 0; q < WO_T; ++q) acc[c][q] = b;
    }

    #pragma unroll 1
    for (int ci = 0; ci < CIN; ++ci) {
        #pragma unroll
        for (int kh = 0; kh < KH; ++kh) {
            const float* row = ip + ((size_t)ci * Hin + kh) * Win;
            float xv[LOAD_W];
            #pragma unroll
            for (int l = 0; l < LOAD_W; ++l) xv[l] = row[l];
            const float* wrow = wp + (ci * KH + kh) * KW;
            #pragma unroll
            for (int c = 0; c < CO_T; ++c) {
                #pragma unroll
                for (int kw = 0; kw < KW; ++kw) {
                    float wv = wrow[c * (CIN * KH * KW) + kw];
                    #pragma unroll
                    for (int q = 0; q < WO_T; ++q)
                        acc[c][q] = fmaf(xv[q * STRIDE + kw], wv, acc[c][q]);
                }
            }
        }
    }

    #pragma unroll
    for (int c = 0; c < CO_T; ++c) {
        float* op = out + (((size_t)m * Cout + co0 + c) * Hout + ho) * Wout + wo0;
        #pragma unroll
        for (int q = 0; q < WO_T; ++q) {
            if (wo0 + q < Wout) op[q] = fmaxf(acc[c][q], 0.0f);
        }
    }
}

// FC (1152 -> 128) + relu. One frame per block, 8-way split-K, float4 loads.
__global__ __launch_bounds__(256)
void fc_relu_kernel(const float* __restrict__ h, const float* __restrict__ w,
                    const float* __restrict__ b, float* __restrict__ out)
{
    __shared__ float hs[1152];
    __shared__ float part[8][32][4];
    int f   = blockIdx.x;
    int tid = threadIdx.x;
    int ks  = tid >> 5;
    int j4  = tid & 31;
    for (int k = tid; k < 1152; k += 256) hs[k] = h[(size_t)f * 1152 + k];
    __syncthreads();
    const float4* w4 = (const float4*)w;
    float4 acc = {0.f, 0.f, 0.f, 0.f};
    int k0 = ks * 144;
    #pragma unroll 4
    for (int kk = 0; kk < 144; ++kk) {
        int k = k0 + kk;
        float4 wv = w4[(size_t)k * 32 + j4];
        float hb = hs[k];
        acc.x = fmaf(wv.x, hb, acc.x);
        acc.y = fmaf(wv.y, hb, acc.y);
        acc.z = fmaf(wv.z, hb, acc.z);
        acc.w = fmaf(wv.w, hb, acc.w);
    }
    *(float4*)&part[ks][j4][0] = acc;
    __syncthreads();
    if (tid < 128) {
        int j = tid, jq = j >> 2, r = j & 3;
        float s = b[j];
        #pragma unroll
        for (int q = 0; q < 8; ++q) s += part[q][jq][r];
        out[(size_t)f * 128 + j] = fmaxf(s, 0.0f);
    }
}

// Sensory synapse pre-computation.
__global__ __launch_bounds__(64)
void sensory_kernel(const float* __restrict__ feat,
                    const float* __restrict__ s_mu,
                    const float* __restrict__ s_sigma,
                    const float* __restrict__ s_w,
                    const float* __restrict__ s_erev,
                    float* __restrict__ wnum, float* __restrict__ wden)
{
    __shared__ float y[128];
    int bt = blockIdx.x;
    int n  = threadIdx.x;
    for (int s = n; s < 128; s += 64) y[s] = feat[bt * 128 + s];
    __syncthreads();
    float num = 0.0f, den = 0.0f;
    for (int s = 0; s < 128; ++s) {
        int o = s * 64 + n;
        float a = s_w[o] * sigmoidf_fast((y[s] - s_mu[o]) * s_sigma[o]);
        num = fmaf(a, s_erev[o], num);
        den += a;
    }
    wnum[bt * 64 + n] = num;
    wden[bt * 64 + n] = den;
}

// LTC recurrence: 8 waves/batch, matrix in registers, one barrier per unfold.
__global__ __launch_bounds__(512)
void ltc_wave_kernel(const float* __restrict__ wnum_s,
                     const float* __restrict__ wden_s,
                     const float* __restrict__ mu, const float* __restrict__ sigma,
                     const float* __restrict__ w, const float* __restrict__ erev,
                     const float* __restrict__ gleak, const float* __restrict__ vleak,
                     const float* __restrict__ cm, float* __restrict__ out, int T)
{
    __shared__ float2 pnd[2][8][64];

    int b    = blockIdx.x;
    int tid  = threadIdx.x;
    int lane = tid & 63;
    int p    = tid >> 6;

    float musig[8], nsg[8], wv[8], wev[8];
    #pragma unroll
    for (int ii = 0; ii < 8; ++ii) {
        int o = (8 * p + ii) * 64 + lane;
        float sg = sigma[o];
        musig[ii] = mu[o] * sg;
        nsg[ii]   = -sg;
        float wl  = w[o];
        wv[ii]    = wl;
        wev[ii]   = wl * erev[o];
    }
    float gl   = gleak[lane];
    float glvl = gl * vleak[lane];
    float cmt  = cm[lane] * 6.0f;
    float v    = 0.0f;
    int   buf  = 0;

    for (int t = 0; t < T; ++t) {
        float ns = wnum_s[(b * T + t) * 64 + lane];
        float ds = wden_s[(b * T + t) * 64 + lane];
        #pragma unroll 1
        for (int u = 0; u < 6; ++u) {
            float num = 0.0f, den = 0.0f;
            #pragma unroll
            for (int ii = 0; ii < 8; ++ii) {
                float vi  = __shfl(v, 8 * p + ii);
                float arg = fmaf(vi, nsg[ii], musig[ii]);
                float e   = __expf(arg);
                float s   = __builtin_amdgcn_rcpf(1.0f + e);
                den = fmaf(wv[ii], s, den);
                num = fmaf(wev[ii], s, num);
            }
            pnd[buf][p][lane] = make_float2(num, den);
            __syncthreads();
            float wn = ns, wd = ds;
            #pragma unroll
            for (int q = 0; q < 8; ++q) {
                float2 pq = pnd[buf][q][lane];
                wn += pq.x; wd += pq.y;
            }
            v = (fmaf(cmt, v, glvl) + wn) *
                __builtin_amdgcn_rcpf(cmt + gl + wd + 1e-8f);
            buf ^= 1;
        }
        if (tid < 3) out[(b * T + t) * 3 + tid] = v;
    }
}

// ---------------------------------------------------------------------------
// Launch
// ---------------------------------------------------------------------------
extern "C" void kernel_launch(void* const* d_in, const int* in_sizes, int n_in,
                              void* d_out, int out_size, void* d_ws, size_t ws_size,
                              hipStream_t stream)
{
    (void)in_sizes; (void)n_in; (void)out_size; (void)ws_size;

    const float* x    = (const float*)d_in[0];
    const float* w1   = (const float*)d_in[1];
    const float* b1   = (const float*)d_in[2];
    const float* w2   = (const float*)d_in[3];
    const float* b2   = (const float*)d_in[4];
    const float* w3   = (const float*)d_in[5];
    const float* b3   = (const float*)d_in[6];
    const float* w4   = (const float*)d_in[7];
    const float* b4   = (const float*)d_in[8];
    const float* w5   = (const float*)d_in[9];
    const float* b5   = (const float*)d_in[10];
    const float* fcw  = (const float*)d_in[11];
    const float* fcb  = (const float*)d_in[12];
    const float* smu  = (const float*)d_in[13];
    const float* ssig = (const float*)d_in[14];
    const float* sw   = (const float*)d_in[15];
    const float* serv = (const float*)d_in[16];
    const float* mu   = (const float*)d_in[17];
    const float* sig  = (const float*)d_in[18];
    const float* ww   = (const float*)d_in[19];
    const float* erev = (const float*)d_in[20];
    const float* gl   = (const float*)d_in[21];
    const float* vl   = (const float*)d_in[22];
    const float* cm   = (const float*)d_in[23];
    float* out = (float*)d_out;

    const int BT = 512;

    char* wsB = (char*)d_ws;
    size_t off = 0;
    f16*   h1T  = (f16*)(wsB + off); off += (size_t)512 * 31 * 2368 * 2;   // 75.2 MB
    f16*   Wpk  = (f16*)(wsB + off); off += 65536;
    f16*   h2f  = (f16*)(wsB + off); off += (size_t)512 * 3374 * 16;       // 27.6 MB
    f16*   Wpk3 = (f16*)(wsB + off); off += 48 * 1032 * 2;
    f16*   Wpk1 = (f16*)(wsB + off); off += 32 * 136 * 2;
    float* h3   = (float*)(wsB + off); off += (size_t)512 * 48 * 5 * 22 * 4;
    float* h4   = (float*)(wsB + off); off += (size_t)512 * 64 * 3 * 20 * 4;
    float* h5   = (float*)(wsB + off); off += (size_t)512 * 64 * 18 * 4;
    float* feat = (float*)(wsB + off); off += (size_t)BT * 128 * 4;
    float* wnum = (float*)(wsB + off); off += (size_t)BT * 64 * 4;
    float* wden = (float*)(wsB + off); off += (size_t)BT * 64 * 4;

    wpack1_kernel<<<(32 * 136 + 255) / 256, 256, 0, stream>>>(w1, Wpk1);
    wpack_kernel<<<(48 * 616 + 255) / 256, 256, 0, stream>>>(w2, Wpk);
    wpack3_kernel<<<(48 * 1032 + 255) / 256, 256, 0, stream>>>(w3, Wpk3);

    conv1_mfma<<<512, 512, 0, stream>>>(x, Wpk1, b1, h1T);
    conv2_mfma<<<512, 384, 0, stream>>>(h1T, Wpk, b2, h2f);
    conv3_mfma<<<512, 384, 0, stream>>>(h2f, Wpk3, b3, h3);

    // conv4: [512,48,5,22] -> [512,64,3,20]
    {
        int n_cg = 16, n_wg = 5;
        int sp_threads = BT * 3 * n_wg;
        int grid = (sp_threads + 255) / 256 * n_cg;
        conv_tile_kernel<48, 3, 3, 1, 4, 4><<<grid, 256, 0, stream>>>(
            h3, w4, b4, h4, 64, 5, 22, 3, 20, n_cg, n_wg, BT);
    }
    // conv5: -> [512,64,1,18]
    {
        int n_cg = 16, n_wg = 6;
        int sp_threads = BT * 1 * n_wg;
        int grid = (sp_threads + 255) / 256 * n_cg;
        conv_tile_kernel<64, 3, 3, 1, 4, 3><<<grid, 256, 0, stream>>>(
            h4, w5, b5, h5, 64, 3, 20, 1, 18, n_cg, n_wg, BT);
    }
    fc_relu_kernel<<<512, 256, 0, stream>>>(h5, fcw, fcb, feat);
    sensory_kernel<<<BT, 64, 0, stream>>>(feat, smu, ssig, sw, serv, wnum, wden);
    ltc_wave_kernel<<<32, 512, 0, stream>>>(wnum, wden, mu, sig, ww, erev,
                                            gl, vl, cm, out, 16);
}

// Round 9
// 260.178 us; speedup vs baseline: 15.5130x; 1.0321x over previous
//
#include <hip/hip_runtime.h>
#include <hip/hip_bf16.h>

// ---------------------------------------------------------------------------
// NCP model: conv head + FC + LTC recurrence.
// Round 8: conv1 split into 2 blocks/image (56 KB LDS -> 2 blocks/CU),
//          float4-vectorized staging, weights direct to registers.
//          Everything else unchanged from round 7.
// ---------------------------------------------------------------------------

typedef _Float16 f16;
typedef _Float16 f16x8 __attribute__((ext_vector_type(8)));
typedef _Float16 f16x4 __attribute__((ext_vector_type(4)));
typedef float    f32x4 __attribute__((ext_vector_type(4)));
typedef unsigned int u32;

static __device__ __forceinline__ float sigmoidf_fast(float x) {
    return __builtin_amdgcn_rcpf(1.0f + __expf(-x));
}

// ---------------------------------------------------------------------------
// h1T layout: [512][31 rows][296 slots][8 halves] f16 (rows of 98 cols, 3 c8):
//   slot(w,c8) = c8*98 + (w&1)*49 + (w>>1)
// h2f layout: [512][14 rows][241 slots][8 halves] f16 (47 cols, 5 c8):
//   slot(w,c8) = c8*47 + (w&1)*24 + (w>>1)
// ---------------------------------------------------------------------------

// Weight pack conv1: w1[24,3,5,5] fp32 -> Wpk1[32][136] f16.
__global__ __launch_bounds__(256)
void wpack1_kernel(const float* __restrict__ w1, f16* __restrict__ Wpk1)
{
    int idx = blockIdx.x * 256 + threadIdx.x;
    if (idx >= 32 * 136) return;
    int co = idx / 136;
    int kk = idx % 136;
    float v = 0.0f;
    if (co < 24 && kk < 120) {
        int p = kk >> 3, jj = kk & 7;
        int kh = p / 3, kwp = p % 3;
        int kws = jj >> 2, ci = jj & 3;
        int kw = 2 * kwp + kws;
        if (kw < 5 && ci < 3)
            v = w1[(((size_t)co * 3 + ci) * 5 + kh) * 5 + kw];
    }
    Wpk1[idx] = (f16)v;
}

// conv1 via MFMA: 2 blocks per image (ho halves). Staged rows [35][200][ci4]
// f16 in LDS (56 KB -> 2 blocks/CU). Weights in registers from global.
__global__ __launch_bounds__(512)
void conv1_mfma(const float* __restrict__ x, const f16* __restrict__ Wpk1,
                const float* __restrict__ b1, f16* __restrict__ h1T)
{
    __shared__ __align__(16) f16 img[35 * 200 * 4];   // 56,000 B

    int blk  = blockIdx.x;
    int m    = blk >> 1;
    int hf   = blk & 1;
    int tid  = threadIdx.x;
    int lane = tid & 63;
    int wv   = tid >> 6;        // 0..7
    int col  = lane & 15;
    int row4 = lane >> 4;

    int ho_base = hf * 16;           // hf=0: ho 0..15, hf=1: ho 16..30
    int r0      = 2 * ho_base;       // input row base (0 or 32)
    int nrows   = hf ? 33 : 35;
    int nho     = hf ? 15 : 16;
    int npx     = nho * 98;          // 1568 or 1470
    int ntile   = (npx + 15) >> 4;   // 98 or 92
    int niter   = (ntile + 7) >> 3;  // 13 or 12

    // A-fragments from global (8.7 KB, L2-hot across 1024 blocks)
    f16x8 af[2][4];
    #pragma unroll
    for (int Mt = 0; Mt < 2; ++Mt)
        #pragma unroll
        for (int t = 0; t < 4; ++t)
            af[Mt][t] = *(const f16x8*)((const char*)Wpk1 +
                           (Mt * 16 + col) * 272 + t * 64 + row4 * 16);

    // stage rows r0..r0+nrows of 3 planes -> [local_row][w][ci4] f16
    {
        const float* p0 = x + (size_t)m * 39600 + (size_t)r0 * 200;
        int n4 = (nrows * 200) >> 2;   // 1750 or 1650 float4 per plane
        for (int u4 = tid; u4 < n4; u4 += 512) {
            float4 a = *(const float4*)(p0 + (size_t)u4 * 4);
            float4 b = *(const float4*)(p0 + 13200 + (size_t)u4 * 4);
            float4 c = *(const float4*)(p0 + 26400 + (size_t)u4 * 4);
            f16x8 lo = { (f16)a.x, (f16)b.x, (f16)c.x, (f16)0.0f,
                         (f16)a.y, (f16)b.y, (f16)c.y, (f16)0.0f };
            f16x8 hi = { (f16)a.z, (f16)b.z, (f16)c.z, (f16)0.0f,
                         (f16)a.w, (f16)b.w, (f16)c.w, (f16)0.0f };
            *(f16x8*)(&img[(size_t)u4 * 16])     = lo;
            *(f16x8*)(&img[(size_t)u4 * 16 + 8]) = hi;
        }
    }

    int rowB[4], kwpv[4];
    #pragma unroll
    for (int t = 0; t < 4; ++t) {
        int p = 4 * t + row4; if (p > 14) p = 14;   // k>=120 rows are zero
        rowB[t] = (p / 3) * 1600;
        kwpv[t] = (p % 3) * 16;
    }

    float bvv[2][4];
    #pragma unroll
    for (int Mt = 0; Mt < 2; ++Mt)
        #pragma unroll
        for (int i = 0; i < 4; ++i) {
            int co = Mt * 16 + row4 * 4 + i;
            bvv[Mt][i] = (co < 24) ? b1[co] : 0.0f;
        }

    __syncthreads();

    const char* ic = (const char*)img;
    for (int it = 0; it < niter; ++it) {
        int s = wv + it * 8;
        if (s >= ntile) continue;
        int px = s * 16 + col;
        bool pv = (px < npx);
        int pc = pv ? px : npx - 1;
        int ho_l = pc / 98;
        int wo   = pc - ho_l * 98;
        int base = ho_l * 3200 + wo * 16;

        f32x4 a0 = {0.f,0.f,0.f,0.f}, a1 = {0.f,0.f,0.f,0.f};
        #pragma unroll
        for (int t = 0; t < 4; ++t) {
            f16x8 xf = *(const f16x8*)(ic + base + rowB[t] + kwpv[t]);
            a0 = __builtin_amdgcn_mfma_f32_16x16x32_f16(af[0][t], xf, a0, 0, 0, 0);
            a1 = __builtin_amdgcn_mfma_f32_16x16x32_f16(af[1][t], xf, a1, 0, 0, 0);
        }

        if (pv) {
            int ho = ho_base + ho_l;
            size_t rowbase = ((size_t)m * 31 + ho) * 296;
            int par = (wo & 1) * 49, wh = wo >> 1;
            int j0 = (row4 & 1) * 4;
            {   // Mt=0: co 0..15, c8 = row4>>1
                int c8 = row4 >> 1;
                f16x4 pk = { (f16)fmaxf(a0[0] + bvv[0][0], 0.0f),
                             (f16)fmaxf(a0[1] + bvv[0][1], 0.0f),
                             (f16)fmaxf(a0[2] + bvv[0][2], 0.0f),
                             (f16)fmaxf(a0[3] + bvv[0][3], 0.0f) };
                int sl = c8 * 98 + par + wh;
                *(f16x4*)(h1T + (rowbase + sl) * 8 + j0) = pk;
            }
            if (row4 < 2) {  // Mt=1: co 16..23, c8 = 2
                f16x4 pk = { (f16)fmaxf(a1[0] + bvv[1][0], 0.0f),
                             (f16)fmaxf(a1[1] + bvv[1][1], 0.0f),
                             (f16)fmaxf(a1[2] + bvv[1][2], 0.0f),
                             (f16)fmaxf(a1[3] + bvv[1][3], 0.0f) };
                int sl = 2 * 98 + par + wh;
                *(f16x4*)(h1T + (rowbase + sl) * 8 + j0) = pk;
            }
        }
    }
}

// Weight pack conv2: w2[36,24,5,5] fp32 -> Wpk[48][616] f16.
__global__ __launch_bounds__(256)
void wpack_kernel(const float* __restrict__ w2, f16* __restrict__ Wpk)
{
    int idx = blockIdx.x * 256 + threadIdx.x;
    if (idx >= 48 * 616) return;
    int co = idx / 616;
    int kk = idx % 616;
    float v = 0.0f;
    if (kk < 608 && co < 36) {
        int c = kk >> 3, j = kk & 7;
        if (c < 75) {
            int pq = c / 3, c8 = c - 3 * pq;
            int kh = pq / 5, kw = pq - 5 * kh;
            int ci = c8 * 8 + j;
            v = w2[(((size_t)co * 24 + ci) * 5 + kh) * 5 + kw];
        }
    }
    Wpk[idx] = (f16)v;
}

// Weight pack conv3: w3[48,36,5,5] fp32 -> Wpk3[48][1032] f16.
__global__ __launch_bounds__(256)
void wpack3_kernel(const float* __restrict__ w3, f16* __restrict__ Wpk3)
{
    int idx = blockIdx.x * 256 + threadIdx.x;
    if (idx >= 48 * 1032) return;
    int co = idx / 1032;
    int kk = idx % 1032;
    float v = 0.0f;
    if (kk < 1024) {
        int c = kk >> 3, j = kk & 7;
        int pq = c / 5, c8 = c - 5 * pq;
        if (pq < 25) {
            int kh = pq / 5, kw = pq - 5 * kh;
            int ci = c8 * 8 + j;
            if (ci < 36)
                v = w3[(((size_t)co * 36 + ci) * 5 + kh) * 5 + kw];
        }
    }
    Wpk3[idx] = (f16)v;
}

// conv2 via MFMA: block = one image, whole image in LDS (146.8 KB), one
// barrier. A-fragments in registers; B reads conflict-free (parity layout).
__global__ __launch_bounds__(384)
void conv2_mfma(const f16* __restrict__ h1T, const f16* __restrict__ Wpk,
                const float* __restrict__ b2, f16* __restrict__ h2f)
{
    __shared__ __align__(16) f16 img[73408];   // [31][296][8] = 146,816 B
    __shared__ u32 lutS[76];

    int m    = blockIdx.x;
    int tid  = threadIdx.x;
    int lane = tid & 63;
    int wv   = tid >> 6;
    int ct   = wv >> 1;
    int sh   = wv & 1;
    int row4 = lane >> 4;
    int col  = lane & 15;

    if (tid < 76) {
        int c = tid; u32 v = 0;
        if (c < 75) {
            int pq = c / 3, c8 = c - 3 * pq;
            int kh = pq / 5, kw = pq - 5 * kh;
            u32 ofs = (u32)(c8 * 98 + (kw & 1) * 49 + (kw >> 1));
            v = ((u32)(kh * 4736) << 8) | ofs;
        }
        lutS[c] = v;
    }

    f16x8 af[19];
    {
        const char* wb = (const char*)Wpk + (size_t)(ct * 16 + col) * 1232 + row4 * 16;
        #pragma unroll
        for (int t = 0; t < 19; ++t)
            af[t] = *(const f16x8*)(wb + t * 64);
    }

    {
        const char* g = (const char*)(h1T + (size_t)m * 73408);
        for (int u = tid; u < 9176; u += 384)
            *(uint4*)((char*)img + (size_t)u * 16) = *(const uint4*)(g + (size_t)u * 16);
    }

    float bv[4];
    #pragma unroll
    for (int i = 0; i < 4; ++i) {
        int co = ct * 16 + row4 * 4 + i;
        bv[i] = (co < 36) ? b2[co] : 0.0f;
    }
    int c8o  = ct * 2 + (row4 >> 1);
    int hsel = (row4 & 1) * 4;

    __syncthreads();

    const char* ic = (const char*)img;
    for (int it = 0; it < 7; ++it) {
        int rbase[3], valid[3], hov[3], wov[3];
        #pragma unroll
        for (int si = 0; si < 3; ++si) {
            int tile = sh * 21 + it * 3 + si;
            int px   = tile * 16 + col;
            valid[si] = (px < 658);
            int pc = valid[si] ? px : 657;
            int ho = pc / 47;
            int wo = pc - 47 * ho;
            rbase[si] = ho * 9472 + wo * 16;
            hov[si] = ho; wov[si] = wo;
        }

        f32x4 acc0 = {0.f,0.f,0.f,0.f}, acc1 = {0.f,0.f,0.f,0.f}, acc2 = {0.f,0.f,0.f,0.f};
        #pragma unroll
        for (int t = 0; t < 19; ++t) {
            u32 lv   = lutS[4 * t + row4];
            int rowb = (int)(lv >> 8);
            int boff = (int)(lv & 255) << 4;
            f16x8 a = af[t];
            {
                f16x8 xf = *(const f16x8*)(ic + rbase[0] + rowb + boff);
                acc0 = __builtin_amdgcn_mfma_f32_16x16x32_f16(a, xf, acc0, 0, 0, 0);
            }
            {
                f16x8 xf = *(const f16x8*)(ic + rbase[1] + rowb + boff);
                acc1 = __builtin_amdgcn_mfma_f32_16x16x32_f16(a, xf, acc1, 0, 0, 0);
            }
            {
                f16x8 xf = *(const f16x8*)(ic + rbase[2] + rowb + boff);
                acc2 = __builtin_amdgcn_mfma_f32_16x16x32_f16(a, xf, acc2, 0, 0, 0);
            }
        }

        #pragma unroll
        for (int si = 0; si < 3; ++si) {
            f32x4 a = (si == 0) ? acc0 : (si == 1) ? acc1 : acc2;
            if (valid[si] && c8o < 5) {
                int wo = wov[si], ho = hov[si];
                f16x4 pk;
                #pragma unroll
                for (int i = 0; i < 4; ++i) pk[i] = (f16)fmaxf(a[i] + bv[i], 0.0f);
                int sl = c8o * 47 + (wo & 1) * 24 + (wo >> 1);
                *(f16x4*)(h2f + ((size_t)m * 3374 + (size_t)ho * 241 + sl) * 8 + hsel) = pk;
            }
        }
    }
}

// conv3 via MFMA: whole image + weights in LDS (unchanged).
__global__ __launch_bounds__(384)
void conv3_mfma(const f16* __restrict__ h2f, const f16* __restrict__ Wpk3,
                const float* __restrict__ b3, float* __restrict__ h3)
{
    __shared__ __align__(16) f16 Wl[48 * 1032];
    __shared__ __align__(16) f16 img[3374 * 8];
    __shared__ u32 lut[128];

    int m    = blockIdx.x;
    int tid  = threadIdx.x;
    int lane = tid & 63;
    int wv   = tid >> 6;
    int ct   = wv >> 1;
    int sh   = wv & 1;
    int row4 = lane >> 4;
    int col  = lane & 15;

    if (tid < 128) {
        int c  = tid;
        int pq = c / 5, c8 = c - 5 * pq;
        int kh = pq / 5, kw = pq - 5 * kh;
        lut[c] = ((u32)(kh * 3856) << 8) |
                 (u32)(c8 * 47 + (kw & 1) * 24 + (kw >> 1));
    }
    for (int u = tid; u < 6192; u += 384)
        *(uint4*)((char*)Wl + (size_t)u * 16) =
            *(const uint4*)((const char*)Wpk3 + (size_t)u * 16);
    {
        const char* g = (const char*)(h2f + (size_t)m * 3374 * 8);
        for (int u = tid; u < 3374; u += 384)
            *(uint4*)((char*)img + (size_t)u * 16) = *(const uint4*)(g + (size_t)u * 16);
    }
    __syncthreads();

    int rb[4], wo16[4], valid[4], hov[4], wov[4];
    int nsi = 4 - sh;
    #pragma unroll
    for (int si = 0; si < 4; ++si) {
        int s  = 4 * sh + si;
        int px = 16 * s + col;
        valid[si] = (si < nsi) && (px < 110);
        int pc = px < 110 ? px : 109;
        int ho = pc / 22, wo = pc - 22 * ho;
        rb[si]   = ho * 7712;
        wo16[si] = wo * 16;
        hov[si]  = ho; wov[si] = wo;
    }

    float bv[4];
    #pragma unroll
    for (int i = 0; i < 4; ++i) bv[i] = b3[ct * 16 + row4 * 4 + i];

    int Abase = (ct * 16 + col) * 2064 + row4 * 16;
    const char* Wc = (const char*)Wl;
    const char* ic = (const char*)img;

    f32x4 a0 = {0.f,0.f,0.f,0.f}, a1 = {0.f,0.f,0.f,0.f};
    f32x4 a2 = {0.f,0.f,0.f,0.f}, a3 = {0.f,0.f,0.f,0.f};
    #pragma unroll 8
    for (int t = 0; t < 32; ++t) {
        u32 lv     = lut[4 * t + row4];
        int rowoff = (int)(lv >> 8);
        int boff   = (int)(lv & 255) << 4;
        f16x8 af = *(const f16x8*)(Wc + Abase + 64 * t);
        {
            f16x8 xf = *(const f16x8*)(ic + rb[0] + rowoff + boff + wo16[0]);
            a0 = __builtin_amdgcn_mfma_f32_16x16x32_f16(af, xf, a0, 0, 0, 0);
        }
        {
            f16x8 xf = *(const f16x8*)(ic + rb[1] + rowoff + boff + wo16[1]);
            a1 = __builtin_amdgcn_mfma_f32_16x16x32_f16(af, xf, a1, 0, 0, 0);
        }
        {
            f16x8 xf = *(const f16x8*)(ic + rb[2] + rowoff + boff + wo16[2]);
            a2 = __builtin_amdgcn_mfma_f32_16x16x32_f16(af, xf, a2, 0, 0, 0);
        }
        {
            f16x8 xf = *(const f16x8*)(ic + rb[3] + rowoff + boff + wo16[3]);
            a3 = __builtin_amdgcn_mfma_f32_16x16x32_f16(af, xf, a3, 0, 0, 0);
        }
    }

    int co0 = ct * 16 + row4 * 4;
    #pragma unroll
    for (int si = 0; si < 4; ++si) {
        if (!valid[si]) continue;
        f32x4 a = (si == 0) ? a0 : (si == 1) ? a1 : (si == 2) ? a2 : a3;
        float* op = h3 + (((size_t)m * 48 + co0) * 5 + hov[si]) * 22 + wov[si];
        #pragma unroll
        for (int i = 0; i < 4; ++i)
            op[(size_t)i * 110] = fmaxf(a[i] + bv[i], 0.0f);
    }
}

// Register-tiled fp32 direct conv for conv4..conv5.
template<int CIN, int KH, int KW, int STRIDE, int CO_T, int WO_T>
__global__ __launch_bounds__(256)
void conv_tile_kernel(const float* __restrict__ in, const float* __restrict__ wt,
                      const float* __restrict__ bias, float* __restrict__ out,
                      int Cout, int Hin, int Win, int Hout, int Wout,
                      int n_cg, int n_wg, int M)
{
    constexpr int LOAD_W = (WO_T - 1) * STRIDE + KW;

    int bx = blockIdx.x;
    int cg = bx % n_cg;
    int gid = (bx / n_cg) * blockDim.x + threadIdx.x;
    int wg = gid % n_wg;
    int t  = gid / n_wg;
    int ho = t % Hout;
    int m  = t / Hout;
    if (m >= M) return;

    int wo0 = wg * WO_T;
    int co0 = cg * CO_T;

    const float* ip = in + ((size_t)(m * CIN) * Hin + (size_t)ho * STRIDE) * Win
                         + (size_t)wo0 * STRIDE;
    const float* wp = wt + (size_t)co0 * (CIN * KH * KW);

    float acc[CO_T][WO_T];
    #pragma unroll
    for (int c = 0; c < CO_T; ++c) {
        float b = bias[co0 + c];
        #pragma unroll
        for (int q = 0; q < WO_T; ++q) acc[c][q] = b;
    }

    #pragma unroll 1
    for (int ci = 0; ci < CIN; ++ci) {
        #pragma unroll
        for (int kh = 0; kh < KH; ++kh) {
            const float* row = ip + ((size_t)ci * Hin + kh) * Win;
            float xv[LOAD_W];
            #pragma unroll
            for (int l = 0; l < LOAD_W; ++l) xv[l] = row[l];
            const float* wrow = wp + (ci * KH + kh) * KW;
            #pragma unroll
            for (int c = 0; c < CO_T; ++c) {
                #pragma unroll
                for (int kw = 0; kw < KW; ++kw) {
                    float wv = wrow[c * (CIN * KH * KW) + kw];
                    #pragma unroll
                    for (int q = 0; q < WO_T; ++q)
                        acc[c][q] = fmaf(xv[q * STRIDE + kw], wv, acc[c][q]);
                }
            }
        }
    }

    #pragma unroll
    for (int c = 0; c < CO_T; ++c) {
        float* op = out + (((size_t)m * Cout + co0 + c) * Hout + ho) * Wout + wo0;
        #pragma unroll
        for (int q = 0; q < WO_T; ++q) {
            if (wo0 + q < Wout) op[q] = fmaxf(acc[c][q], 0.0f);
        }
    }
}

// FC (1152 -> 128) + relu. One frame per block, 8-way split-K, float4 loads.
__global__ __launch_bounds__(256)
void fc_relu_kernel(const float* __restrict__ h, const float* __restrict__ w,
                    const float* __restrict__ b, float* __restrict__ out)
{
    __shared__ float hs[1152];
    __shared__ float part[8][32][4];
    int f   = blockIdx.x;
    int tid = threadIdx.x;
    int ks  = tid >> 5;
    int j4  = tid & 31;
    for (int k = tid; k < 1152; k += 256) hs[k] = h[(size_t)f * 1152 + k];
    __syncthreads();
    const float4* w4 = (const float4*)w;
    float4 acc = {0.f, 0.f, 0.f, 0.f};
    int k0 = ks * 144;
    #pragma unroll 4
    for (int kk = 0; kk < 144; ++kk) {
        int k = k0 + kk;
        float4 wv = w4[(size_t)k * 32 + j4];
        float hb = hs[k];
        acc.x = fmaf(wv.x, hb, acc.x);
        acc.y = fmaf(wv.y, hb, acc.y);
        acc.z = fmaf(wv.z, hb, acc.z);
        acc.w = fmaf(wv.w, hb, acc.w);
    }
    *(float4*)&part[ks][j4][0] = acc;
    __syncthreads();
    if (tid < 128) {
        int j = tid, jq = j >> 2, r = j & 3;
        float s = b[j];
        #pragma unroll
        for (int q = 0; q < 8; ++q) s += part[q][jq][r];
        out[(size_t)f * 128 + j] = fmaxf(s, 0.0f);
    }
}

// Sensory synapse pre-computation.
__global__ __launch_bounds__(64)
void sensory_kernel(const float* __restrict__ feat,
                    const float* __restrict__ s_mu,
                    const float* __restrict__ s_sigma,
                    const float* __restrict__ s_w,
                    const float* __restrict__ s_erev,
                    float* __restrict__ wnum, float* __restrict__ wden)
{
    __shared__ float y[128];
    int bt = blockIdx.x;
    int n  = threadIdx.x;
    for (int s = n; s < 128; s += 64) y[s] = feat[bt * 128 + s];
    __syncthreads();
    float num = 0.0f, den = 0.0f;
    for (int s = 0; s < 128; ++s) {
        int o = s * 64 + n;
        float a = s_w[o] * sigmoidf_fast((y[s] - s_mu[o]) * s_sigma[o]);
        num = fmaf(a, s_erev[o], num);
        den += a;
    }
    wnum[bt * 64 + n] = num;
    wden[bt * 64 + n] = den;
}

// LTC recurrence: 8 waves/batch, matrix in registers, one barrier per unfold.
__global__ __launch_bounds__(512)
void ltc_wave_kernel(const float* __restrict__ wnum_s,
                     const float* __restrict__ wden_s,
                     const float* __restrict__ mu, const float* __restrict__ sigma,
                     const float* __restrict__ w, const float* __restrict__ erev,
                     const float* __restrict__ gleak, const float* __restrict__ vleak,
                     const float* __restrict__ cm, float* __restrict__ out, int T)
{
    __shared__ float2 pnd[2][8][64];

    int b    = blockIdx.x;
    int tid  = threadIdx.x;
    int lane = tid & 63;
    int p    = tid >> 6;

    float musig[8], nsg[8], wv[8], wev[8];
    #pragma unroll
    for (int ii = 0; ii < 8; ++ii) {
        int o = (8 * p + ii) * 64 + lane;
        float sg = sigma[o];
        musig[ii] = mu[o] * sg;
        nsg[ii]   = -sg;
        float wl  = w[o];
        wv[ii]    = wl;
        wev[ii]   = wl * erev[o];
    }
    float gl   = gleak[lane];
    float glvl = gl * vleak[lane];
    float cmt  = cm[lane] * 6.0f;
    float v    = 0.0f;
    int   buf  = 0;

    for (int t = 0; t < T; ++t) {
        float ns = wnum_s[(b * T + t) * 64 + lane];
        float ds = wden_s[(b * T + t) * 64 + lane];
        #pragma unroll 1
        for (int u = 0; u < 6; ++u) {
            float num = 0.0f, den = 0.0f;
            #pragma unroll
            for (int ii = 0; ii < 8; ++ii) {
                float vi  = __shfl(v, 8 * p + ii);
                float arg = fmaf(vi, nsg[ii], musig[ii]);
                float e   = __expf(arg);
                float s   = __builtin_amdgcn_rcpf(1.0f + e);
                den = fmaf(wv[ii], s, den);
                num = fmaf(wev[ii], s, num);
            }
            pnd[buf][p][lane] = make_float2(num, den);
            __syncthreads();
            float wn = ns, wd = ds;
            #pragma unroll
            for (int q = 0; q < 8; ++q) {
                float2 pq = pnd[buf][q][lane];
                wn += pq.x; wd += pq.y;
            }
            v = (fmaf(cmt, v, glvl) + wn) *
                __builtin_amdgcn_rcpf(cmt + gl + wd + 1e-8f);
            buf ^= 1;
        }
        if (tid < 3) out[(b * T + t) * 3 + tid] = v;
    }
}

// ---------------------------------------------------------------------------
// Launch
// ---------------------------------------------------------------------------
extern "C" void kernel_launch(void* const* d_in, const int* in_sizes, int n_in,
                              void* d_out, int out_size, void* d_ws, size_t ws_size,
                              hipStream_t stream)
{
    (void)in_sizes; (void)n_in; (void)out_size; (void)ws_size;

    const float* x    = (const float*)d_in[0];
    const float* w1   = (const float*)d_in[1];
    const float* b1   = (const float*)d_in[2];
    const float* w2   = (const float*)d_in[3];
    const float* b2   = (const float*)d_in[4];
    const float* w3   = (const float*)d_in[5];
    const float* b3   = (const float*)d_in[6];
    const float* w4   = (const float*)d_in[7];
    const float* b4   = (const float*)d_in[8];
    const float* w5   = (const float*)d_in[9];
    const float* b5   = (const float*)d_in[10];
    const float* fcw  = (const float*)d_in[11];
    const float* fcb  = (const float*)d_in[12];
    const float* smu  = (const float*)d_in[13];
    const float* ssig = (const float*)d_in[14];
    const float* sw   = (const float*)d_in[15];
    const float* serv = (const float*)d_in[16];
    const float* mu   = (const float*)d_in[17];
    const float* sig  = (const float*)d_in[18];
    const float* ww   = (const float*)d_in[19];
    const float* erev = (const float*)d_in[20];
    const float* gl   = (const float*)d_in[21];
    const float* vl   = (const float*)d_in[22];
    const float* cm   = (const float*)d_in[23];
    float* out = (float*)d_out;

    const int BT = 512;

    char* wsB = (char*)d_ws;
    size_t off = 0;
    f16*   h1T  = (f16*)(wsB + off); off += (size_t)512 * 31 * 2368 * 2;   // 75.2 MB
    f16*   Wpk  = (f16*)(wsB + off); off += 65536;
    f16*   h2f  = (f16*)(wsB + off); off += (size_t)512 * 3374 * 16;       // 27.6 MB
    f16*   Wpk3 = (f16*)(wsB + off); off += 48 * 1032 * 2;
    f16*   Wpk1 = (f16*)(wsB + off); off += 32 * 136 * 2;
    float* h3   = (float*)(wsB + off); off += (size_t)512 * 48 * 5 * 22 * 4;
    float* h4   = (float*)(wsB + off); off += (size_t)512 * 64 * 3 * 20 * 4;
    float* h5   = (float*)(wsB + off); off += (size_t)512 * 64 * 18 * 4;
    float* feat = (float*)(wsB + off); off += (size_t)BT * 128 * 4;
    float* wnum = (float*)(wsB + off); off += (size_t)BT * 64 * 4;
    float* wden = (float*)(wsB + off); off += (size_t)BT * 64 * 4;

    wpack1_kernel<<<(32 * 136 + 255) / 256, 256, 0, stream>>>(w1, Wpk1);
    wpack_kernel<<<(48 * 616 + 255) / 256, 256, 0, stream>>>(w2, Wpk);
    wpack3_kernel<<<(48 * 1032 + 255) / 256, 256, 0, stream>>>(w3, Wpk3);

    conv1_mfma<<<1024, 512, 0, stream>>>(x, Wpk1, b1, h1T);
    conv2_mfma<<<512, 384, 0, stream>>>(h1T, Wpk, b2, h2f);
    conv3_mfma<<<512, 384, 0, stream>>>(h2f, Wpk3, b3, h3);

    // conv4: [512,48,5,22] -> [512,64,3,20]
    {
        int n_cg = 16, n_wg = 5;
        int sp_threads = BT * 3 * n_wg;
        int grid = (sp_threads + 255) / 256 * n_cg;
        conv_tile_kernel<48, 3, 3, 1, 4, 4><<<grid, 256, 0, stream>>>(
            h3, w4, b4, h4, 64, 5, 22, 3, 20, n_cg, n_wg, BT);
    }
    // conv5: -> [512,64,1,18]
    {
        int n_cg = 16, n_wg = 6;
        int sp_threads = BT * 1 * n_wg;
        int grid = (sp_threads + 255) / 256 * n_cg;
        conv_tile_kernel<64, 3, 3, 1, 4, 3><<<grid, 256, 0, stream>>>(
            h4, w5, b5, h5, 64, 3, 20, 1, 18, n_cg, n_wg, BT);
    }
    fc_relu_kernel<<<512, 256, 0, stream>>>(h5, fcw, fcb, feat);
    sensory_kernel<<<BT, 64, 0, stream>>>(feat, smu, ssig, sw, serv, wnum, wden);
    ltc_wave_kernel<<<32, 512, 0, stream>>>(wnum, wden, mu, sig, ww, erev,
                                            gl, vl, cm, out, 16);
}